// Round 8
// baseline (893.498 us; speedup 1.0000x reference)
//
#include <hip/hip_runtime.h>
#include <stdint.h>

#define NPTS 8192
#define SSZ  2048
#define QTOT (8*2048*32)   // 524288 positions (b,s,k)

// ---- float-index offsets within ws param region F ----
#define F_MOM1   4
#define F_MOM2   12
#define F_SC1    972
#define F_SH1    1004
#define F_SC2    1036
#define F_SH2    1100
#define F_SC3    1164
#define F_SH3    1292
#define F_SC4    1420
#define F_SH4    1676
#define F_WF1    1932
#define F_WF2    2188
#define F_SUM3   204
#define F_SSQ3   332
#define F_SUM4   460
#define F_SSQ4   716
#define F_G1     53388
#define F_BE1    53420
#define F_G2     53452
#define F_BE2    53516
#define F_G3     53580
#define F_BE3    53708
#define F_G4     53836
#define F_BE4    54092
// h1 moment results (BN2 analytic): M1[32] then M2[32*32]
#define F_M1     57344
#define F_M2     57376
// 16-slot partials for stats2m flush: P[16][1056] floats
#define F_P      60000
// byte offsets of big ws buffers
#define CTR_OFF  524288ull
#define LOA_OFF  1310720ull
#define U3H_OFF  2097152ull   // W3 A-frag packed, hi bf16 [16384]
#define U3L_OFF  2129920ull   // lo
#define U4H_OFF  2162688ull   // W4 A-frag packed, hi bf16 [32768]
#define U4L_OFF  2228224ull   // lo
#define U2H_OFF  2293760ull   // W2 A-frag packed, hi bf16 [2048]
#define U2L_OFF  2297856ull   // lo; ends 2301952
// tier-1 (h2 split, bit-exact): 8192 blocks x 8KB each buffer
#define H2H_OFF  2301952ull
#define H2L_OFF  (2301952ull + 67108864ull)
#define WS_H2    (2301952ull + 2ull*67108864ull)    // ~130.2 MiB

typedef __attribute__((ext_vector_type(8))) short s8v;   // 8 bf16 (4 VGPRs)
typedef __attribute__((ext_vector_type(4))) short s4v;   // 4 bf16 (b64)
typedef __attribute__((ext_vector_type(4))) float f4v;   // MFMA acc
#define MFMA(a,b,c) __builtin_amdgcn_mfma_f32_16x16x32_bf16(a,b,c,0,0,0)

__device__ inline float bf2f(unsigned short u){ return __uint_as_float(((uint32_t)u)<<16); }
__device__ inline unsigned short f2bf(float f){
    uint32_t x=__float_as_uint(f);
    return (unsigned short)((x + 0x7fffu + ((x>>16)&1u))>>16);
}
__device__ inline float clipf(float x){
    const float LO=(float)(-1.0+1e-7), HI=(float)(1.0-1e-7);
    return fminf(fmaxf(x,LO),HI);
}
__device__ inline float wredsum(float v){
#pragma unroll
    for(int m=1;m<64;m<<=1) v+=__shfl_xor(v,m,64);
    return v;
}
// mode: 0 = bf16 ushort storage, 1 = f32 storage
__device__ inline float ldin(const void* p,size_t i,int md){
    return md ? ((const float*)p)[i] : bf2f(((const unsigned short*)p)[i]);
}
// exact np.linspace(0,8191,2048)[s].astype(int32)
__device__ inline int sidx(int s){ return (s*8191)/2047; }

// ---- dtype probe ----
__global__ void k_detect(const void* contour,int* flag){
    __shared__ int he;
    if(threadIdx.x==0) he=0;
    __syncthreads();
    const unsigned short* u=(const unsigned short*)contour;
    int h=0;
    for(int i=threadIdx.x;i<4096;i+=256){
        unsigned short lo=u[2*i];
        if(((lo>>7)&0xFF)>=0x86) h++;
    }
    atomicAdd(&he,h);
    __syncthreads();
    if(threadIdx.x==0) *flag = (he>400) ? 1 : 0;
}

// ---- outputs 0/1: pure gather, f32 writes ----
__global__ __launch_bounds__(256) void k_out01(
    const void* __restrict__ ctr,const void* __restrict__ loa,
    const float* __restrict__ F,float* __restrict__ out)
{
    int md=((const int*)F)[0];
    int e=blockIdx.x*256+threadIdx.x;      // 16384 = B*S
    int b=e>>11, s=e&2047;
    int idx=sidx(s);
    size_t cb=((size_t)b*NPTS+idx)*3;
    size_t ob=(size_t)e*3;
    out[ob]        =ldin(ctr,cb  ,md);
    out[ob+1]      =ldin(ctr,cb+1,md);
    out[ob+2]      =ldin(ctr,cb+2,md);
    out[49152+ob]  =ldin(loa,cb  ,md);
    out[49152+ob+1]=ldin(loa,cb+1,md);
    out[49152+ob+2]=ldin(loa,cb+2,md);
}

// ---- canonicalize inputs, pack W2/W3/W4 into A-fragment order (hi/lo bf16) ----
__global__ __launch_bounds__(256) void k_convert(
    const void* ctr,const void* loa,
    const void* w1,const void* w2,const void* w3,const void* w4,
    const void* g1,const void* be1,const void* g2,const void* be2,
    const void* g3,const void* be3,const void* g4,const void* be4,
    float* F, float* ctrf, float* loaf,
    unsigned short* u2h, unsigned short* u2l,
    unsigned short* u3h, unsigned short* u3l,
    unsigned short* u4h, unsigned short* u4l)
{
    int md=((const int*)F)[0];
    int i = blockIdx.x*256+threadIdx.x;     // 768 blocks -> 196608
    ctrf[i]=ldin(ctr,i,md);
    loaf[i]=ldin(loa,i,md);
    if(i<256)  F[F_WF1+i]=ldin(w1,i,md);
    if(i<2048) F[F_WF2+i]=ldin(w2,i,md);
    if(i<2048){
        // W2 (64x32) A-frags, kt=0 only: mt 0..3
        int j=i&7, lane=(i>>3)&63, mt=i>>9;
        int m=lane&15, kk=((lane>>4)<<3)|j;
        float w=ldin(w2,(size_t)(mt*16+m)*32 + kk, md);
        unsigned short hi=f2bf(w);
        u2h[i]=hi; u2l[i]=f2bf(w-bf2f(hi));
    }
    if(i<16384){
        int j=i&7, lane=(i>>3)&63, kt=(i>>9)&3, mt=i>>11;
        int m=lane&15, kk=((lane>>4)<<3)|j;
        float w=ldin(w3,(size_t)(mt*16+m)*128 + kt*32+kk, md);
        unsigned short hi=f2bf(w);
        u3h[i]=hi; u3l[i]=f2bf(w-bf2f(hi));
    }
    if(i<32768){
        int j=i&7, lane=(i>>3)&63, kt=(i>>9)&3, mt=i>>11;   // mt 0..15
        int m=lane&15, kk=((lane>>4)<<3)|j;
        float w=ldin(w4,(size_t)(mt*16+m)*128 + kt*32+kk, md);
        unsigned short hi=f2bf(w);
        u4h[i]=hi; u4l[i]=f2bf(w-bf2f(hi));
    }
    if(i<968)   F[4+i]=0.f;
    if(i<16896) F[F_P+i]=0.f;   // 16-slot partials
    if(i<32){ F[F_G1+i]=ldin(g1,i,md); F[F_BE1+i]=ldin(be1,i,md); }
    if(i<64){ F[F_G2+i]=ldin(g2,i,md); F[F_BE2+i]=ldin(be2,i,md); }
    if(i<128){ F[F_G3+i]=ldin(g3,i,md); F[F_BE3+i]=ldin(be3,i,md); }
    if(i<256){ F[F_G4+i]=ldin(g4,i,md); F[F_BE4+i]=ldin(be4,i,md); }
}

// ---- shared feature computation: r[8]; lane groups of 32 = one (b,s) ----
__device__ inline void rif_compute(const float* __restrict__ ctr,const float* __restrict__ loa,
                                   int b,int s,int k,float r[8])
{
    int idx=sidx(s);
    int gi=(idx-16+k)&(NPTS-1);
    size_t cb=((size_t)b*NPTS+gi)*3;
    float px=ctr[cb],py=ctr[cb+1],pz=ctr[cb+2];
    float lx=loa[cb],ly=loa[cb+1],lz=loa[cb+2];
    float sx=__shfl(px,16,32),sy=__shfl(py,16,32),sz=__shfl(pz,16,32);
    float ax=__shfl(lx,16,32),ay=__shfl(ly,16,32),az=__shfl(lz,16,32);
    float vx=px-sx,vy=py-sy,vz=pz-sz;
    float sq=vx*vx+vy*vy+vz*vz;
    float d1=sq>0.f?sqrtf(sq):0.f;
    float inv=d1>0.f?1.f/d1:0.f;
    float ux=vx*inv,uy=vy*inv,uz=vz*inv;
    float a1=ux*ax+uy*ay+uz*az;
    float a2=ux*lx+uy*ly+uz*lz;
    float a3=acosf(clipf(lx*ax+ly*ay+lz*az));
    int src=(k+31)&31;
    float pvx=__shfl(vx,src,32),pvy=__shfl(vy,src,32),pvz=__shfl(vz,src,32);
    float plx=__shfl(lx,src,32),ply=__shfl(ly,src,32),plz=__shfl(lz,src,32);
    float pux=__shfl(ux,src,32),puy=__shfl(uy,src,32),puz=__shfl(uz,src,32);
    float ivx=vx-pvx,ivy=vy-pvy,ivz=vz-pvz;
    float isq=ivx*ivx+ivy*ivy+ivz*ivz;
    float idn=isq>0.f?1.f/sqrtf(isq):0.f;
    float iux=ivx*idn,iuy=ivy*idn,iuz=ivz*idn;
    float a4=iux*lx+iuy*ly+iuz*lz;
    float a5=iux*plx+iuy*ply+iuz*plz;
    float a6=acosf(clipf(lx*plx+ly*ply+lz*plz));
    float d2=acosf(clipf(ux*pux+uy*puy+uz*puz));
    r[0]=d1;r[1]=d2;r[2]=a1;r[3]=a2;r[4]=a3;r[5]=a4;r[6]=a5;r[7]=a6;
}

// ---- features: rif moments (analytic BN1) ----
__global__ __launch_bounds__(256) void k_features(
    const float* __restrict__ ctrf,const float* __restrict__ loaf,
    float* __restrict__ mom1,float* __restrict__ mom2)
{
    __shared__ float sm1[8],sm2[64];
    int t=threadIdx.x;
    if(t<8)sm1[t]=0.f;
    if(t<64)sm2[t]=0.f;
    __syncthreads();
    int lane=t&63,k=t&31;
    int q=blockIdx.x*256+t;
    int pos=q>>5,b=pos>>11,s=pos&2047;
    float r[8];
    rif_compute(ctrf,loaf,b,s,k,r);
#pragma unroll
    for(int i=0;i<8;i++){ float sv=wredsum(r[i]); if(lane==0)atomicAdd(&sm1[i],sv); }
#pragma unroll
    for(int i=0;i<8;i++)
#pragma unroll
        for(int j=i;j<8;j++){ float sv=wredsum(r[i]*r[j]); if(lane==0)atomicAdd(&sm2[i*8+j],sv); }
    __syncthreads();
    if(t<8)atomicAdd(&mom1[t],sm1[t]);
    if(t<64)atomicAdd(&mom2[t],sm2[t]);
}

// ---- analytic BN1 ----
__global__ void k_bn1(float* F){
    int o=threadIdx.x;
    if(o>=32)return;
    const float invP=1.0f/(float)QTOT;
    float m[8],w[8];
#pragma unroll
    for(int c=0;c<8;c++){ m[c]=F[F_MOM1+c]*invP; w[c]=F[F_WF1+o*8+c]; }
    float Ey=0.f;
#pragma unroll
    for(int c=0;c<8;c++) Ey+=w[c]*m[c];
    float Eyy=0.f;
#pragma unroll
    for(int i=0;i<8;i++)
#pragma unroll
        for(int j=0;j<8;j++){
            int a=i<j?i:j,bb=i<j?j:i;
            Eyy+=w[i]*w[j]*F[F_MOM2+a*8+bb]*invP;
        }
    float var=fmaxf(Eyy-Ey*Ey,0.f);
    float sc=F[F_G1+o]/sqrtf(var+1e-5f);
    F[F_SC1+o]=sc;
    F[F_SH1+o]=F[F_BE1+o]-Ey*sc;
}

// ---- generic BN finalize ----
__global__ void k_bnd(float* F,int C,int sumO,int ssqO,int gO,int beO,int scO,int shO){
    int o=threadIdx.x;
    if(o>=C)return;
    const float invP=1.0f/(float)QTOT;
    float mean=F[sumO+o]*invP;
    float var=fmaxf(F[ssqO+o]*invP-mean*mean,0.f);
    float s=F[gO+o]/sqrtf(var+1e-5f);
    F[scO+o]=s;
    F[shO+o]=F[beO+o]-mean*s;
}

// ---- stats2m: accumulate M1 = sum h1, M2 = sum h1 h1^T via MFMA ----
#define S2T 264
__global__ __launch_bounds__(256) void k_stats2m(
    const float* __restrict__ ctrf,const float* __restrict__ loaf,
    const float* __restrict__ F,float* __restrict__ P)
{
    __shared__ unsigned short TH[32*S2T];
    __shared__ unsigned short TL[32*S2T];
    int t=threadIdx.x, wv=t>>6, lane=t&63;
    int quad=lane>>4, col=lane&15;
    int mi=wv>>1, ni=wv&1;           // wave's M2 quadrant
    float acc8[8];                   // M1 partials: wave wv owns ch 8wv..8wv+7
#pragma unroll
    for(int k=0;k<8;k++) acc8[k]=0.f;
    f4v Z; Z[0]=0.f;Z[1]=0.f;Z[2]=0.f;Z[3]=0.f;
    f4v C0=Z, C1=Z;
    const float* wf1=F+F_WF1;
    const float* sc1=F+F_SC1; const float* sh1=F+F_SH1;
    for(int tt=0;tt<2;++tt){
        int tile=blockIdx.x*2+tt;                 // 0..2047
        int pos=tile*8 + wv*2 + (lane>>5);        // (b,s) index
        int b=pos>>11, s=pos&2047;
        float r[8]; rif_compute(ctrf,loaf,b,s,lane&31,r);
        int mypos=wv*64+lane;                     // 0..255 within tile
#pragma unroll
        for(int c=0;c<32;c++){                    // fused h1: no h1[32] array
            const float* w=wf1+c*8;
            float y=w[0]*r[0]+w[1]*r[1]+w[2]*r[2]+w[3]*r[3]
                   +w[4]*r[4]+w[5]*r[5]+w[6]*r[6]+w[7]*r[7];
            float h=fmaxf(y*sc1[c]+sh1[c],0.f);
            unsigned short hi=f2bf(h);
            TH[c*S2T+mypos]=hi;
            TL[c*S2T+mypos]=f2bf(h-bf2f(hi));
        }
        __syncthreads();
#pragma unroll
        for(int kt=0;kt<8;kt++){
            s8v AH=*(const s8v*)(TH+(mi*16+col)*S2T + kt*32 + quad*8);
            s8v AL=*(const s8v*)(TL+(mi*16+col)*S2T + kt*32 + quad*8);
            s8v BH=*(const s8v*)(TH+(ni*16+col)*S2T + kt*32 + quad*8);
            s8v BL=*(const s8v*)(TL+(ni*16+col)*S2T + kt*32 + quad*8);
            if(kt&1){
                C1=MFMA(AH,BH,C1); C1=MFMA(AH,BL,C1); C1=MFMA(AL,BH,C1);
            }else{
                C0=MFMA(AH,BH,C0); C0=MFMA(AH,BL,C0); C0=MFMA(AL,BH,C0);
            }
        }
        // M1 from LDS: lane covers pos lane*4..lane*4+3 of each owned channel
#pragma unroll
        for(int k=0;k<8;k++){
            int c=wv*8+k;
            const unsigned short* ph=TH+c*S2T+lane*4;
            const unsigned short* pl=TL+c*S2T+lane*4;
            acc8[k]+=bf2f(ph[0])+bf2f(ph[1])+bf2f(ph[2])+bf2f(ph[3])
                    +bf2f(pl[0])+bf2f(pl[1])+bf2f(pl[2])+bf2f(pl[3]);
        }
        __syncthreads();
    }
    // flush to partial slot (slot = blk & 15): P[slot][0..31]=M1, [32..1055]=M2
    float* Ps=P+(size_t)(blockIdx.x&15)*1056;
#pragma unroll
    for(int rg=0;rg<4;rg++){
        float v=C0[rg]+C1[rg];
        atomicAdd(&Ps[32+(mi*16+quad*4+rg)*32 + ni*16+col], v);
    }
#pragma unroll
    for(int k=0;k<8;k++){
        float sv=wredsum(acc8[k]);
        if(lane==0) atomicAdd(&Ps[wv*8+k],sv);
    }
}

// ---- fold 16 partial slots into F_M1/F_M2, then analytic BN2 (merged) ----
__global__ void k_red(float* F){
    int t=threadIdx.x;   // 1 block x 256 threads
    for(int e=t;e<1056;e+=256){
        float s=0.f;
#pragma unroll
        for(int k=0;k<16;k++) s+=F[F_P+k*1056+e];
        if(e<32) F[F_M1+e]=s; else F[F_M2+e-32]=s;
    }
    __syncthreads();
    int o=t;
    if(o<64){
        const float invP=1.0f/(float)QTOT;
        const float* w=F+F_WF2+o*32;
        const float* M2=F+F_M2;
        float Ey=0.f;
#pragma unroll
        for(int c=0;c<32;c++) Ey+=w[c]*F[F_M1+c];
        Ey*=invP;
        float Eyy=0.f;
        for(int c1=0;c1<32;c1++){
            float acc=0.f;
#pragma unroll
            for(int c2=0;c2<32;c2++) acc+=w[c2]*M2[c1*32+c2];
            Eyy+=w[c1]*acc;
        }
        Eyy*=invP;
        float var=fmaxf(Eyy-Ey*Ey,0.f);
        float s=F[F_G2+o]/sqrtf(var+1e-5f);
        F[F_SC2+o]=s;
        F[F_SH2+o]=F[F_BE2+o]-Ey*s;
    }
}

// =====================================================================
// MFMA tile kernels, 512-thread (8-wave). Tile = 64 positions (2 s).
// A-fragments HOISTED into registers before the MFMA loops (the round-7
// VGPR=44 build serialized A-loads -> ~200cy L2 latency exposed per kt
// step). __launch_bounds__(512,4) caps VGPR at 128 to keep 2 blocks/CU.
// Per-accumulator MFMA order unchanged -> bit-identical output.
// =====================================================================
#define XST 136   // ushort row stride (16B-aligned rows)

__device__ inline void build_x2_8(
    const float* __restrict__ ctrf,const float* __restrict__ loaf,
    const void* __restrict__ fm,const float* __restrict__ F,
    const unsigned short* __restrict__ u2h,const unsigned short* __restrict__ u2l,
    int md,int b,int s0,int wv,int lane,
    unsigned short* XH,unsigned short* XL)
{
    int quad=lane>>4, col=lane&15;
    if(wv<4){
        // rif + h1, 8 channels per wave (waves 0-3)
        float r8[8]; rif_compute(ctrf,loaf,b,s0+(lane>>5),lane&31,r8);
        const float* wf1=F+F_WF1;
        const float* sc1=F+F_SC1; const float* sh1=F+F_SH1;
        s8v vh,vl;
#pragma unroll
        for(int j=0;j<8;j++){
            int o=8*wv+j;
            const float* w=wf1+o*8;
            float y=w[0]*r8[0]+w[1]*r8[1]+w[2]*r8[2]+w[3]*r8[3]
                   +w[4]*r8[4]+w[5]*r8[5]+w[6]*r8[6]+w[7]*r8[7];
            float h=fmaxf(y*sc1[o]+sh1[o],0.f);
            unsigned short hi=f2bf(h);
            vh[j]=(short)hi;
            vl[j]=(short)f2bf(h-bf2f(hi));
        }
        *(s8v*)(XH + lane*XST + 8*wv)=vh;
        *(s8v*)(XL + lane*XST + 8*wv)=vl;
    }else{
        // fm gather, 16 d per wave (waves 4-7)
        int dbase=16*(wv-4);
        int s=s0+(lane>>5), k=lane&31;
        int gi=(sidx(s)-16+k)&(NPTS-1);
        size_t fb=(size_t)b*64*NPTS+gi;
        for(int g=0;g<2;g++){
            s8v vh,vl;
#pragma unroll
            for(int j=0;j<8;j++){
                int d=dbase+g*8+j;
                float v = md ? ((const float*)fm)[fb+(size_t)d*NPTS]
                             : bf2f(((const unsigned short*)fm)[fb+(size_t)d*NPTS]);
                unsigned short hi=f2bf(v);
                vh[j]=(short)hi;
                vl[j]=(short)f2bf(v-bf2f(hi));
            }
            *(s8v*)(XH + lane*XST + 64 + dbase + g*8)=vh;
            *(s8v*)(XL + lane*XST + 64 + dbase + g*8)=vl;
        }
    }
    __syncthreads();   // h1 (cols 0..31) + fm (cols 64..127) visible
    // ---- conv2 via MFMA: wave -> (ch-group cg, nt-pair nb) ----
    int cg=wv>>1, nb=(wv&1)*2;
    s8v AH=*(const s8v*)(u2h+(cg*64+lane)*8);
    s8v AL=*(const s8v*)(u2l+(cg*64+lane)*8);
    s8v BH0=*(const s8v*)(XH+((nb  )*16+col)*XST+quad*8);
    s8v BL0=*(const s8v*)(XL+((nb  )*16+col)*XST+quad*8);
    s8v BH1=*(const s8v*)(XH+((nb+1)*16+col)*XST+quad*8);
    s8v BL1=*(const s8v*)(XL+((nb+1)*16+col)*XST+quad*8);
    f4v Z; Z[0]=0.f;Z[1]=0.f;Z[2]=0.f;Z[3]=0.f;
    f4v c0=MFMA(AH,BH0,Z), c1=MFMA(AH,BH1,Z);
    c0=MFMA(AH,BL0,c0); c1=MFMA(AH,BL1,c1);
    c0=MFMA(AL,BH0,c0); c1=MFMA(AL,BH1,c1);
    __syncthreads();   // all h1 reads done before cols 0..63 overwritten
    // ---- BN2 + relu, write split h2 to cols 0..63 ----
    const float* sc2=F+F_SC2; const float* sh2=F+F_SH2;
    int chb=cg*16+quad*4;
    float g0=sc2[chb],g1=sc2[chb+1],g2=sc2[chb+2],g3=sc2[chb+3];
    float b0=sh2[chb],b1=sh2[chb+1],b2=sh2[chb+2],b3=sh2[chb+3];
#pragma unroll
    for(int i=0;i<2;i++){
        f4v c = i? c1 : c0;
        int p=(nb+i)*16+col;
        float v0=fmaxf(c[0]*g0+b0,0.f);
        float v1=fmaxf(c[1]*g1+b1,0.f);
        float v2=fmaxf(c[2]*g2+b2,0.f);
        float v3=fmaxf(c[3]*g3+b3,0.f);
        unsigned short h0=f2bf(v0),h1=f2bf(v1),h2=f2bf(v2),h3=f2bf(v3);
        s4v vh,vl;
        vh[0]=(short)h0; vh[1]=(short)h1; vh[2]=(short)h2; vh[3]=(short)h3;
        vl[0]=(short)f2bf(v0-bf2f(h0)); vl[1]=(short)f2bf(v1-bf2f(h1));
        vl[2]=(short)f2bf(v2-bf2f(h2)); vl[3]=(short)f2bf(v3-bf2f(h3));
        *(s4v*)(XH + p*XST + chb)=vh;
        *(s4v*)(XL + p*XST + chb)=vl;
    }
    // caller's __syncthreads() completes the tile
}

// GEMM1 (512t): wave wv owns mt=wv; A-frags hoisted (8 s8v = 32 VGPR)
#define G1_STEP8(UH,UL) \
    { \
        s8v A1h[4],A1l[4]; \
        for(int kt=0;kt<4;kt++){ \
            A1h[kt]=*(const s8v*)(UH+((wv*4+kt)*64+lane)*8); \
            A1l[kt]=*(const s8v*)(UL+((wv*4+kt)*64+lane)*8); \
        } \
        for(int kt=0;kt<4;kt++){ \
            s8v BH[4],BL[4]; \
            for(int nt=0;nt<4;nt++){ \
                int boff=(nt*16+col)*XST + kt*32 + quad*8; \
                BH[nt]=*(const s8v*)(XH+boff); \
                BL[nt]=*(const s8v*)(XL+boff); \
            } \
            for(int nt=0;nt<4;nt++) C[nt]=MFMA(A1h[kt],BH[nt],C[nt]); \
            for(int nt=0;nt<4;nt++) C[nt]=MFMA(A1h[kt],BL[nt],C[nt]); \
            for(int nt=0;nt<4;nt++) C[nt]=MFMA(A1l[kt],BH[nt],C[nt]); \
        } \
    }

// GEMM2 (512t): wave wv owns mt=2wv..2wv+1; mi-outer with hoisted A
#define G2_STEP8(UH,UL) \
    for(int mi=0;mi<2;mi++){ \
        int mt=2*wv+mi; \
        s8v A2h[4],A2l[4]; \
        for(int kt=0;kt<4;kt++){ \
            A2h[kt]=*(const s8v*)(UH+((mt*4+kt)*64+lane)*8); \
            A2l[kt]=*(const s8v*)(UL+((mt*4+kt)*64+lane)*8); \
        } \
        for(int kt=0;kt<4;kt++){ \
            s8v BH[4],BL[4]; \
            for(int nt=0;nt<4;nt++){ \
                int boff=(nt*16+col)*XST + kt*32 + quad*8; \
                BH[nt]=*(const s8v*)(XH+boff); \
                BL[nt]=*(const s8v*)(XL+boff); \
            } \
            for(int nt=0;nt<4;nt++) C2[mi][nt]=MFMA(A2h[kt],BH[nt],C2[mi][nt]); \
            for(int nt=0;nt<4;nt++) C2[mi][nt]=MFMA(A2h[kt],BL[nt],C2[mi][nt]); \
            for(int nt=0;nt<4;nt++) C2[mi][nt]=MFMA(A2l[kt],BH[nt],C2[mi][nt]); \
        } \
    }

// ---- stats3: x2 tile -> GEMM1 (W3) -> sum/ssq of y3; exports h2 tile ----
__global__ __launch_bounds__(512,4) void k_stats3(
    const float* __restrict__ ctrf,const float* __restrict__ loaf,
    const void* __restrict__ fm,const float* __restrict__ F,
    const unsigned short* __restrict__ u2h,const unsigned short* __restrict__ u2l,
    const unsigned short* __restrict__ u3h,const unsigned short* __restrict__ u3l,
    unsigned short* __restrict__ h2h,unsigned short* __restrict__ h2l,
    float* __restrict__ sum3,float* __restrict__ ssq3)
{
    __shared__ unsigned short XH[64*XST];
    __shared__ unsigned short XL[64*XST];
    __shared__ float as_[128],qs_[128];
    int t=threadIdx.x, wv=t>>6, lane=t&63;
    if(t<128){as_[t]=0.f;qs_[t]=0.f;}
    int md=((const int*)F)[0];
    int pos0=blockIdx.x*2, b=pos0>>11, s0=pos0&2047;
    build_x2_8(ctrf,loaf,fm,F,u2h,u2l,md,b,s0,wv,lane,XH,XL);
    __syncthreads();
    int quad=lane>>4, col=lane&15;
    f4v Z; Z[0]=0.f;Z[1]=0.f;Z[2]=0.f;Z[3]=0.f;
    f4v C[4];
#pragma unroll
    for(int nt=0;nt<4;nt++) C[nt]=Z;
    G1_STEP8(u3h,u3l)
    // ---- tier1 export: h2 tile (cols 0..63) bit-exact to global ----
    if(h2h){
        int pos=t>>3, off=((t&7)^(pos&7))*8;    // XOR chunk swizzle, bijective per pos
        size_t go=(size_t)blockIdx.x*4096 + (size_t)pos*64 + off;
        *(s8v*)(h2h+go)=*(const s8v*)(XH+pos*XST+off);
        *(s8v*)(h2l+go)=*(const s8v*)(XL+pos*XST+off);
    }
#pragma unroll
    for(int rg=0;rg<4;rg++){
        float sm=0.f,sq=0.f;
#pragma unroll
        for(int nt=0;nt<4;nt++){ float v=C[nt][rg]; sm+=v; sq+=v*v; }
        sm+=__shfl_xor(sm,1); sq+=__shfl_xor(sq,1);
        sm+=__shfl_xor(sm,2); sq+=__shfl_xor(sq,2);
        sm+=__shfl_xor(sm,4); sq+=__shfl_xor(sq,4);
        sm+=__shfl_xor(sm,8); sq+=__shfl_xor(sq,8);
        if(col==0){
            int ch=wv*16+quad*4+rg;
            atomicAdd(&as_[ch],sm); atomicAdd(&qs_[ch],sq);
        }
    }
    __syncthreads();
    if(t<128){atomicAdd(&sum3[t],as_[t]);atomicAdd(&ssq3[t],qs_[t]);}
}

// ---- conv4 H2 (tier1): reload h2, regather fm, GEMM1->BN3->GEMM2 ----
__global__ __launch_bounds__(512,4) void k_conv4h(
    const void* __restrict__ fm,const float* __restrict__ F,
    const unsigned short* __restrict__ u3h,const unsigned short* __restrict__ u3l,
    const unsigned short* __restrict__ u4h,const unsigned short* __restrict__ u4l,
    const unsigned short* __restrict__ h2h,const unsigned short* __restrict__ h2l,
    float* __restrict__ maxb,float* __restrict__ sum4,float* __restrict__ ssq4)
{
    __shared__ unsigned short XH[64*XST];
    __shared__ unsigned short XL[64*XST];
    __shared__ float as_[256],qs_[256];
    int t=threadIdx.x, wv=t>>6, lane=t&63;
    if(t<256){as_[t]=0.f; qs_[t]=0.f;}
    int md=((const int*)F)[0];
    int pos0=blockIdx.x*2, b=pos0>>11, s0=pos0&2047;
    // ---- h2 import (matches export layout: global[pos][j]=lds[pos][j]) ----
    {
        int pos=t>>3, off=((t&7)^(pos&7))*8;
        size_t go=(size_t)blockIdx.x*4096 + (size_t)pos*64 + off;
        *(s8v*)(XH+pos*XST+off)=*(const s8v*)(h2h+go);
        *(s8v*)(XL+pos*XST+off)=*(const s8v*)(h2l+go);
    }
    // ---- fm gather: wave wv covers d [8wv, 8wv+8) ----
    {
        int dbase=8*wv;
        int s=s0+(lane>>5), k=lane&31;
        int gi=(sidx(s)-16+k)&(NPTS-1);
        size_t fb=(size_t)b*64*NPTS+gi;
        s8v vh,vl;
#pragma unroll
        for(int j=0;j<8;j++){
            int d=dbase+j;
            float v = md ? ((const float*)fm)[fb+(size_t)d*NPTS]
                         : bf2f(((const unsigned short*)fm)[fb+(size_t)d*NPTS]);
            unsigned short hi=f2bf(v);
            vh[j]=(short)hi;
            vl[j]=(short)f2bf(v-bf2f(hi));
        }
        *(s8v*)(XH + lane*XST + 64 + dbase)=vh;
        *(s8v*)(XL + lane*XST + 64 + dbase)=vl;
    }
    __syncthreads();   // x2 tile complete
    int quad=lane>>4, col=lane&15;
    // ---- GEMM1: C[4], mt=wv ----
    f4v Z; Z[0]=0.f;Z[1]=0.f;Z[2]=0.f;Z[3]=0.f;
    f4v C[4];
#pragma unroll
    for(int nt=0;nt<4;nt++) C[nt]=Z;
    G1_STEP8(u3h,u3l)
    __syncthreads();   // all waves done reading x2
    // ---- BN3 + relu -> h3 split ----
    const float* sc3=F+F_SC3; const float* sh3=F+F_SH3;
    {
        int chb=wv*16+quad*4;
#pragma unroll
        for(int nt=0;nt<4;nt++){
            int p=nt*16+col;
            s4v vh,vl;
#pragma unroll
            for(int rg=0;rg<4;rg++){
                float v=C[nt][rg];
                v=fmaxf(v*sc3[chb+rg]+sh3[chb+rg],0.f);
                unsigned short hi=f2bf(v);
                vh[rg]=(short)hi;
                vl[rg]=(short)f2bf(v-bf2f(hi));
            }
            *(s4v*)(XH + p*XST + chb)=vh;
            *(s4v*)(XL + p*XST + chb)=vl;
        }
    }
    __syncthreads();   // h3 tile complete
    // ---- GEMM2: C2[2][4], mt=2wv..2wv+1 ----
    f4v C2[2][4];
#pragma unroll
    for(int mi=0;mi<2;mi++)
#pragma unroll
        for(int nt=0;nt<4;nt++) C2[mi][nt]=Z;
    G2_STEP8(u4h,u4l)
    // ---- epilogue ----
#pragma unroll
    for(int mi=0;mi<2;mi++){
        int mt=2*wv+mi;
#pragma unroll
        for(int rg=0;rg<4;rg++){
            float sm=0.f,sq=0.f,mx0=-3.4e38f,mx1=-3.4e38f;
#pragma unroll
            for(int nt=0;nt<4;nt++){
                float v=C2[mi][nt][rg];
                sm+=v; sq+=v*v;
                if(nt<2) mx0=fmaxf(mx0,v); else mx1=fmaxf(mx1,v);
            }
            sm+=__shfl_xor(sm,1); sq+=__shfl_xor(sq,1);
            sm+=__shfl_xor(sm,2); sq+=__shfl_xor(sq,2);
            sm+=__shfl_xor(sm,4); sq+=__shfl_xor(sq,4);
            sm+=__shfl_xor(sm,8); sq+=__shfl_xor(sq,8);
            mx0=fmaxf(mx0,__shfl_xor(mx0,1)); mx1=fmaxf(mx1,__shfl_xor(mx1,1));
            mx0=fmaxf(mx0,__shfl_xor(mx0,2)); mx1=fmaxf(mx1,__shfl_xor(mx1,2));
            mx0=fmaxf(mx0,__shfl_xor(mx0,4)); mx1=fmaxf(mx1,__shfl_xor(mx1,4));
            mx0=fmaxf(mx0,__shfl_xor(mx0,8)); mx1=fmaxf(mx1,__shfl_xor(mx1,8));
            if(col==0){
                int ch=mt*16+quad*4+rg;
                atomicAdd(&as_[ch],sm); atomicAdd(&qs_[ch],sq);
                size_t ob=((size_t)b*256+ch)*SSZ + s0;
                maxb[ob]=mx0; maxb[ob+1]=mx1;
            }
        }
    }
    __syncthreads();
    if(t<256){atomicAdd(&sum4[t],as_[t]);atomicAdd(&ssq4[t],qs_[t]);}
}

// ---- conv4 SLOW (fallback when ws too small): full rebuild, 512t ----
__global__ __launch_bounds__(512,4) void k_conv4(
    const float* __restrict__ ctrf,const float* __restrict__ loaf,
    const void* __restrict__ fm,const float* __restrict__ F,
    const unsigned short* __restrict__ u2h,const unsigned short* __restrict__ u2l,
    const unsigned short* __restrict__ u3h,const unsigned short* __restrict__ u3l,
    const unsigned short* __restrict__ u4h,const unsigned short* __restrict__ u4l,
    float* __restrict__ maxb,float* __restrict__ sum4,float* __restrict__ ssq4)
{
    __shared__ unsigned short XH[64*XST];
    __shared__ unsigned short XL[64*XST];
    __shared__ float as_[256],qs_[256];
    int t=threadIdx.x, wv=t>>6, lane=t&63;
    if(t<256){as_[t]=0.f; qs_[t]=0.f;}
    int md=((const int*)F)[0];
    int pos0=blockIdx.x*2, b=pos0>>11, s0=pos0&2047;
    build_x2_8(ctrf,loaf,fm,F,u2h,u2l,md,b,s0,wv,lane,XH,XL);
    __syncthreads();
    int quad=lane>>4, col=lane&15;
    f4v Z; Z[0]=0.f;Z[1]=0.f;Z[2]=0.f;Z[3]=0.f;
    f4v C[4];
#pragma unroll
    for(int nt=0;nt<4;nt++) C[nt]=Z;
    G1_STEP8(u3h,u3l)
    __syncthreads();
    const float* sc3=F+F_SC3; const float* sh3=F+F_SH3;
    {
        int chb=wv*16+quad*4;
#pragma unroll
        for(int nt=0;nt<4;nt++){
            int p=nt*16+col;
            s4v vh,vl;
#pragma unroll
            for(int rg=0;rg<4;rg++){
                float v=C[nt][rg];
                v=fmaxf(v*sc3[chb+rg]+sh3[chb+rg],0.f);
                unsigned short hi=f2bf(v);
                vh[rg]=(short)hi;
                vl[rg]=(short)f2bf(v-bf2f(hi));
            }
            *(s4v*)(XH + p*XST + chb)=vh;
            *(s4v*)(XL + p*XST + chb)=vl;
        }
    }
    __syncthreads();
    f4v C2[2][4];
#pragma unroll
    for(int mi=0;mi<2;mi++)
#pragma unroll
        for(int nt=0;nt<4;nt++) C2[mi][nt]=Z;
    G2_STEP8(u4h,u4l)
#pragma unroll
    for(int mi=0;mi<2;mi++){
        int mt=2*wv+mi;
#pragma unroll
        for(int rg=0;rg<4;rg++){
            float sm=0.f,sq=0.f,mx0=-3.4e38f,mx1=-3.4e38f;
#pragma unroll
            for(int nt=0;nt<4;nt++){
                float v=C2[mi][nt][rg];
                sm+=v; sq+=v*v;
                if(nt<2) mx0=fmaxf(mx0,v); else mx1=fmaxf(mx1,v);
            }
            sm+=__shfl_xor(sm,1); sq+=__shfl_xor(sq,1);
            sm+=__shfl_xor(sm,2); sq+=__shfl_xor(sq,2);
            sm+=__shfl_xor(sm,4); sq+=__shfl_xor(sq,4);
            sm+=__shfl_xor(sm,8); sq+=__shfl_xor(sq,8);
            mx0=fmaxf(mx0,__shfl_xor(mx0,1)); mx1=fmaxf(mx1,__shfl_xor(mx1,1));
            mx0=fmaxf(mx0,__shfl_xor(mx0,2)); mx1=fmaxf(mx1,__shfl_xor(mx1,2));
            mx0=fmaxf(mx0,__shfl_xor(mx0,4)); mx1=fmaxf(mx1,__shfl_xor(mx1,4));
            mx0=fmaxf(mx0,__shfl_xor(mx0,8)); mx1=fmaxf(mx1,__shfl_xor(mx1,8));
            if(col==0){
                int ch=mt*16+quad*4+rg;
                atomicAdd(&as_[ch],sm); atomicAdd(&qs_[ch],sq);
                size_t ob=((size_t)b*256+ch)*SSZ + s0;
                maxb[ob]=mx0; maxb[ob+1]=mx1;
            }
        }
    }
    __syncthreads();
    if(t<256){atomicAdd(&sum4[t],as_[t]);atomicAdd(&ssq4[t],qs_[t]);}
}

// ---- final: out2 = relu(BN4(K-max)) in place, f32 (gamma=1 => scale>0) ----
__global__ __launch_bounds__(256) void k_apply(
    const float* __restrict__ F,float* __restrict__ out)
{
    int e=blockIdx.x*256+threadIdx.x;      // 4194304 = B*256*S
    int j=(e>>11)&255;
    float sc=F[F_SC4+j],sh=F[F_SH4+j];
    float v=out[98304+e];
    out[98304+e]=fmaxf(v*sc+sh,0.f);
}

extern "C" void kernel_launch(void* const* d_in, const int* in_sizes, int n_in,
                              void* d_out, int out_size, void* d_ws, size_t ws_size,
                              hipStream_t stream)
{
    const void* contour=d_in[0];
    const void* loa    =d_in[1];
    const void* fm     =d_in[2];
    const void* w1 =d_in[3];  const void* g1 =d_in[5];  const void* be1=d_in[6];
    const void* w2 =d_in[7];  const void* g2 =d_in[9];  const void* be2=d_in[10];
    const void* w3 =d_in[11]; const void* g3 =d_in[13]; const void* be3=d_in[14];
    const void* w4 =d_in[15]; const void* g4 =d_in[17]; const void* be4=d_in[18];
    float* out=(float*)d_out;          // output buffer is float32

    float* F=(float*)d_ws;
    char* base=(char*)d_ws;
    float* ctrf=(float*)(base+CTR_OFF);
    float* loaf=(float*)(base+LOA_OFF);
    unsigned short* u3h=(unsigned short*)(base+U3H_OFF);
    unsigned short* u3l=(unsigned short*)(base+U3L_OFF);
    unsigned short* u4h=(unsigned short*)(base+U4H_OFF);
    unsigned short* u4l=(unsigned short*)(base+U4L_OFF);
    unsigned short* u2h=(unsigned short*)(base+U2H_OFF);
    unsigned short* u2l=(unsigned short*)(base+U2L_OFF);
    int tier = (ws_size >= WS_H2) ? 1 : 0;
    unsigned short* h2h = tier==1 ? (unsigned short*)(base+H2H_OFF) : (unsigned short*)0;
    unsigned short* h2l = tier==1 ? (unsigned short*)(base+H2L_OFF) : (unsigned short*)0;
    float* maxb=out+98304;             // out2 f32 region doubles as K-max scratch

    k_detect<<<1,256,0,stream>>>(contour,(int*)d_ws);
    k_out01<<<64,256,0,stream>>>(contour,loa,F,out);
    k_convert<<<768,256,0,stream>>>(contour,loa,w1,w2,w3,w4,g1,be1,g2,be2,g3,be3,g4,be4,
                                    F,ctrf,loaf,u2h,u2l,u3h,u3l,u4h,u4l);
    k_features<<<2048,256,0,stream>>>(ctrf,loaf,F+F_MOM1,F+F_MOM2);
    k_bn1<<<1,32,0,stream>>>(F);
    k_stats2m<<<1024,256,0,stream>>>(ctrf,loaf,F,F+F_P);
    k_red<<<1,256,0,stream>>>(F);
    k_stats3<<<8192,512,0,stream>>>(ctrf,loaf,fm,F,u2h,u2l,u3h,u3l,h2h,h2l,
                                    F+F_SUM3,F+F_SSQ3);
    k_bnd<<<1,256,0,stream>>>(F,128,F_SUM3,F_SSQ3,F_G3,F_BE3,F_SC3,F_SH3);
    if(tier==1){
        k_conv4h<<<8192,512,0,stream>>>(fm,F,u3h,u3l,u4h,u4l,h2h,h2l,maxb,F+F_SUM4,F+F_SSQ4);
    }else{
        k_conv4<<<8192,512,0,stream>>>(ctrf,loaf,fm,F,u2h,u2l,u3h,u3l,u4h,u4l,maxb,F+F_SUM4,F+F_SSQ4);
    }
    k_bnd<<<1,256,0,stream>>>(F,256,F_SUM4,F_SSQ4,F_G4,F_BE4,F_SC4,F_SH4);
    k_apply<<<16384,256,0,stream>>>(F,out);
}

// Round 9
// 889.509 us; speedup vs baseline: 1.0045x; 1.0045x over previous
//
#include <hip/hip_runtime.h>
#include <stdint.h>

#define NPTS 8192
#define SSZ  2048
#define QTOT (8*2048*32)   // 524288 positions (b,s,k)

// ---- float-index offsets within ws param region F ----
#define F_MOM1   4
#define F_MOM2   12
#define F_SC1    972
#define F_SH1    1004
#define F_SC2    1036
#define F_SH2    1100
#define F_SC3    1164
#define F_SH3    1292
#define F_SC4    1420
#define F_SH4    1676
#define F_WF1    1932
#define F_WF2    2188
#define F_SUM3   204
#define F_SSQ3   332
#define F_SUM4   460
#define F_SSQ4   716
#define F_G1     53388
#define F_BE1    53420
#define F_G2     53452
#define F_BE2    53516
#define F_G3     53580
#define F_BE3    53708
#define F_G4     53836
#define F_BE4    54092
// h1 moment results (BN2 analytic): M1[32] then M2[32*32]
#define F_M1     57344
#define F_M2     57376
// 16-slot partials for stats2m flush: P[16][1056] floats
#define F_P      60000
// byte offsets of big ws buffers
#define CTR_OFF  524288ull
#define LOA_OFF  1310720ull
#define U3H_OFF  2097152ull   // W3 A-frag packed, hi bf16 [16384]
#define U3L_OFF  2129920ull   // lo
#define U4H_OFF  2162688ull   // W4 A-frag packed, hi bf16 [32768]
#define U4L_OFF  2228224ull   // lo
#define U2H_OFF  2293760ull   // W2 A-frag packed, hi bf16 [2048]
#define U2L_OFF  2297856ull   // lo; ends 2301952
// tier-1 (h2 split, bit-exact): 8192 blocks x 8KB each buffer
#define H2H_OFF  2301952ull
#define H2L_OFF  (2301952ull + 67108864ull)
#define WS_H2    (2301952ull + 2ull*67108864ull)    // ~130.2 MiB

typedef __attribute__((ext_vector_type(8))) short s8v;   // 8 bf16 (4 VGPRs)
typedef __attribute__((ext_vector_type(4))) short s4v;   // 4 bf16 (b64)
typedef __attribute__((ext_vector_type(4))) float f4v;   // MFMA acc
#define MFMA(a,b,c) __builtin_amdgcn_mfma_f32_16x16x32_bf16(a,b,c,0,0,0)

__device__ inline float bf2f(unsigned short u){ return __uint_as_float(((uint32_t)u)<<16); }
__device__ inline unsigned short f2bf(float f){
    uint32_t x=__float_as_uint(f);
    return (unsigned short)((x + 0x7fffu + ((x>>16)&1u))>>16);
}
__device__ inline float clipf(float x){
    const float LO=(float)(-1.0+1e-7), HI=(float)(1.0-1e-7);
    return fminf(fmaxf(x,LO),HI);
}
__device__ inline float wredsum(float v){
#pragma unroll
    for(int m=1;m<64;m<<=1) v+=__shfl_xor(v,m,64);
    return v;
}
// mode: 0 = bf16 ushort storage, 1 = f32 storage
__device__ inline float ldin(const void* p,size_t i,int md){
    return md ? ((const float*)p)[i] : bf2f(((const unsigned short*)p)[i]);
}
// exact np.linspace(0,8191,2048)[s].astype(int32)
__device__ inline int sidx(int s){ return (s*8191)/2047; }

// ---- dtype probe ----
__global__ void k_detect(const void* contour,int* flag){
    __shared__ int he;
    if(threadIdx.x==0) he=0;
    __syncthreads();
    const unsigned short* u=(const unsigned short*)contour;
    int h=0;
    for(int i=threadIdx.x;i<4096;i+=256){
        unsigned short lo=u[2*i];
        if(((lo>>7)&0xFF)>=0x86) h++;
    }
    atomicAdd(&he,h);
    __syncthreads();
    if(threadIdx.x==0) *flag = (he>400) ? 1 : 0;
}

// ---- outputs 0/1: pure gather, f32 writes ----
__global__ __launch_bounds__(256) void k_out01(
    const void* __restrict__ ctr,const void* __restrict__ loa,
    const float* __restrict__ F,float* __restrict__ out)
{
    int md=((const int*)F)[0];
    int e=blockIdx.x*256+threadIdx.x;      // 16384 = B*S
    int b=e>>11, s=e&2047;
    int idx=sidx(s);
    size_t cb=((size_t)b*NPTS+idx)*3;
    size_t ob=(size_t)e*3;
    out[ob]        =ldin(ctr,cb  ,md);
    out[ob+1]      =ldin(ctr,cb+1,md);
    out[ob+2]      =ldin(ctr,cb+2,md);
    out[49152+ob]  =ldin(loa,cb  ,md);
    out[49152+ob+1]=ldin(loa,cb+1,md);
    out[49152+ob+2]=ldin(loa,cb+2,md);
}

// ---- canonicalize inputs, pack W2/W3/W4 into A-fragment order (hi/lo bf16) ----
__global__ __launch_bounds__(256) void k_convert(
    const void* ctr,const void* loa,
    const void* w1,const void* w2,const void* w3,const void* w4,
    const void* g1,const void* be1,const void* g2,const void* be2,
    const void* g3,const void* be3,const void* g4,const void* be4,
    float* F, float* ctrf, float* loaf,
    unsigned short* u2h, unsigned short* u2l,
    unsigned short* u3h, unsigned short* u3l,
    unsigned short* u4h, unsigned short* u4l)
{
    int md=((const int*)F)[0];
    int i = blockIdx.x*256+threadIdx.x;     // 768 blocks -> 196608
    ctrf[i]=ldin(ctr,i,md);
    loaf[i]=ldin(loa,i,md);
    if(i<256)  F[F_WF1+i]=ldin(w1,i,md);
    if(i<2048) F[F_WF2+i]=ldin(w2,i,md);
    if(i<2048){
        // W2 (64x32) A-frags, kt=0 only: mt 0..3
        int j=i&7, lane=(i>>3)&63, mt=i>>9;
        int m=lane&15, kk=((lane>>4)<<3)|j;
        float w=ldin(w2,(size_t)(mt*16+m)*32 + kk, md);
        unsigned short hi=f2bf(w);
        u2h[i]=hi; u2l[i]=f2bf(w-bf2f(hi));
    }
    if(i<16384){
        int j=i&7, lane=(i>>3)&63, kt=(i>>9)&3, mt=i>>11;
        int m=lane&15, kk=((lane>>4)<<3)|j;
        float w=ldin(w3,(size_t)(mt*16+m)*128 + kt*32+kk, md);
        unsigned short hi=f2bf(w);
        u3h[i]=hi; u3l[i]=f2bf(w-bf2f(hi));
    }
    if(i<32768){
        int j=i&7, lane=(i>>3)&63, kt=(i>>9)&3, mt=i>>11;   // mt 0..15
        int m=lane&15, kk=((lane>>4)<<3)|j;
        float w=ldin(w4,(size_t)(mt*16+m)*128 + kt*32+kk, md);
        unsigned short hi=f2bf(w);
        u4h[i]=hi; u4l[i]=f2bf(w-bf2f(hi));
    }
    if(i<968)   F[4+i]=0.f;
    if(i<16896) F[F_P+i]=0.f;   // 16-slot partials
    if(i<32){ F[F_G1+i]=ldin(g1,i,md); F[F_BE1+i]=ldin(be1,i,md); }
    if(i<64){ F[F_G2+i]=ldin(g2,i,md); F[F_BE2+i]=ldin(be2,i,md); }
    if(i<128){ F[F_G3+i]=ldin(g3,i,md); F[F_BE3+i]=ldin(be3,i,md); }
    if(i<256){ F[F_G4+i]=ldin(g4,i,md); F[F_BE4+i]=ldin(be4,i,md); }
}

// ---- shared feature computation: r[8]; lane groups of 32 = one (b,s) ----
__device__ inline void rif_compute(const float* __restrict__ ctr,const float* __restrict__ loa,
                                   int b,int s,int k,float r[8])
{
    int idx=sidx(s);
    int gi=(idx-16+k)&(NPTS-1);
    size_t cb=((size_t)b*NPTS+gi)*3;
    float px=ctr[cb],py=ctr[cb+1],pz=ctr[cb+2];
    float lx=loa[cb],ly=loa[cb+1],lz=loa[cb+2];
    float sx=__shfl(px,16,32),sy=__shfl(py,16,32),sz=__shfl(pz,16,32);
    float ax=__shfl(lx,16,32),ay=__shfl(ly,16,32),az=__shfl(lz,16,32);
    float vx=px-sx,vy=py-sy,vz=pz-sz;
    float sq=vx*vx+vy*vy+vz*vz;
    float d1=sq>0.f?sqrtf(sq):0.f;
    float inv=d1>0.f?1.f/d1:0.f;
    float ux=vx*inv,uy=vy*inv,uz=vz*inv;
    float a1=ux*ax+uy*ay+uz*az;
    float a2=ux*lx+uy*ly+uz*lz;
    float a3=acosf(clipf(lx*ax+ly*ay+lz*az));
    int src=(k+31)&31;
    float pvx=__shfl(vx,src,32),pvy=__shfl(vy,src,32),pvz=__shfl(vz,src,32);
    float plx=__shfl(lx,src,32),ply=__shfl(ly,src,32),plz=__shfl(lz,src,32);
    float pux=__shfl(ux,src,32),puy=__shfl(uy,src,32),puz=__shfl(uz,src,32);
    float ivx=vx-pvx,ivy=vy-pvy,ivz=vz-pvz;
    float isq=ivx*ivx+ivy*ivy+ivz*ivz;
    float idn=isq>0.f?1.f/sqrtf(isq):0.f;
    float iux=ivx*idn,iuy=ivy*idn,iuz=ivz*idn;
    float a4=iux*lx+iuy*ly+iuz*lz;
    float a5=iux*plx+iuy*ply+iuz*plz;
    float a6=acosf(clipf(lx*plx+ly*ply+lz*plz));
    float d2=acosf(clipf(ux*pux+uy*puy+uz*puz));
    r[0]=d1;r[1]=d2;r[2]=a1;r[3]=a2;r[4]=a3;r[5]=a4;r[6]=a5;r[7]=a6;
}

// ---- features: rif moments (analytic BN1) ----
__global__ __launch_bounds__(256) void k_features(
    const float* __restrict__ ctrf,const float* __restrict__ loaf,
    float* __restrict__ mom1,float* __restrict__ mom2)
{
    __shared__ float sm1[8],sm2[64];
    int t=threadIdx.x;
    if(t<8)sm1[t]=0.f;
    if(t<64)sm2[t]=0.f;
    __syncthreads();
    int lane=t&63,k=t&31;
    int q=blockIdx.x*256+t;
    int pos=q>>5,b=pos>>11,s=pos&2047;
    float r[8];
    rif_compute(ctrf,loaf,b,s,k,r);
#pragma unroll
    for(int i=0;i<8;i++){ float sv=wredsum(r[i]); if(lane==0)atomicAdd(&sm1[i],sv); }
#pragma unroll
    for(int i=0;i<8;i++)
#pragma unroll
        for(int j=i;j<8;j++){ float sv=wredsum(r[i]*r[j]); if(lane==0)atomicAdd(&sm2[i*8+j],sv); }
    __syncthreads();
    if(t<8)atomicAdd(&mom1[t],sm1[t]);
    if(t<64)atomicAdd(&mom2[t],sm2[t]);
}

// ---- analytic BN1 ----
__global__ void k_bn1(float* F){
    int o=threadIdx.x;
    if(o>=32)return;
    const float invP=1.0f/(float)QTOT;
    float m[8],w[8];
#pragma unroll
    for(int c=0;c<8;c++){ m[c]=F[F_MOM1+c]*invP; w[c]=F[F_WF1+o*8+c]; }
    float Ey=0.f;
#pragma unroll
    for(int c=0;c<8;c++) Ey+=w[c]*m[c];
    float Eyy=0.f;
#pragma unroll
    for(int i=0;i<8;i++)
#pragma unroll
        for(int j=0;j<8;j++){
            int a=i<j?i:j,bb=i<j?j:i;
            Eyy+=w[i]*w[j]*F[F_MOM2+a*8+bb]*invP;
        }
    float var=fmaxf(Eyy-Ey*Ey,0.f);
    float sc=F[F_G1+o]/sqrtf(var+1e-5f);
    F[F_SC1+o]=sc;
    F[F_SH1+o]=F[F_BE1+o]-Ey*sc;
}

// ---- generic BN finalize ----
__global__ void k_bnd(float* F,int C,int sumO,int ssqO,int gO,int beO,int scO,int shO){
    int o=threadIdx.x;
    if(o>=C)return;
    const float invP=1.0f/(float)QTOT;
    float mean=F[sumO+o]*invP;
    float var=fmaxf(F[ssqO+o]*invP-mean*mean,0.f);
    float s=F[gO+o]/sqrtf(var+1e-5f);
    F[scO+o]=s;
    F[shO+o]=F[beO+o]-mean*s;
}

// ---- stats2m: accumulate M1 = sum h1, M2 = sum h1 h1^T via MFMA ----
#define S2T 264
__global__ __launch_bounds__(256) void k_stats2m(
    const float* __restrict__ ctrf,const float* __restrict__ loaf,
    const float* __restrict__ F,float* __restrict__ P)
{
    __shared__ unsigned short TH[32*S2T];
    __shared__ unsigned short TL[32*S2T];
    int t=threadIdx.x, wv=t>>6, lane=t&63;
    int quad=lane>>4, col=lane&15;
    int mi=wv>>1, ni=wv&1;           // wave's M2 quadrant
    float acc8[8];                   // M1 partials: wave wv owns ch 8wv..8wv+7
#pragma unroll
    for(int k=0;k<8;k++) acc8[k]=0.f;
    f4v Z; Z[0]=0.f;Z[1]=0.f;Z[2]=0.f;Z[3]=0.f;
    f4v C0=Z, C1=Z;
    const float* wf1=F+F_WF1;
    const float* sc1=F+F_SC1; const float* sh1=F+F_SH1;
    for(int tt=0;tt<2;++tt){
        int tile=blockIdx.x*2+tt;                 // 0..2047
        int pos=tile*8 + wv*2 + (lane>>5);        // (b,s) index
        int b=pos>>11, s=pos&2047;
        float r[8]; rif_compute(ctrf,loaf,b,s,lane&31,r);
        int mypos=wv*64+lane;                     // 0..255 within tile
#pragma unroll
        for(int c=0;c<32;c++){                    // fused h1: no h1[32] array
            const float* w=wf1+c*8;
            float y=w[0]*r[0]+w[1]*r[1]+w[2]*r[2]+w[3]*r[3]
                   +w[4]*r[4]+w[5]*r[5]+w[6]*r[6]+w[7]*r[7];
            float h=fmaxf(y*sc1[c]+sh1[c],0.f);
            unsigned short hi=f2bf(h);
            TH[c*S2T+mypos]=hi;
            TL[c*S2T+mypos]=f2bf(h-bf2f(hi));
        }
        __syncthreads();
#pragma unroll
        for(int kt=0;kt<8;kt++){
            s8v AH=*(const s8v*)(TH+(mi*16+col)*S2T + kt*32 + quad*8);
            s8v AL=*(const s8v*)(TL+(mi*16+col)*S2T + kt*32 + quad*8);
            s8v BH=*(const s8v*)(TH+(ni*16+col)*S2T + kt*32 + quad*8);
            s8v BL=*(const s8v*)(TL+(ni*16+col)*S2T + kt*32 + quad*8);
            if(kt&1){
                C1=MFMA(AH,BH,C1); C1=MFMA(AH,BL,C1); C1=MFMA(AL,BH,C1);
            }else{
                C0=MFMA(AH,BH,C0); C0=MFMA(AH,BL,C0); C0=MFMA(AL,BH,C0);
            }
        }
        // M1 from LDS: lane covers pos lane*4..lane*4+3 of each owned channel
#pragma unroll
        for(int k=0;k<8;k++){
            int c=wv*8+k;
            const unsigned short* ph=TH+c*S2T+lane*4;
            const unsigned short* pl=TL+c*S2T+lane*4;
            acc8[k]+=bf2f(ph[0])+bf2f(ph[1])+bf2f(ph[2])+bf2f(ph[3])
                    +bf2f(pl[0])+bf2f(pl[1])+bf2f(pl[2])+bf2f(pl[3]);
        }
        __syncthreads();
    }
    // flush to partial slot (slot = blk & 15): P[slot][0..31]=M1, [32..1055]=M2
    float* Ps=P+(size_t)(blockIdx.x&15)*1056;
#pragma unroll
    for(int rg=0;rg<4;rg++){
        float v=C0[rg]+C1[rg];
        atomicAdd(&Ps[32+(mi*16+quad*4+rg)*32 + ni*16+col], v);
    }
#pragma unroll
    for(int k=0;k<8;k++){
        float sv=wredsum(acc8[k]);
        if(lane==0) atomicAdd(&Ps[wv*8+k],sv);
    }
}

// ---- fold 16 partial slots into F_M1/F_M2, then analytic BN2 (merged) ----
__global__ void k_red(float* F){
    int t=threadIdx.x;   // 1 block x 256 threads
    for(int e=t;e<1056;e+=256){
        float s=0.f;
#pragma unroll
        for(int k=0;k<16;k++) s+=F[F_P+k*1056+e];
        if(e<32) F[F_M1+e]=s; else F[F_M2+e-32]=s;
    }
    __syncthreads();
    int o=t;
    if(o<64){
        const float invP=1.0f/(float)QTOT;
        const float* w=F+F_WF2+o*32;
        const float* M2=F+F_M2;
        float Ey=0.f;
#pragma unroll
        for(int c=0;c<32;c++) Ey+=w[c]*F[F_M1+c];
        Ey*=invP;
        float Eyy=0.f;
        for(int c1=0;c1<32;c1++){
            float acc=0.f;
#pragma unroll
            for(int c2=0;c2<32;c2++) acc+=w[c2]*M2[c1*32+c2];
            Eyy+=w[c1]*acc;
        }
        Eyy*=invP;
        float var=fmaxf(Eyy-Ey*Ey,0.f);
        float s=F[F_G2+o]/sqrtf(var+1e-5f);
        F[F_SC2+o]=s;
        F[F_SH2+o]=F[F_BE2+o]-Ey*s;
    }
}

// =====================================================================
// MFMA tile kernels, 512-thread (8-wave). Tile = 64 positions (2 s).
// A-fragments are loaded into registers BEFORE a __syncthreads so the
// compiler cannot sink them into the MFMA loop (round-7: VGPR=44 build
// serialized A-loads -> ~200cy L2 latency exposed per kt step; round-8
// macro version spilled via runtime-indexed arrays -> all loops now
// carry _Pragma unroll). __launch_bounds__(512,4) caps VGPR at 128.
// Per-accumulator MFMA order unchanged -> bit-identical output.
// =====================================================================
#define XST 136   // ushort row stride (16B-aligned rows)

__device__ inline void build_x2_8(
    const float* __restrict__ ctrf,const float* __restrict__ loaf,
    const void* __restrict__ fm,const float* __restrict__ F,
    const unsigned short* __restrict__ u2h,const unsigned short* __restrict__ u2l,
    int md,int b,int s0,int wv,int lane,
    unsigned short* XH,unsigned short* XL)
{
    int quad=lane>>4, col=lane&15;
    if(wv<4){
        // rif + h1, 8 channels per wave (waves 0-3)
        float r8[8]; rif_compute(ctrf,loaf,b,s0+(lane>>5),lane&31,r8);
        const float* wf1=F+F_WF1;
        const float* sc1=F+F_SC1; const float* sh1=F+F_SH1;
        s8v vh,vl;
#pragma unroll
        for(int j=0;j<8;j++){
            int o=8*wv+j;
            const float* w=wf1+o*8;
            float y=w[0]*r8[0]+w[1]*r8[1]+w[2]*r8[2]+w[3]*r8[3]
                   +w[4]*r8[4]+w[5]*r8[5]+w[6]*r8[6]+w[7]*r8[7];
            float h=fmaxf(y*sc1[o]+sh1[o],0.f);
            unsigned short hi=f2bf(h);
            vh[j]=(short)hi;
            vl[j]=(short)f2bf(h-bf2f(hi));
        }
        *(s8v*)(XH + lane*XST + 8*wv)=vh;
        *(s8v*)(XL + lane*XST + 8*wv)=vl;
    }else{
        // fm gather, 16 d per wave (waves 4-7)
        int dbase=16*(wv-4);
        int s=s0+(lane>>5), k=lane&31;
        int gi=(sidx(s)-16+k)&(NPTS-1);
        size_t fb=(size_t)b*64*NPTS+gi;
#pragma unroll
        for(int g=0;g<2;g++){
            s8v vh,vl;
#pragma unroll
            for(int j=0;j<8;j++){
                int d=dbase+g*8+j;
                float v = md ? ((const float*)fm)[fb+(size_t)d*NPTS]
                             : bf2f(((const unsigned short*)fm)[fb+(size_t)d*NPTS]);
                unsigned short hi=f2bf(v);
                vh[j]=(short)hi;
                vl[j]=(short)f2bf(v-bf2f(hi));
            }
            *(s8v*)(XH + lane*XST + 64 + dbase + g*8)=vh;
            *(s8v*)(XL + lane*XST + 64 + dbase + g*8)=vl;
        }
    }
    __syncthreads();   // h1 (cols 0..31) + fm (cols 64..127) visible
    // ---- conv2 via MFMA: wave -> (ch-group cg, nt-pair nb) ----
    int cg=wv>>1, nb=(wv&1)*2;
    s8v AH=*(const s8v*)(u2h+(cg*64+lane)*8);
    s8v AL=*(const s8v*)(u2l+(cg*64+lane)*8);
    s8v BH0=*(const s8v*)(XH+((nb  )*16+col)*XST+quad*8);
    s8v BL0=*(const s8v*)(XL+((nb  )*16+col)*XST+quad*8);
    s8v BH1=*(const s8v*)(XH+((nb+1)*16+col)*XST+quad*8);
    s8v BL1=*(const s8v*)(XL+((nb+1)*16+col)*XST+quad*8);
    f4v Z; Z[0]=0.f;Z[1]=0.f;Z[2]=0.f;Z[3]=0.f;
    f4v c0=MFMA(AH,BH0,Z), c1=MFMA(AH,BH1,Z);
    c0=MFMA(AH,BL0,c0); c1=MFMA(AH,BL1,c1);
    c0=MFMA(AL,BH0,c0); c1=MFMA(AL,BH1,c1);
    __syncthreads();   // all h1 reads done before cols 0..63 overwritten
    // ---- BN2 + relu, write split h2 to cols 0..63 ----
    const float* sc2=F+F_SC2; const float* sh2=F+F_SH2;
    int chb=cg*16+quad*4;
    float g0=sc2[chb],g1=sc2[chb+1],g2=sc2[chb+2],g3=sc2[chb+3];
    float b0=sh2[chb],b1=sh2[chb+1],b2=sh2[chb+2],b3=sh2[chb+3];
#pragma unroll
    for(int i=0;i<2;i++){
        f4v c = i? c1 : c0;
        int p=(nb+i)*16+col;
        float v0=fmaxf(c[0]*g0+b0,0.f);
        float v1=fmaxf(c[1]*g1+b1,0.f);
        float v2=fmaxf(c[2]*g2+b2,0.f);
        float v3=fmaxf(c[3]*g3+b3,0.f);
        unsigned short h0=f2bf(v0),h1=f2bf(v1),h2=f2bf(v2),h3=f2bf(v3);
        s4v vh,vl;
        vh[0]=(short)h0; vh[1]=(short)h1; vh[2]=(short)h2; vh[3]=(short)h3;
        vl[0]=(short)f2bf(v0-bf2f(h0)); vl[1]=(short)f2bf(v1-bf2f(h1));
        vl[2]=(short)f2bf(v2-bf2f(h2)); vl[3]=(short)f2bf(v3-bf2f(h3));
        *(s4v*)(XH + p*XST + chb)=vh;
        *(s4v*)(XL + p*XST + chb)=vl;
    }
    // caller's __syncthreads() completes the tile
}

// ---- A-fragment preload (issued before a barrier; cannot sink past it) ----
#define G1_LOADA(UH,UL) \
    s8v A1h[4],A1l[4]; \
    _Pragma("unroll") \
    for(int kt=0;kt<4;kt++){ \
        A1h[kt]=*(const s8v*)((UH)+((wv*4+kt)*64+lane)*8); \
        A1l[kt]=*(const s8v*)((UL)+((wv*4+kt)*64+lane)*8); \
    }

// GEMM1 (512t): wave wv owns mt=wv; consumes preloaded A1h/A1l
#define G1_STEP8 \
    _Pragma("unroll") \
    for(int kt=0;kt<4;kt++){ \
        s8v BH[4],BL[4]; \
        _Pragma("unroll") \
        for(int nt=0;nt<4;nt++){ \
            int boff=(nt*16+col)*XST + kt*32 + quad*8; \
            BH[nt]=*(const s8v*)(XH+boff); \
            BL[nt]=*(const s8v*)(XL+boff); \
        } \
        _Pragma("unroll") \
        for(int nt=0;nt<4;nt++) C[nt]=MFMA(A1h[kt],BH[nt],C[nt]); \
        _Pragma("unroll") \
        for(int nt=0;nt<4;nt++) C[nt]=MFMA(A1h[kt],BL[nt],C[nt]); \
        _Pragma("unroll") \
        for(int nt=0;nt<4;nt++) C[nt]=MFMA(A1l[kt],BH[nt],C[nt]); \
    }

#define G2_LOADA(UH,UL,MI) \
    _Pragma("unroll") \
    for(int kt=0;kt<4;kt++){ \
        A2h[kt]=*(const s8v*)((UH)+(((2*wv+(MI))*4+kt)*64+lane)*8); \
        A2l[kt]=*(const s8v*)((UL)+(((2*wv+(MI))*4+kt)*64+lane)*8); \
    }

#define G2_MFMA(MI) \
    _Pragma("unroll") \
    for(int kt=0;kt<4;kt++){ \
        s8v BH[4],BL[4]; \
        _Pragma("unroll") \
        for(int nt=0;nt<4;nt++){ \
            int boff=(nt*16+col)*XST + kt*32 + quad*8; \
            BH[nt]=*(const s8v*)(XH+boff); \
            BL[nt]=*(const s8v*)(XL+boff); \
        } \
        _Pragma("unroll") \
        for(int nt=0;nt<4;nt++) C2[MI][nt]=MFMA(A2h[kt],BH[nt],C2[MI][nt]); \
        _Pragma("unroll") \
        for(int nt=0;nt<4;nt++) C2[MI][nt]=MFMA(A2h[kt],BL[nt],C2[MI][nt]); \
        _Pragma("unroll") \
        for(int nt=0;nt<4;nt++) C2[MI][nt]=MFMA(A2l[kt],BH[nt],C2[MI][nt]); \
    }

// ---- stats3: x2 tile -> GEMM1 (W3) -> sum/ssq of y3; exports h2 tile ----
__global__ __launch_bounds__(512,4) void k_stats3(
    const float* __restrict__ ctrf,const float* __restrict__ loaf,
    const void* __restrict__ fm,const float* __restrict__ F,
    const unsigned short* __restrict__ u2h,const unsigned short* __restrict__ u2l,
    const unsigned short* __restrict__ u3h,const unsigned short* __restrict__ u3l,
    unsigned short* __restrict__ h2h,unsigned short* __restrict__ h2l,
    float* __restrict__ sum3,float* __restrict__ ssq3)
{
    __shared__ unsigned short XH[64*XST];
    __shared__ unsigned short XL[64*XST];
    __shared__ float as_[128],qs_[128];
    int t=threadIdx.x, wv=t>>6, lane=t&63;
    if(t<128){as_[t]=0.f;qs_[t]=0.f;}
    int md=((const int*)F)[0];
    int pos0=blockIdx.x*2, b=pos0>>11, s0=pos0&2047;
    G1_LOADA(u3h,u3l)                       // issued before build's barriers
    build_x2_8(ctrf,loaf,fm,F,u2h,u2l,md,b,s0,wv,lane,XH,XL);
    __syncthreads();
    int quad=lane>>4, col=lane&15;
    f4v Z; Z[0]=0.f;Z[1]=0.f;Z[2]=0.f;Z[3]=0.f;
    f4v C[4];
#pragma unroll
    for(int nt=0;nt<4;nt++) C[nt]=Z;
    G1_STEP8
    // ---- tier1 export: h2 tile (cols 0..63) bit-exact to global ----
    if(h2h){
        int pos=t>>3, off=((t&7)^(pos&7))*8;    // XOR chunk swizzle, bijective per pos
        size_t go=(size_t)blockIdx.x*4096 + (size_t)pos*64 + off;
        *(s8v*)(h2h+go)=*(const s8v*)(XH+pos*XST+off);
        *(s8v*)(h2l+go)=*(const s8v*)(XL+pos*XST+off);
    }
#pragma unroll
    for(int rg=0;rg<4;rg++){
        float sm=0.f,sq=0.f;
#pragma unroll
        for(int nt=0;nt<4;nt++){ float v=C[nt][rg]; sm+=v; sq+=v*v; }
        sm+=__shfl_xor(sm,1); sq+=__shfl_xor(sq,1);
        sm+=__shfl_xor(sm,2); sq+=__shfl_xor(sq,2);
        sm+=__shfl_xor(sm,4); sq+=__shfl_xor(sq,4);
        sm+=__shfl_xor(sm,8); sq+=__shfl_xor(sq,8);
        if(col==0){
            int ch=wv*16+quad*4+rg;
            atomicAdd(&as_[ch],sm); atomicAdd(&qs_[ch],sq);
        }
    }
    __syncthreads();
    if(t<128){atomicAdd(&sum3[t],as_[t]);atomicAdd(&ssq3[t],qs_[t]);}
}

// ---- conv4 H2 (tier1): reload h2, regather fm, GEMM1->BN3->GEMM2 ----
__global__ __launch_bounds__(512,4) void k_conv4h(
    const void* __restrict__ fm,const float* __restrict__ F,
    const unsigned short* __restrict__ u3h,const unsigned short* __restrict__ u3l,
    const unsigned short* __restrict__ u4h,const unsigned short* __restrict__ u4l,
    const unsigned short* __restrict__ h2h,const unsigned short* __restrict__ h2l,
    float* __restrict__ maxb,float* __restrict__ sum4,float* __restrict__ ssq4)
{
    __shared__ unsigned short XH[64*XST];
    __shared__ unsigned short XL[64*XST];
    __shared__ float as_[256],qs_[256];
    int t=threadIdx.x, wv=t>>6, lane=t&63;
    if(t<256){as_[t]=0.f; qs_[t]=0.f;}
    int md=((const int*)F)[0];
    int pos0=blockIdx.x*2, b=pos0>>11, s0=pos0&2047;
    G1_LOADA(u3h,u3l)                       // issued before the x2 barrier
    // ---- h2 import (matches export layout: global[pos][j]=lds[pos][j]) ----
    {
        int pos=t>>3, off=((t&7)^(pos&7))*8;
        size_t go=(size_t)blockIdx.x*4096 + (size_t)pos*64 + off;
        *(s8v*)(XH+pos*XST+off)=*(const s8v*)(h2h+go);
        *(s8v*)(XL+pos*XST+off)=*(const s8v*)(h2l+go);
    }
    // ---- fm gather: wave wv covers d [8wv, 8wv+8) ----
    {
        int dbase=8*wv;
        int s=s0+(lane>>5), k=lane&31;
        int gi=(sidx(s)-16+k)&(NPTS-1);
        size_t fb=(size_t)b*64*NPTS+gi;
        s8v vh,vl;
#pragma unroll
        for(int j=0;j<8;j++){
            int d=dbase+j;
            float v = md ? ((const float*)fm)[fb+(size_t)d*NPTS]
                         : bf2f(((const unsigned short*)fm)[fb+(size_t)d*NPTS]);
            unsigned short hi=f2bf(v);
            vh[j]=(short)hi;
            vl[j]=(short)f2bf(v-bf2f(hi));
        }
        *(s8v*)(XH + lane*XST + 64 + dbase)=vh;
        *(s8v*)(XL + lane*XST + 64 + dbase)=vl;
    }
    __syncthreads();   // x2 tile complete
    int quad=lane>>4, col=lane&15;
    // ---- GEMM1: C[4], mt=wv ----
    f4v Z; Z[0]=0.f;Z[1]=0.f;Z[2]=0.f;Z[3]=0.f;
    f4v C[4];
#pragma unroll
    for(int nt=0;nt<4;nt++) C[nt]=Z;
    G1_STEP8
    __syncthreads();   // all waves done reading x2
    // ---- BN3 + relu -> h3 split; preload G2 mi=0 A-frags under it ----
    s8v A2h[4],A2l[4];
    G2_LOADA(u4h,u4l,0)
    const float* sc3=F+F_SC3; const float* sh3=F+F_SH3;
    {
        int chb=wv*16+quad*4;
#pragma unroll
        for(int nt=0;nt<4;nt++){
            int p=nt*16+col;
            s4v vh,vl;
#pragma unroll
            for(int rg=0;rg<4;rg++){
                float v=C[nt][rg];
                v=fmaxf(v*sc3[chb+rg]+sh3[chb+rg],0.f);
                unsigned short hi=f2bf(v);
                vh[rg]=(short)hi;
                vl[rg]=(short)f2bf(v-bf2f(hi));
            }
            *(s4v*)(XH + p*XST + chb)=vh;
            *(s4v*)(XL + p*XST + chb)=vl;
        }
    }
    __syncthreads();   // h3 tile complete (A2 mi=0 already in regs)
    // ---- GEMM2: C2[2][4], mt=2wv..2wv+1 ----
    f4v C2[2][4];
#pragma unroll
    for(int mi=0;mi<2;mi++)
#pragma unroll
        for(int nt=0;nt<4;nt++) C2[mi][nt]=Z;
    G2_MFMA(0)
    G2_LOADA(u4h,u4l,1)
    G2_MFMA(1)
    // ---- epilogue ----
#pragma unroll
    for(int mi=0;mi<2;mi++){
        int mt=2*wv+mi;
#pragma unroll
        for(int rg=0;rg<4;rg++){
            float sm=0.f,sq=0.f,mx0=-3.4e38f,mx1=-3.4e38f;
#pragma unroll
            for(int nt=0;nt<4;nt++){
                float v=C2[mi][nt][rg];
                sm+=v; sq+=v*v;
                if(nt<2) mx0=fmaxf(mx0,v); else mx1=fmaxf(mx1,v);
            }
            sm+=__shfl_xor(sm,1); sq+=__shfl_xor(sq,1);
            sm+=__shfl_xor(sm,2); sq+=__shfl_xor(sq,2);
            sm+=__shfl_xor(sm,4); sq+=__shfl_xor(sq,4);
            sm+=__shfl_xor(sm,8); sq+=__shfl_xor(sq,8);
            mx0=fmaxf(mx0,__shfl_xor(mx0,1)); mx1=fmaxf(mx1,__shfl_xor(mx1,1));
            mx0=fmaxf(mx0,__shfl_xor(mx0,2)); mx1=fmaxf(mx1,__shfl_xor(mx1,2));
            mx0=fmaxf(mx0,__shfl_xor(mx0,4)); mx1=fmaxf(mx1,__shfl_xor(mx1,4));
            mx0=fmaxf(mx0,__shfl_xor(mx0,8)); mx1=fmaxf(mx1,__shfl_xor(mx1,8));
            if(col==0){
                int ch=mt*16+quad*4+rg;
                atomicAdd(&as_[ch],sm); atomicAdd(&qs_[ch],sq);
                size_t ob=((size_t)b*256+ch)*SSZ + s0;
                maxb[ob]=mx0; maxb[ob+1]=mx1;
            }
        }
    }
    __syncthreads();
    if(t<256){atomicAdd(&sum4[t],as_[t]);atomicAdd(&ssq4[t],qs_[t]);}
}

// ---- conv4 SLOW (fallback when ws too small): full rebuild, 512t ----
__global__ __launch_bounds__(512,4) void k_conv4(
    const float* __restrict__ ctrf,const float* __restrict__ loaf,
    const void* __restrict__ fm,const float* __restrict__ F,
    const unsigned short* __restrict__ u2h,const unsigned short* __restrict__ u2l,
    const unsigned short* __restrict__ u3h,const unsigned short* __restrict__ u3l,
    const unsigned short* __restrict__ u4h,const unsigned short* __restrict__ u4l,
    float* __restrict__ maxb,float* __restrict__ sum4,float* __restrict__ ssq4)
{
    __shared__ unsigned short XH[64*XST];
    __shared__ unsigned short XL[64*XST];
    __shared__ float as_[256],qs_[256];
    int t=threadIdx.x, wv=t>>6, lane=t&63;
    if(t<256){as_[t]=0.f; qs_[t]=0.f;}
    int md=((const int*)F)[0];
    int pos0=blockIdx.x*2, b=pos0>>11, s0=pos0&2047;
    G1_LOADA(u3h,u3l)
    build_x2_8(ctrf,loaf,fm,F,u2h,u2l,md,b,s0,wv,lane,XH,XL);
    __syncthreads();
    int quad=lane>>4, col=lane&15;
    f4v Z; Z[0]=0.f;Z[1]=0.f;Z[2]=0.f;Z[3]=0.f;
    f4v C[4];
#pragma unroll
    for(int nt=0;nt<4;nt++) C[nt]=Z;
    G1_STEP8
    __syncthreads();
    s8v A2h[4],A2l[4];
    G2_LOADA(u4h,u4l,0)
    const float* sc3=F+F_SC3; const float* sh3=F+F_SH3;
    {
        int chb=wv*16+quad*4;
#pragma unroll
        for(int nt=0;nt<4;nt++){
            int p=nt*16+col;
            s4v vh,vl;
#pragma unroll
            for(int rg=0;rg<4;rg++){
                float v=C[nt][rg];
                v=fmaxf(v*sc3[chb+rg]+sh3[chb+rg],0.f);
                unsigned short hi=f2bf(v);
                vh[rg]=(short)hi;
                vl[rg]=(short)f2bf(v-bf2f(hi));
            }
            *(s4v*)(XH + p*XST + chb)=vh;
            *(s4v*)(XL + p*XST + chb)=vl;
        }
    }
    __syncthreads();
    f4v C2[2][4];
#pragma unroll
    for(int mi=0;mi<2;mi++)
#pragma unroll
        for(int nt=0;nt<4;nt++) C2[mi][nt]=Z;
    G2_MFMA(0)
    G2_LOADA(u4h,u4l,1)
    G2_MFMA(1)
#pragma unroll
    for(int mi=0;mi<2;mi++){
        int mt=2*wv+mi;
#pragma unroll
        for(int rg=0;rg<4;rg++){
            float sm=0.f,sq=0.f,mx0=-3.4e38f,mx1=-3.4e38f;
#pragma unroll
            for(int nt=0;nt<4;nt++){
                float v=C2[mi][nt][rg];
                sm+=v; sq+=v*v;
                if(nt<2) mx0=fmaxf(mx0,v); else mx1=fmaxf(mx1,v);
            }
            sm+=__shfl_xor(sm,1); sq+=__shfl_xor(sq,1);
            sm+=__shfl_xor(sm,2); sq+=__shfl_xor(sq,2);
            sm+=__shfl_xor(sm,4); sq+=__shfl_xor(sq,4);
            sm+=__shfl_xor(sm,8); sq+=__shfl_xor(sq,8);
            mx0=fmaxf(mx0,__shfl_xor(mx0,1)); mx1=fmaxf(mx1,__shfl_xor(mx1,1));
            mx0=fmaxf(mx0,__shfl_xor(mx0,2)); mx1=fmaxf(mx1,__shfl_xor(mx1,2));
            mx0=fmaxf(mx0,__shfl_xor(mx0,4)); mx1=fmaxf(mx1,__shfl_xor(mx1,4));
            mx0=fmaxf(mx0,__shfl_xor(mx0,8)); mx1=fmaxf(mx1,__shfl_xor(mx1,8));
            if(col==0){
                int ch=mt*16+quad*4+rg;
                atomicAdd(&as_[ch],sm); atomicAdd(&qs_[ch],sq);
                size_t ob=((size_t)b*256+ch)*SSZ + s0;
                maxb[ob]=mx0; maxb[ob+1]=mx1;
            }
        }
    }
    __syncthreads();
    if(t<256){atomicAdd(&sum4[t],as_[t]);atomicAdd(&ssq4[t],qs_[t]);}
}

// ---- final: out2 = relu(BN4(K-max)) in place, f32 (gamma=1 => scale>0) ----
__global__ __launch_bounds__(256) void k_apply(
    const float* __restrict__ F,float* __restrict__ out)
{
    int e=blockIdx.x*256+threadIdx.x;      // 4194304 = B*256*S
    int j=(e>>11)&255;
    float sc=F[F_SC4+j],sh=F[F_SH4+j];
    float v=out[98304+e];
    out[98304+e]=fmaxf(v*sc+sh,0.f);
}

extern "C" void kernel_launch(void* const* d_in, const int* in_sizes, int n_in,
                              void* d_out, int out_size, void* d_ws, size_t ws_size,
                              hipStream_t stream)
{
    const void* contour=d_in[0];
    const void* loa    =d_in[1];
    const void* fm     =d_in[2];
    const void* w1 =d_in[3];  const void* g1 =d_in[5];  const void* be1=d_in[6];
    const void* w2 =d_in[7];  const void* g2 =d_in[9];  const void* be2=d_in[10];
    const void* w3 =d_in[11]; const void* g3 =d_in[13]; const void* be3=d_in[14];
    const void* w4 =d_in[15]; const void* g4 =d_in[17]; const void* be4=d_in[18];
    float* out=(float*)d_out;          // output buffer is float32

    float* F=(float*)d_ws;
    char* base=(char*)d_ws;
    float* ctrf=(float*)(base+CTR_OFF);
    float* loaf=(float*)(base+LOA_OFF);
    unsigned short* u3h=(unsigned short*)(base+U3H_OFF);
    unsigned short* u3l=(unsigned short*)(base+U3L_OFF);
    unsigned short* u4h=(unsigned short*)(base+U4H_OFF);
    unsigned short* u4l=(unsigned short*)(base+U4L_OFF);
    unsigned short* u2h=(unsigned short*)(base+U2H_OFF);
    unsigned short* u2l=(unsigned short*)(base+U2L_OFF);
    int tier = (ws_size >= WS_H2) ? 1 : 0;
    unsigned short* h2h = tier==1 ? (unsigned short*)(base+H2H_OFF) : (unsigned short*)0;
    unsigned short* h2l = tier==1 ? (unsigned short*)(base+H2L_OFF) : (unsigned short*)0;
    float* maxb=out+98304;             // out2 f32 region doubles as K-max scratch

    k_detect<<<1,256,0,stream>>>(contour,(int*)d_ws);
    k_out01<<<64,256,0,stream>>>(contour,loa,F,out);
    k_convert<<<768,256,0,stream>>>(contour,loa,w1,w2,w3,w4,g1,be1,g2,be2,g3,be3,g4,be4,
                                    F,ctrf,loaf,u2h,u2l,u3h,u3l,u4h,u4l);
    k_features<<<2048,256,0,stream>>>(ctrf,loaf,F+F_MOM1,F+F_MOM2);
    k_bn1<<<1,32,0,stream>>>(F);
    k_stats2m<<<1024,256,0,stream>>>(ctrf,loaf,F,F+F_P);
    k_red<<<1,256,0,stream>>>(F);
    k_stats3<<<8192,512,0,stream>>>(ctrf,loaf,fm,F,u2h,u2l,u3h,u3l,h2h,h2l,
                                    F+F_SUM3,F+F_SSQ3);
    k_bnd<<<1,256,0,stream>>>(F,128,F_SUM3,F_SSQ3,F_G3,F_BE3,F_SC3,F_SH3);
    if(tier==1){
        k_conv4h<<<8192,512,0,stream>>>(fm,F,u3h,u3l,u4h,u4l,h2h,h2l,maxb,F+F_SUM4,F+F_SSQ4);
    }else{
        k_conv4<<<8192,512,0,stream>>>(ctrf,loaf,fm,F,u2h,u2l,u3h,u3l,u4h,u4l,maxb,F+F_SUM4,F+F_SSQ4);
    }
    k_bnd<<<1,256,0,stream>>>(F,256,F_SUM4,F_SSQ4,F_G4,F_BE4,F_SC4,F_SH4);
    k_apply<<<16384,256,0,stream>>>(F,out);
}

// Round 10
// 860.559 us; speedup vs baseline: 1.0383x; 1.0336x over previous
//
#include <hip/hip_runtime.h>
#include <stdint.h>

#define NPTS 8192
#define SSZ  2048
#define QTOT (8*2048*32)   // 524288 positions (b,s,k)

// ---- float-index offsets within ws param region F ----
#define F_MOM1   4
#define F_MOM2   12
#define F_SC1    972
#define F_SH1    1004
#define F_SC2    1036
#define F_SH2    1100
#define F_SC3    1164
#define F_SH3    1292
#define F_SC4    1420
#define F_SH4    1676
#define F_WF1    1932
#define F_WF2    2188
#define F_SUM3   204
#define F_SSQ3   332
#define F_SUM4   460
#define F_SSQ4   716
#define F_G1     53388
#define F_BE1    53420
#define F_G2     53452
#define F_BE2    53516
#define F_G3     53580
#define F_BE3    53708
#define F_G4     53836
#define F_BE4    54092
// h1 moment results (BN2 analytic): M1[32] then M2[32*32]
#define F_M1     57344
#define F_M2     57376
// 16-slot partials for stats2m flush: P[16][1056] floats
#define F_P      60000
// byte offsets of big ws buffers
#define CTR_OFF  524288ull
#define LOA_OFF  1310720ull
#define U3H_OFF  2097152ull   // W3 A-frag packed, hi bf16 [16384]
#define U3L_OFF  2129920ull   // lo
#define U4H_OFF  2162688ull   // W4 A-frag packed, hi bf16 [32768]
#define U4L_OFF  2228224ull   // lo
#define U2H_OFF  2293760ull   // W2 A-frag packed, hi bf16 [2048]
#define U2L_OFF  2297856ull   // lo; ends 2301952
// tier-1 (h2 split, bit-exact): 8192 blocks x 8KB each buffer
#define H2H_OFF  2301952ull
#define H2L_OFF  (2301952ull + 67108864ull)
#define WS_H2    (2301952ull + 2ull*67108864ull)    // ~130.2 MiB

typedef __attribute__((ext_vector_type(8))) short s8v;   // 8 bf16 (4 VGPRs)
typedef __attribute__((ext_vector_type(4))) short s4v;   // 4 bf16 (b64)
typedef __attribute__((ext_vector_type(4))) float f4v;   // MFMA acc
typedef __attribute__((ext_vector_type(4))) float fl4;
#define MFMA(a,b,c) __builtin_amdgcn_mfma_f32_16x16x32_bf16(a,b,c,0,0,0)

__device__ inline float bf2f(unsigned short u){ return __uint_as_float(((uint32_t)u)<<16); }
__device__ inline unsigned short f2bf(float f){
    uint32_t x=__float_as_uint(f);
    return (unsigned short)((x + 0x7fffu + ((x>>16)&1u))>>16);
}
__device__ inline float clipf(float x){
    const float LO=(float)(-1.0+1e-7), HI=(float)(1.0-1e-7);
    return fminf(fmaxf(x,LO),HI);
}
__device__ inline float wredsum(float v){
#pragma unroll
    for(int m=1;m<64;m<<=1) v+=__shfl_xor(v,m,64);
    return v;
}
// mode: 0 = bf16 ushort storage, 1 = f32 storage
__device__ inline float ldin(const void* p,size_t i,int md){
    return md ? ((const float*)p)[i] : bf2f(((const unsigned short*)p)[i]);
}
// exact np.linspace(0,8191,2048)[s].astype(int32)
__device__ inline int sidx(int s){ return (s*8191)/2047; }

// ---- dtype probe ----
__global__ void k_detect(const void* contour,int* flag){
    __shared__ int he;
    if(threadIdx.x==0) he=0;
    __syncthreads();
    const unsigned short* u=(const unsigned short*)contour;
    int h=0;
    for(int i=threadIdx.x;i<4096;i+=256){
        unsigned short lo=u[2*i];
        if(((lo>>7)&0xFF)>=0x86) h++;
    }
    atomicAdd(&he,h);
    __syncthreads();
    if(threadIdx.x==0) *flag = (he>400) ? 1 : 0;
}

// ---- canonicalize inputs, pack W2/W3/W4 A-frags, write outputs 0/1 ----
__global__ __launch_bounds__(256) void k_convert(
    const void* ctr,const void* loa,
    const void* w1,const void* w2,const void* w3,const void* w4,
    const void* g1,const void* be1,const void* g2,const void* be2,
    const void* g3,const void* be3,const void* g4,const void* be4,
    float* F, float* ctrf, float* loaf,
    unsigned short* u2h, unsigned short* u2l,
    unsigned short* u3h, unsigned short* u3l,
    unsigned short* u4h, unsigned short* u4l,
    float* out)
{
    int md=((const int*)F)[0];
    int i = blockIdx.x*256+threadIdx.x;     // 768 blocks -> 196608
    ctrf[i]=ldin(ctr,i,md);
    loaf[i]=ldin(loa,i,md);
    if(i<16384){
        // outputs 0/1: sampled contour + LOA (f32)
        int b=i>>11, s=i&2047;
        int idx=sidx(s);
        size_t cb=((size_t)b*NPTS+idx)*3;
        size_t ob=(size_t)i*3;
        out[ob]        =ldin(ctr,cb  ,md);
        out[ob+1]      =ldin(ctr,cb+1,md);
        out[ob+2]      =ldin(ctr,cb+2,md);
        out[49152+ob]  =ldin(loa,cb  ,md);
        out[49152+ob+1]=ldin(loa,cb+1,md);
        out[49152+ob+2]=ldin(loa,cb+2,md);
    }
    if(i<256)  F[F_WF1+i]=ldin(w1,i,md);
    if(i<2048) F[F_WF2+i]=ldin(w2,i,md);
    if(i<2048){
        // W2 (64x32) A-frags, kt=0 only: mt 0..3
        int j=i&7, lane=(i>>3)&63, mt=i>>9;
        int m=lane&15, kk=((lane>>4)<<3)|j;
        float w=ldin(w2,(size_t)(mt*16+m)*32 + kk, md);
        unsigned short hi=f2bf(w);
        u2h[i]=hi; u2l[i]=f2bf(w-bf2f(hi));
    }
    if(i<16384){
        int j=i&7, lane=(i>>3)&63, kt=(i>>9)&3, mt=i>>11;
        int m=lane&15, kk=((lane>>4)<<3)|j;
        float w=ldin(w3,(size_t)(mt*16+m)*128 + kt*32+kk, md);
        unsigned short hi=f2bf(w);
        u3h[i]=hi; u3l[i]=f2bf(w-bf2f(hi));
    }
    if(i<32768){
        int j=i&7, lane=(i>>3)&63, kt=(i>>9)&3, mt=i>>11;   // mt 0..15
        int m=lane&15, kk=((lane>>4)<<3)|j;
        float w=ldin(w4,(size_t)(mt*16+m)*128 + kt*32+kk, md);
        unsigned short hi=f2bf(w);
        u4h[i]=hi; u4l[i]=f2bf(w-bf2f(hi));
    }
    if(i<968)   F[4+i]=0.f;
    if(i<16896) F[F_P+i]=0.f;   // 16-slot partials
    if(i<32){ F[F_G1+i]=ldin(g1,i,md); F[F_BE1+i]=ldin(be1,i,md); }
    if(i<64){ F[F_G2+i]=ldin(g2,i,md); F[F_BE2+i]=ldin(be2,i,md); }
    if(i<128){ F[F_G3+i]=ldin(g3,i,md); F[F_BE3+i]=ldin(be3,i,md); }
    if(i<256){ F[F_G4+i]=ldin(g4,i,md); F[F_BE4+i]=ldin(be4,i,md); }
}

// ---- shared feature computation: r[8]; lane groups of 32 = one (b,s) ----
__device__ inline void rif_compute(const float* __restrict__ ctr,const float* __restrict__ loa,
                                   int b,int s,int k,float r[8])
{
    int idx=sidx(s);
    int gi=(idx-16+k)&(NPTS-1);
    size_t cb=((size_t)b*NPTS+gi)*3;
    float px=ctr[cb],py=ctr[cb+1],pz=ctr[cb+2];
    float lx=loa[cb],ly=loa[cb+1],lz=loa[cb+2];
    float sx=__shfl(px,16,32),sy=__shfl(py,16,32),sz=__shfl(pz,16,32);
    float ax=__shfl(lx,16,32),ay=__shfl(ly,16,32),az=__shfl(lz,16,32);
    float vx=px-sx,vy=py-sy,vz=pz-sz;
    float sq=vx*vx+vy*vy+vz*vz;
    float d1=sq>0.f?sqrtf(sq):0.f;
    float inv=d1>0.f?1.f/d1:0.f;
    float ux=vx*inv,uy=vy*inv,uz=vz*inv;
    float a1=ux*ax+uy*ay+uz*az;
    float a2=ux*lx+uy*ly+uz*lz;
    float a3=acosf(clipf(lx*ax+ly*ay+lz*az));
    int src=(k+31)&31;
    float pvx=__shfl(vx,src,32),pvy=__shfl(vy,src,32),pvz=__shfl(vz,src,32);
    float plx=__shfl(lx,src,32),ply=__shfl(ly,src,32),plz=__shfl(lz,src,32);
    float pux=__shfl(ux,src,32),puy=__shfl(uy,src,32),puz=__shfl(uz,src,32);
    float ivx=vx-pvx,ivy=vy-pvy,ivz=vz-pvz;
    float isq=ivx*ivx+ivy*ivy+ivz*ivz;
    float idn=isq>0.f?1.f/sqrtf(isq):0.f;
    float iux=ivx*idn,iuy=ivy*idn,iuz=ivz*idn;
    float a4=iux*lx+iuy*ly+iuz*lz;
    float a5=iux*plx+iuy*ply+iuz*plz;
    float a6=acosf(clipf(lx*plx+ly*ply+lz*plz));
    float d2=acosf(clipf(ux*pux+uy*puy+uz*puz));
    r[0]=d1;r[1]=d2;r[2]=a1;r[3]=a2;r[4]=a3;r[5]=a4;r[6]=a5;r[7]=a6;
}

// ---- features: rif moments (analytic BN1) ----
__global__ __launch_bounds__(256) void k_features(
    const float* __restrict__ ctrf,const float* __restrict__ loaf,
    float* __restrict__ mom1,float* __restrict__ mom2)
{
    __shared__ float sm1[8],sm2[64];
    int t=threadIdx.x;
    if(t<8)sm1[t]=0.f;
    if(t<64)sm2[t]=0.f;
    __syncthreads();
    int lane=t&63,k=t&31;
    int q=blockIdx.x*256+t;
    int pos=q>>5,b=pos>>11,s=pos&2047;
    float r[8];
    rif_compute(ctrf,loaf,b,s,k,r);
#pragma unroll
    for(int i=0;i<8;i++){ float sv=wredsum(r[i]); if(lane==0)atomicAdd(&sm1[i],sv); }
#pragma unroll
    for(int i=0;i<8;i++)
#pragma unroll
        for(int j=i;j<8;j++){ float sv=wredsum(r[i]*r[j]); if(lane==0)atomicAdd(&sm2[i*8+j],sv); }
    __syncthreads();
    if(t<8)atomicAdd(&mom1[t],sm1[t]);
    if(t<64)atomicAdd(&mom2[t],sm2[t]);
}

// ---- analytic BN1 ----
__global__ void k_bn1(float* F){
    int o=threadIdx.x;
    if(o>=32)return;
    const float invP=1.0f/(float)QTOT;
    float m[8],w[8];
#pragma unroll
    for(int c=0;c<8;c++){ m[c]=F[F_MOM1+c]*invP; w[c]=F[F_WF1+o*8+c]; }
    float Ey=0.f;
#pragma unroll
    for(int c=0;c<8;c++) Ey+=w[c]*m[c];
    float Eyy=0.f;
#pragma unroll
    for(int i=0;i<8;i++)
#pragma unroll
        for(int j=0;j<8;j++){
            int a=i<j?i:j,bb=i<j?j:i;
            Eyy+=w[i]*w[j]*F[F_MOM2+a*8+bb]*invP;
        }
    float var=fmaxf(Eyy-Ey*Ey,0.f);
    float sc=F[F_G1+o]/sqrtf(var+1e-5f);
    F[F_SC1+o]=sc;
    F[F_SH1+o]=F[F_BE1+o]-Ey*sc;
}

// ---- generic BN finalize ----
__global__ void k_bnd(float* F,int C,int sumO,int ssqO,int gO,int beO,int scO,int shO){
    int o=threadIdx.x;
    if(o>=C)return;
    const float invP=1.0f/(float)QTOT;
    float mean=F[sumO+o]*invP;
    float var=fmaxf(F[ssqO+o]*invP-mean*mean,0.f);
    float s=F[gO+o]/sqrtf(var+1e-5f);
    F[scO+o]=s;
    F[shO+o]=F[beO+o]-mean*s;
}

// ---- stats2m: accumulate M1 = sum h1, M2 = sum h1 h1^T via MFMA ----
#define S2T 264
__global__ __launch_bounds__(256) void k_stats2m(
    const float* __restrict__ ctrf,const float* __restrict__ loaf,
    const float* __restrict__ F,float* __restrict__ P)
{
    __shared__ unsigned short TH[32*S2T];
    __shared__ unsigned short TL[32*S2T];
    int t=threadIdx.x, wv=t>>6, lane=t&63;
    int quad=lane>>4, col=lane&15;
    int mi=wv>>1, ni=wv&1;           // wave's M2 quadrant
    float acc8[8];                   // M1 partials: wave wv owns ch 8wv..8wv+7
#pragma unroll
    for(int k=0;k<8;k++) acc8[k]=0.f;
    f4v Z; Z[0]=0.f;Z[1]=0.f;Z[2]=0.f;Z[3]=0.f;
    f4v C0=Z, C1=Z;
    const float* wf1=F+F_WF1;
    const float* sc1=F+F_SC1; const float* sh1=F+F_SH1;
    for(int tt=0;tt<2;++tt){
        int tile=blockIdx.x*2+tt;                 // 0..2047
        int pos=tile*8 + wv*2 + (lane>>5);        // (b,s) index
        int b=pos>>11, s=pos&2047;
        float r[8]; rif_compute(ctrf,loaf,b,s,lane&31,r);
        int mypos=wv*64+lane;                     // 0..255 within tile
#pragma unroll
        for(int c=0;c<32;c++){                    // fused h1: no h1[32] array
            const float* w=wf1+c*8;
            float y=w[0]*r[0]+w[1]*r[1]+w[2]*r[2]+w[3]*r[3]
                   +w[4]*r[4]+w[5]*r[5]+w[6]*r[6]+w[7]*r[7];
            float h=fmaxf(y*sc1[c]+sh1[c],0.f);
            unsigned short hi=f2bf(h);
            TH[c*S2T+mypos]=hi;
            TL[c*S2T+mypos]=f2bf(h-bf2f(hi));
        }
        __syncthreads();
#pragma unroll
        for(int kt=0;kt<8;kt++){
            s8v AH=*(const s8v*)(TH+(mi*16+col)*S2T + kt*32 + quad*8);
            s8v AL=*(const s8v*)(TL+(mi*16+col)*S2T + kt*32 + quad*8);
            s8v BH=*(const s8v*)(TH+(ni*16+col)*S2T + kt*32 + quad*8);
            s8v BL=*(const s8v*)(TL+(ni*16+col)*S2T + kt*32 + quad*8);
            if(kt&1){
                C1=MFMA(AH,BH,C1); C1=MFMA(AH,BL,C1); C1=MFMA(AL,BH,C1);
            }else{
                C0=MFMA(AH,BH,C0); C0=MFMA(AH,BL,C0); C0=MFMA(AL,BH,C0);
            }
        }
        // M1 from LDS: lane covers pos lane*4..lane*4+3 of each owned channel
#pragma unroll
        for(int k=0;k<8;k++){
            int c=wv*8+k;
            const unsigned short* ph=TH+c*S2T+lane*4;
            const unsigned short* pl=TL+c*S2T+lane*4;
            acc8[k]+=bf2f(ph[0])+bf2f(ph[1])+bf2f(ph[2])+bf2f(ph[3])
                    +bf2f(pl[0])+bf2f(pl[1])+bf2f(pl[2])+bf2f(pl[3]);
        }
        __syncthreads();
    }
    // flush to partial slot (slot = blk & 15): P[slot][0..31]=M1, [32..1055]=M2
    float* Ps=P+(size_t)(blockIdx.x&15)*1056;
#pragma unroll
    for(int rg=0;rg<4;rg++){
        float v=C0[rg]+C1[rg];
        atomicAdd(&Ps[32+(mi*16+quad*4+rg)*32 + ni*16+col], v);
    }
#pragma unroll
    for(int k=0;k<8;k++){
        float sv=wredsum(acc8[k]);
        if(lane==0) atomicAdd(&Ps[wv*8+k],sv);
    }
}

// ---- fold 16 partial slots into F_M1/F_M2, then analytic BN2 (merged) ----
__global__ void k_red(float* F){
    int t=threadIdx.x;   // 1 block x 256 threads
    for(int e=t;e<1056;e+=256){
        float s=0.f;
#pragma unroll
        for(int k=0;k<16;k++) s+=F[F_P+k*1056+e];
        if(e<32) F[F_M1+e]=s; else F[F_M2+e-32]=s;
    }
    __syncthreads();
    int o=t;
    if(o<64){
        const float invP=1.0f/(float)QTOT;
        const float* w=F+F_WF2+o*32;
        const float* M2=F+F_M2;
        float Ey=0.f;
#pragma unroll
        for(int c=0;c<32;c++) Ey+=w[c]*F[F_M1+c];
        Ey*=invP;
        float Eyy=0.f;
        for(int c1=0;c1<32;c1++){
            float acc=0.f;
#pragma unroll
            for(int c2=0;c2<32;c2++) acc+=w[c2]*M2[c1*32+c2];
            Eyy+=w[c1]*acc;
        }
        Eyy*=invP;
        float var=fmaxf(Eyy-Ey*Ey,0.f);
        float s=F[F_G2+o]/sqrtf(var+1e-5f);
        F[F_SC2+o]=s;
        F[F_SH2+o]=F[F_BE2+o]-Ey*s;
    }
}

// =====================================================================
// MFMA tile kernels, 512-thread (8-wave) version (round-7 known-good:
// VGPR 44/60, no spill, conv4h 321us). Tile = 64 positions (2 s).
// =====================================================================
#define XST 136   // ushort row stride (16B-aligned rows)

__device__ inline void build_x2_8(
    const float* __restrict__ ctrf,const float* __restrict__ loaf,
    const void* __restrict__ fm,const float* __restrict__ F,
    const unsigned short* __restrict__ u2h,const unsigned short* __restrict__ u2l,
    int md,int b,int s0,int wv,int lane,
    unsigned short* XH,unsigned short* XL)
{
    int quad=lane>>4, col=lane&15;
    if(wv<4){
        // rif + h1, 8 channels per wave (waves 0-3)
        float r8[8]; rif_compute(ctrf,loaf,b,s0+(lane>>5),lane&31,r8);
        const float* wf1=F+F_WF1;
        const float* sc1=F+F_SC1; const float* sh1=F+F_SH1;
        s8v vh,vl;
#pragma unroll
        for(int j=0;j<8;j++){
            int o=8*wv+j;
            const float* w=wf1+o*8;
            float y=w[0]*r8[0]+w[1]*r8[1]+w[2]*r8[2]+w[3]*r8[3]
                   +w[4]*r8[4]+w[5]*r8[5]+w[6]*r8[6]+w[7]*r8[7];
            float h=fmaxf(y*sc1[o]+sh1[o],0.f);
            unsigned short hi=f2bf(h);
            vh[j]=(short)hi;
            vl[j]=(short)f2bf(h-bf2f(hi));
        }
        *(s8v*)(XH + lane*XST + 8*wv)=vh;
        *(s8v*)(XL + lane*XST + 8*wv)=vl;
    }else{
        // fm gather, 16 d per wave (waves 4-7)
        int dbase=16*(wv-4);
        int s=s0+(lane>>5), k=lane&31;
        int gi=(sidx(s)-16+k)&(NPTS-1);
        size_t fb=(size_t)b*64*NPTS+gi;
        for(int g=0;g<2;g++){
            s8v vh,vl;
#pragma unroll
            for(int j=0;j<8;j++){
                int d=dbase+g*8+j;
                float v = md ? ((const float*)fm)[fb+(size_t)d*NPTS]
                             : bf2f(((const unsigned short*)fm)[fb+(size_t)d*NPTS]);
                unsigned short hi=f2bf(v);
                vh[j]=(short)hi;
                vl[j]=(short)f2bf(v-bf2f(hi));
            }
            *(s8v*)(XH + lane*XST + 64 + dbase + g*8)=vh;
            *(s8v*)(XL + lane*XST + 64 + dbase + g*8)=vl;
        }
    }
    __syncthreads();   // h1 (cols 0..31) + fm (cols 64..127) visible
    // ---- conv2 via MFMA: wave -> (ch-group cg, nt-pair nb) ----
    int cg=wv>>1, nb=(wv&1)*2;
    s8v AH=*(const s8v*)(u2h+(cg*64+lane)*8);
    s8v AL=*(const s8v*)(u2l+(cg*64+lane)*8);
    s8v BH0=*(const s8v*)(XH+((nb  )*16+col)*XST+quad*8);
    s8v BL0=*(const s8v*)(XL+((nb  )*16+col)*XST+quad*8);
    s8v BH1=*(const s8v*)(XH+((nb+1)*16+col)*XST+quad*8);
    s8v BL1=*(const s8v*)(XL+((nb+1)*16+col)*XST+quad*8);
    f4v Z; Z[0]=0.f;Z[1]=0.f;Z[2]=0.f;Z[3]=0.f;
    f4v c0=MFMA(AH,BH0,Z), c1=MFMA(AH,BH1,Z);
    c0=MFMA(AH,BL0,c0); c1=MFMA(AH,BL1,c1);
    c0=MFMA(AL,BH0,c0); c1=MFMA(AL,BH1,c1);
    __syncthreads();   // all h1 reads done before cols 0..63 overwritten
    // ---- BN2 + relu, write split h2 to cols 0..63 ----
    const float* sc2=F+F_SC2; const float* sh2=F+F_SH2;
    int chb=cg*16+quad*4;
    float g0=sc2[chb],g1=sc2[chb+1],g2=sc2[chb+2],g3=sc2[chb+3];
    float b0=sh2[chb],b1=sh2[chb+1],b2=sh2[chb+2],b3=sh2[chb+3];
#pragma unroll
    for(int i=0;i<2;i++){
        f4v c = i? c1 : c0;
        int p=(nb+i)*16+col;
        float v0=fmaxf(c[0]*g0+b0,0.f);
        float v1=fmaxf(c[1]*g1+b1,0.f);
        float v2=fmaxf(c[2]*g2+b2,0.f);
        float v3=fmaxf(c[3]*g3+b3,0.f);
        unsigned short h0=f2bf(v0),h1=f2bf(v1),h2=f2bf(v2),h3=f2bf(v3);
        s4v vh,vl;
        vh[0]=(short)h0; vh[1]=(short)h1; vh[2]=(short)h2; vh[3]=(short)h3;
        vl[0]=(short)f2bf(v0-bf2f(h0)); vl[1]=(short)f2bf(v1-bf2f(h1));
        vl[2]=(short)f2bf(v2-bf2f(h2)); vl[3]=(short)f2bf(v3-bf2f(h3));
        *(s4v*)(XH + p*XST + chb)=vh;
        *(s4v*)(XL + p*XST + chb)=vl;
    }
    // caller's __syncthreads() completes the tile
}

// GEMM1 (512t): wave wv owns mt=wv (mt 0..7), acc C[4]
#define G1_STEP8(UH,UL) \
    for(int kt=0;kt<4;kt++){ \
        s8v BH[4],BL[4]; \
        for(int nt=0;nt<4;nt++){ \
            int boff=(nt*16+col)*XST + kt*32 + quad*8; \
            BH[nt]=*(const s8v*)(XH+boff); \
            BL[nt]=*(const s8v*)(XL+boff); \
        } \
        { \
            s8v AH=*(const s8v*)(UH+((wv*4+kt)*64+lane)*8); \
            s8v AL=*(const s8v*)(UL+((wv*4+kt)*64+lane)*8); \
            for(int nt=0;nt<4;nt++) C[nt]=MFMA(AH,BH[nt],C[nt]); \
            for(int nt=0;nt<4;nt++) C[nt]=MFMA(AH,BL[nt],C[nt]); \
            for(int nt=0;nt<4;nt++) C[nt]=MFMA(AL,BH[nt],C[nt]); \
        } \
    }

// GEMM2 (512t): wave wv owns mt=2wv..2wv+1, acc C2[2][4]
#define G2_STEP8(UH,UL) \
    for(int kt=0;kt<4;kt++){ \
        s8v BH[4],BL[4]; \
        for(int nt=0;nt<4;nt++){ \
            int boff=(nt*16+col)*XST + kt*32 + quad*8; \
            BH[nt]=*(const s8v*)(XH+boff); \
            BL[nt]=*(const s8v*)(XL+boff); \
        } \
        for(int mi=0;mi<2;mi++){ \
            int mt=2*wv+mi; \
            s8v AH=*(const s8v*)(UH+((mt*4+kt)*64+lane)*8); \
            s8v AL=*(const s8v*)(UL+((mt*4+kt)*64+lane)*8); \
            for(int nt=0;nt<4;nt++) C2[mi][nt]=MFMA(AH,BH[nt],C2[mi][nt]); \
            for(int nt=0;nt<4;nt++) C2[mi][nt]=MFMA(AH,BL[nt],C2[mi][nt]); \
            for(int nt=0;nt<4;nt++) C2[mi][nt]=MFMA(AL,BH[nt],C2[mi][nt]); \
        } \
    }

// ---- stats3: x2 tile -> GEMM1 (W3) -> sum/ssq of y3; exports h2 tile ----
__global__ __launch_bounds__(512) void k_stats3(
    const float* __restrict__ ctrf,const float* __restrict__ loaf,
    const void* __restrict__ fm,const float* __restrict__ F,
    const unsigned short* __restrict__ u2h,const unsigned short* __restrict__ u2l,
    const unsigned short* __restrict__ u3h,const unsigned short* __restrict__ u3l,
    unsigned short* __restrict__ h2h,unsigned short* __restrict__ h2l,
    float* __restrict__ sum3,float* __restrict__ ssq3)
{
    __shared__ unsigned short XH[64*XST];
    __shared__ unsigned short XL[64*XST];
    __shared__ float as_[128],qs_[128];
    int t=threadIdx.x, wv=t>>6, lane=t&63;
    if(t<128){as_[t]=0.f;qs_[t]=0.f;}
    int md=((const int*)F)[0];
    int pos0=blockIdx.x*2, b=pos0>>11, s0=pos0&2047;
    build_x2_8(ctrf,loaf,fm,F,u2h,u2l,md,b,s0,wv,lane,XH,XL);
    __syncthreads();
    int quad=lane>>4, col=lane&15;
    f4v Z; Z[0]=0.f;Z[1]=0.f;Z[2]=0.f;Z[3]=0.f;
    f4v C[4];
#pragma unroll
    for(int nt=0;nt<4;nt++) C[nt]=Z;
#pragma unroll
    G1_STEP8(u3h,u3l)
    // ---- tier1 export: h2 tile (cols 0..63) bit-exact to global ----
    if(h2h){
        int pos=t>>3, off=((t&7)^(pos&7))*8;    // XOR chunk swizzle, bijective per pos
        size_t go=(size_t)blockIdx.x*4096 + (size_t)pos*64 + off;
        *(s8v*)(h2h+go)=*(const s8v*)(XH+pos*XST+off);
        *(s8v*)(h2l+go)=*(const s8v*)(XL+pos*XST+off);
    }
#pragma unroll
    for(int rg=0;rg<4;rg++){
        float sm=0.f,sq=0.f;
#pragma unroll
        for(int nt=0;nt<4;nt++){ float v=C[nt][rg]; sm+=v; sq+=v*v; }
        sm+=__shfl_xor(sm,1); sq+=__shfl_xor(sq,1);
        sm+=__shfl_xor(sm,2); sq+=__shfl_xor(sq,2);
        sm+=__shfl_xor(sm,4); sq+=__shfl_xor(sq,4);
        sm+=__shfl_xor(sm,8); sq+=__shfl_xor(sq,8);
        if(col==0){
            int ch=wv*16+quad*4+rg;
            atomicAdd(&as_[ch],sm); atomicAdd(&qs_[ch],sq);
        }
    }
    __syncthreads();
    if(t<128){atomicAdd(&sum3[t],as_[t]);atomicAdd(&ssq3[t],qs_[t]);}
}

// ---- conv4 H2 (tier1): reload h2, regather fm, GEMM1->BN3->GEMM2 ----
__global__ __launch_bounds__(512) void k_conv4h(
    const void* __restrict__ fm,const float* __restrict__ F,
    const unsigned short* __restrict__ u3h,const unsigned short* __restrict__ u3l,
    const unsigned short* __restrict__ u4h,const unsigned short* __restrict__ u4l,
    const unsigned short* __restrict__ h2h,const unsigned short* __restrict__ h2l,
    float* __restrict__ maxb,float* __restrict__ sum4,float* __restrict__ ssq4)
{
    __shared__ unsigned short XH[64*XST];
    __shared__ unsigned short XL[64*XST];
    __shared__ float as_[256],qs_[256];
    int t=threadIdx.x, wv=t>>6, lane=t&63;
    if(t<256){as_[t]=0.f; qs_[t]=0.f;}
    int md=((const int*)F)[0];
    int pos0=blockIdx.x*2, b=pos0>>11, s0=pos0&2047;
    // ---- h2 import (matches export layout: global[pos][j]=lds[pos][j]) ----
    {
        int pos=t>>3, off=((t&7)^(pos&7))*8;
        size_t go=(size_t)blockIdx.x*4096 + (size_t)pos*64 + off;
        *(s8v*)(XH+pos*XST+off)=*(const s8v*)(h2h+go);
        *(s8v*)(XL+pos*XST+off)=*(const s8v*)(h2l+go);
    }
    // ---- fm gather: wave wv covers d [8wv, 8wv+8) ----
    {
        int dbase=8*wv;
        int s=s0+(lane>>5), k=lane&31;
        int gi=(sidx(s)-16+k)&(NPTS-1);
        size_t fb=(size_t)b*64*NPTS+gi;
        s8v vh,vl;
#pragma unroll
        for(int j=0;j<8;j++){
            int d=dbase+j;
            float v = md ? ((const float*)fm)[fb+(size_t)d*NPTS]
                         : bf2f(((const unsigned short*)fm)[fb+(size_t)d*NPTS]);
            unsigned short hi=f2bf(v);
            vh[j]=(short)hi;
            vl[j]=(short)f2bf(v-bf2f(hi));
        }
        *(s8v*)(XH + lane*XST + 64 + dbase)=vh;
        *(s8v*)(XL + lane*XST + 64 + dbase)=vl;
    }
    __syncthreads();   // x2 tile complete
    int quad=lane>>4, col=lane&15;
    // ---- GEMM1: C[4], mt=wv ----
    f4v Z; Z[0]=0.f;Z[1]=0.f;Z[2]=0.f;Z[3]=0.f;
    f4v C[4];
#pragma unroll
    for(int nt=0;nt<4;nt++) C[nt]=Z;
#pragma unroll
    G1_STEP8(u3h,u3l)
    __syncthreads();   // all waves done reading x2
    // ---- BN3 + relu -> h3 split ----
    const float* sc3=F+F_SC3; const float* sh3=F+F_SH3;
    {
        int chb=wv*16+quad*4;
#pragma unroll
        for(int nt=0;nt<4;nt++){
            int p=nt*16+col;
            s4v vh,vl;
#pragma unroll
            for(int rg=0;rg<4;rg++){
                float v=C[nt][rg];
                v=fmaxf(v*sc3[chb+rg]+sh3[chb+rg],0.f);
                unsigned short hi=f2bf(v);
                vh[rg]=(short)hi;
                vl[rg]=(short)f2bf(v-bf2f(hi));
            }
            *(s4v*)(XH + p*XST + chb)=vh;
            *(s4v*)(XL + p*XST + chb)=vl;
        }
    }
    __syncthreads();   // h3 tile complete
    // ---- GEMM2: C2[2][4], mt=2wv..2wv+1 ----
    f4v C2[2][4];
#pragma unroll
    for(int mi=0;mi<2;mi++)
#pragma unroll
        for(int nt=0;nt<4;nt++) C2[mi][nt]=Z;
#pragma unroll
    G2_STEP8(u4h,u4l)
    // ---- epilogue ----
#pragma unroll
    for(int mi=0;mi<2;mi++){
        int mt=2*wv+mi;
#pragma unroll
        for(int rg=0;rg<4;rg++){
            float sm=0.f,sq=0.f,mx0=-3.4e38f,mx1=-3.4e38f;
#pragma unroll
            for(int nt=0;nt<4;nt++){
                float v=C2[mi][nt][rg];
                sm+=v; sq+=v*v;
                if(nt<2) mx0=fmaxf(mx0,v); else mx1=fmaxf(mx1,v);
            }
            sm+=__shfl_xor(sm,1); sq+=__shfl_xor(sq,1);
            sm+=__shfl_xor(sm,2); sq+=__shfl_xor(sq,2);
            sm+=__shfl_xor(sm,4); sq+=__shfl_xor(sq,4);
            sm+=__shfl_xor(sm,8); sq+=__shfl_xor(sq,8);
            mx0=fmaxf(mx0,__shfl_xor(mx0,1)); mx1=fmaxf(mx1,__shfl_xor(mx1,1));
            mx0=fmaxf(mx0,__shfl_xor(mx0,2)); mx1=fmaxf(mx1,__shfl_xor(mx1,2));
            mx0=fmaxf(mx0,__shfl_xor(mx0,4)); mx1=fmaxf(mx1,__shfl_xor(mx1,4));
            mx0=fmaxf(mx0,__shfl_xor(mx0,8)); mx1=fmaxf(mx1,__shfl_xor(mx1,8));
            if(col==0){
                int ch=mt*16+quad*4+rg;
                atomicAdd(&as_[ch],sm); atomicAdd(&qs_[ch],sq);
                size_t ob=((size_t)b*256+ch)*SSZ + s0;
                maxb[ob]=mx0; maxb[ob+1]=mx1;
            }
        }
    }
    __syncthreads();
    if(t<256){atomicAdd(&sum4[t],as_[t]);atomicAdd(&ssq4[t],qs_[t]);}
}

// ---- conv4 SLOW (fallback when ws too small): full rebuild, 512t ----
__global__ __launch_bounds__(512) void k_conv4(
    const float* __restrict__ ctrf,const float* __restrict__ loaf,
    const void* __restrict__ fm,const float* __restrict__ F,
    const unsigned short* __restrict__ u2h,const unsigned short* __restrict__ u2l,
    const unsigned short* __restrict__ u3h,const unsigned short* __restrict__ u3l,
    const unsigned short* __restrict__ u4h,const unsigned short* __restrict__ u4l,
    float* __restrict__ maxb,float* __restrict__ sum4,float* __restrict__ ssq4)
{
    __shared__ unsigned short XH[64*XST];
    __shared__ unsigned short XL[64*XST];
    __shared__ float as_[256],qs_[256];
    int t=threadIdx.x, wv=t>>6, lane=t&63;
    if(t<256){as_[t]=0.f; qs_[t]=0.f;}
    int md=((const int*)F)[0];
    int pos0=blockIdx.x*2, b=pos0>>11, s0=pos0&2047;
    build_x2_8(ctrf,loaf,fm,F,u2h,u2l,md,b,s0,wv,lane,XH,XL);
    __syncthreads();
    int quad=lane>>4, col=lane&15;
    f4v Z; Z[0]=0.f;Z[1]=0.f;Z[2]=0.f;Z[3]=0.f;
    f4v C[4];
#pragma unroll
    for(int nt=0;nt<4;nt++) C[nt]=Z;
#pragma unroll
    G1_STEP8(u3h,u3l)
    __syncthreads();
    const float* sc3=F+F_SC3; const float* sh3=F+F_SH3;
    {
        int chb=wv*16+quad*4;
#pragma unroll
        for(int nt=0;nt<4;nt++){
            int p=nt*16+col;
            s4v vh,vl;
#pragma unroll
            for(int rg=0;rg<4;rg++){
                float v=C[nt][rg];
                v=fmaxf(v*sc3[chb+rg]+sh3[chb+rg],0.f);
                unsigned short hi=f2bf(v);
                vh[rg]=(short)hi;
                vl[rg]=(short)f2bf(v-bf2f(hi));
            }
            *(s4v*)(XH + p*XST + chb)=vh;
            *(s4v*)(XL + p*XST + chb)=vl;
        }
    }
    __syncthreads();
    f4v C2[2][4];
#pragma unroll
    for(int mi=0;mi<2;mi++)
#pragma unroll
        for(int nt=0;nt<4;nt++) C2[mi][nt]=Z;
#pragma unroll
    G2_STEP8(u4h,u4l)
#pragma unroll
    for(int mi=0;mi<2;mi++){
        int mt=2*wv+mi;
#pragma unroll
        for(int rg=0;rg<4;rg++){
            float sm=0.f,sq=0.f,mx0=-3.4e38f,mx1=-3.4e38f;
#pragma unroll
            for(int nt=0;nt<4;nt++){
                float v=C2[mi][nt][rg];
                sm+=v; sq+=v*v;
                if(nt<2) mx0=fmaxf(mx0,v); else mx1=fmaxf(mx1,v);
            }
            sm+=__shfl_xor(sm,1); sq+=__shfl_xor(sq,1);
            sm+=__shfl_xor(sm,2); sq+=__shfl_xor(sq,2);
            sm+=__shfl_xor(sm,4); sq+=__shfl_xor(sq,4);
            sm+=__shfl_xor(sm,8); sq+=__shfl_xor(sq,8);
            mx0=fmaxf(mx0,__shfl_xor(mx0,1)); mx1=fmaxf(mx1,__shfl_xor(mx1,1));
            mx0=fmaxf(mx0,__shfl_xor(mx0,2)); mx1=fmaxf(mx1,__shfl_xor(mx1,2));
            mx0=fmaxf(mx0,__shfl_xor(mx0,4)); mx1=fmaxf(mx1,__shfl_xor(mx1,4));
            mx0=fmaxf(mx0,__shfl_xor(mx0,8)); mx1=fmaxf(mx1,__shfl_xor(mx1,8));
            if(col==0){
                int ch=mt*16+quad*4+rg;
                atomicAdd(&as_[ch],sm); atomicAdd(&qs_[ch],sq);
                size_t ob=((size_t)b*256+ch)*SSZ + s0;
                maxb[ob]=mx0; maxb[ob+1]=mx1;
            }
        }
    }
    __syncthreads();
    if(t<256){atomicAdd(&sum4[t],as_[t]);atomicAdd(&ssq4[t],qs_[t]);}
}

// ---- final: out2 = relu(BN4(K-max)) in place, float4 (gamma=1 => scale>0) ----
__global__ __launch_bounds__(256) void k_apply(
    const float* __restrict__ F,float* __restrict__ out)
{
    int e4=blockIdx.x*256+threadIdx.x;     // 1048576 quads = B*256*S/4
    int j=(e4>>9)&255;                     // (e4*4>>11)&255; 4 elems share j
    float sc=F[F_SC4+j],sh=F[F_SH4+j];
    fl4* p=(fl4*)(out+98304)+e4;
    fl4 v=*p;
    v[0]=fmaxf(v[0]*sc+sh,0.f);
    v[1]=fmaxf(v[1]*sc+sh,0.f);
    v[2]=fmaxf(v[2]*sc+sh,0.f);
    v[3]=fmaxf(v[3]*sc+sh,0.f);
    *p=v;
}

extern "C" void kernel_launch(void* const* d_in, const int* in_sizes, int n_in,
                              void* d_out, int out_size, void* d_ws, size_t ws_size,
                              hipStream_t stream)
{
    const void* contour=d_in[0];
    const void* loa    =d_in[1];
    const void* fm     =d_in[2];
    const void* w1 =d_in[3];  const void* g1 =d_in[5];  const void* be1=d_in[6];
    const void* w2 =d_in[7];  const void* g2 =d_in[9];  const void* be2=d_in[10];
    const void* w3 =d_in[11]; const void* g3 =d_in[13]; const void* be3=d_in[14];
    const void* w4 =d_in[15]; const void* g4 =d_in[17]; const void* be4=d_in[18];
    float* out=(float*)d_out;          // output buffer is float32

    float* F=(float*)d_ws;
    char* base=(char*)d_ws;
    float* ctrf=(float*)(base+CTR_OFF);
    float* loaf=(float*)(base+LOA_OFF);
    unsigned short* u3h=(unsigned short*)(base+U3H_OFF);
    unsigned short* u3l=(unsigned short*)(base+U3L_OFF);
    unsigned short* u4h=(unsigned short*)(base+U4H_OFF);
    unsigned short* u4l=(unsigned short*)(base+U4L_OFF);
    unsigned short* u2h=(unsigned short*)(base+U2H_OFF);
    unsigned short* u2l=(unsigned short*)(base+U2L_OFF);
    int tier = (ws_size >= WS_H2) ? 1 : 0;
    unsigned short* h2h = tier==1 ? (unsigned short*)(base+H2H_OFF) : (unsigned short*)0;
    unsigned short* h2l = tier==1 ? (unsigned short*)(base+H2L_OFF) : (unsigned short*)0;
    float* maxb=out+98304;             // out2 f32 region doubles as K-max scratch

    k_detect<<<1,256,0,stream>>>(contour,(int*)d_ws);
    k_convert<<<768,256,0,stream>>>(contour,loa,w1,w2,w3,w4,g1,be1,g2,be2,g3,be3,g4,be4,
                                    F,ctrf,loaf,u2h,u2l,u3h,u3l,u4h,u4l,out);
    k_features<<<2048,256,0,stream>>>(ctrf,loaf,F+F_MOM1,F+F_MOM2);
    k_bn1<<<1,32,0,stream>>>(F);
    k_stats2m<<<1024,256,0,stream>>>(ctrf,loaf,F,F+F_P);
    k_red<<<1,256,0,stream>>>(F);
    k_stats3<<<8192,512,0,stream>>>(ctrf,loaf,fm,F,u2h,u2l,u3h,u3l,h2h,h2l,
                                    F+F_SUM3,F+F_SSQ3);
    k_bnd<<<1,256,0,stream>>>(F,128,F_SUM3,F_SSQ3,F_G3,F_BE3,F_SC3,F_SH3);
    if(tier==1){
        k_conv4h<<<8192,512,0,stream>>>(fm,F,u3h,u3l,u4h,u4l,h2h,h2l,maxb,F+F_SUM4,F+F_SSQ4);
    }else{
        k_conv4<<<8192,512,0,stream>>>(ctrf,loaf,fm,F,u2h,u2l,u3h,u3l,u4h,u4l,maxb,F+F_SUM4,F+F_SSQ4);
    }
    k_bnd<<<1,256,0,stream>>>(F,256,F_SUM4,F_SSQ4,F_G4,F_BE4,F_SC4,F_SH4);
    k_apply<<<4096,256,0,stream>>>(F,out);
}

// Round 13
// 635.755 us; speedup vs baseline: 1.4054x; 1.3536x over previous
//
#include <hip/hip_runtime.h>
#include <stdint.h>

#define NPTS 8192
#define SSZ  2048
#define QTOT (8*2048*32)   // 524288 positions (b,s,k)

// ---- float-index offsets within ws param region F ----
#define F_MOM1   4
#define F_MOM2   12
#define F_SC1    972
#define F_SH1    1004
#define F_SC2    1036
#define F_SH2    1100
#define F_SC3    1164
#define F_SH3    1292
#define F_SC4    1420
#define F_SH4    1676
#define F_WF1    1932
#define F_WF2    2188
#define F_G1     53388
#define F_BE1    53420
#define F_G2     53452
#define F_BE2    53516
#define F_G3     53580
#define F_BE3    53708
#define F_G4     53836
#define F_BE4    54092
// h1 moment results (BN2 analytic): M1[32] then M2[32*32]
#define F_M1     57344
#define F_M2     57376
// 16-slot partials for stats2m flush: P[16][1056] floats (60000..76896)
#define F_P      60000
// 64-slot partials for stats3 flush: [64][256] floats (77000..93384)
#define F_S3P    77000
// 64-slot partials for conv4 flush: [64][512] floats (94000..126768 < 131072)
#define F_C4P    94000
// byte offsets of big ws buffers
#define CTR_OFF  524288ull
#define LOA_OFF  1310720ull
#define U3H_OFF  2097152ull   // W3 A-frag packed, hi bf16 [16384]
#define U3L_OFF  2129920ull   // lo
#define U4H_OFF  2162688ull   // W4 A-frag packed, hi bf16 [32768]
#define U4L_OFF  2228224ull   // lo
#define U2H_OFF  2293760ull   // W2 A-frag packed, hi bf16 [2048]
#define U2L_OFF  2297856ull   // lo; ends 2301952
// tier-1 (h2 split, bit-exact): 8192 blocks x 8KB each buffer
#define H2H_OFF  2301952ull
#define H2L_OFF  (2301952ull + 67108864ull)
#define WS_H2    (2301952ull + 2ull*67108864ull)    // ~130.2 MiB

typedef __attribute__((ext_vector_type(8))) short s8v;   // 8 bf16 (4 VGPRs)
typedef __attribute__((ext_vector_type(4))) short s4v;   // 4 bf16 (b64)
typedef __attribute__((ext_vector_type(4))) float f4v;   // MFMA acc
typedef __attribute__((ext_vector_type(4))) float fl4;
#define MFMA(a,b,c) __builtin_amdgcn_mfma_f32_16x16x32_bf16(a,b,c,0,0,0)

__device__ inline float bf2f(unsigned short u){ return __uint_as_float(((uint32_t)u)<<16); }
__device__ inline unsigned short f2bf(float f){
    uint32_t x=__float_as_uint(f);
    return (unsigned short)((x + 0x7fffu + ((x>>16)&1u))>>16);
}
__device__ inline float clipf(float x){
    const float LO=(float)(-1.0+1e-7), HI=(float)(1.0-1e-7);
    return fminf(fmaxf(x,LO),HI);
}
__device__ inline float wredsum(float v){
#pragma unroll
    for(int m=1;m<64;m<<=1) v+=__shfl_xor(v,m,64);
    return v;
}
// mode: 0 = bf16 ushort storage, 1 = f32 storage
__device__ inline float ldin(const void* p,size_t i,int md){
    return md ? ((const float*)p)[i] : bf2f(((const unsigned short*)p)[i]);
}
// exact np.linspace(0,8191,2048)[s].astype(int32)
__device__ inline int sidx(int s){ return (s*8191)/2047; }

// ---- dtype probe ----
__global__ void k_detect(const void* contour,int* flag){
    __shared__ int he;
    if(threadIdx.x==0) he=0;
    __syncthreads();
    const unsigned short* u=(const unsigned short*)contour;
    int h=0;
    for(int i=threadIdx.x;i<4096;i+=256){
        unsigned short lo=u[2*i];
        if(((lo>>7)&0xFF)>=0x86) h++;
    }
    atomicAdd(&he,h);
    __syncthreads();
    if(threadIdx.x==0) *flag = (he>400) ? 1 : 0;
}

// ---- canonicalize inputs, pack W2/W3/W4 A-frags, write outputs 0/1 ----
__global__ __launch_bounds__(256) void k_convert(
    const void* ctr,const void* loa,
    const void* w1,const void* w2,const void* w3,const void* w4,
    const void* g1,const void* be1,const void* g2,const void* be2,
    const void* g3,const void* be3,const void* g4,const void* be4,
    float* F, float* ctrf, float* loaf,
    unsigned short* u2h, unsigned short* u2l,
    unsigned short* u3h, unsigned short* u3l,
    unsigned short* u4h, unsigned short* u4l,
    float* out)
{
    int md=((const int*)F)[0];
    int i = blockIdx.x*256+threadIdx.x;     // 768 blocks -> 196608
    ctrf[i]=ldin(ctr,i,md);
    loaf[i]=ldin(loa,i,md);
    if(i<16384){
        // outputs 0/1: sampled contour + LOA (f32)
        int b=i>>11, s=i&2047;
        int idx=sidx(s);
        size_t cb=((size_t)b*NPTS+idx)*3;
        size_t ob=(size_t)i*3;
        out[ob]        =ldin(ctr,cb  ,md);
        out[ob+1]      =ldin(ctr,cb+1,md);
        out[ob+2]      =ldin(ctr,cb+2,md);
        out[49152+ob]  =ldin(loa,cb  ,md);
        out[49152+ob+1]=ldin(loa,cb+1,md);
        out[49152+ob+2]=ldin(loa,cb+2,md);
    }
    if(i<256)  F[F_WF1+i]=ldin(w1,i,md);
    if(i<2048) F[F_WF2+i]=ldin(w2,i,md);
    if(i<2048){
        // W2 (64x32) A-frags, kt=0 only: mt 0..3
        int j=i&7, lane=(i>>3)&63, mt=i>>9;
        int m=lane&15, kk=((lane>>4)<<3)|j;
        float w=ldin(w2,(size_t)(mt*16+m)*32 + kk, md);
        unsigned short hi=f2bf(w);
        u2h[i]=hi; u2l[i]=f2bf(w-bf2f(hi));
    }
    if(i<16384){
        int j=i&7, lane=(i>>3)&63, kt=(i>>9)&3, mt=i>>11;
        int m=lane&15, kk=((lane>>4)<<3)|j;
        float w=ldin(w3,(size_t)(mt*16+m)*128 + kt*32+kk, md);
        unsigned short hi=f2bf(w);
        u3h[i]=hi; u3l[i]=f2bf(w-bf2f(hi));
    }
    if(i<32768){
        int j=i&7, lane=(i>>3)&63, kt=(i>>9)&3, mt=i>>11;   // mt 0..15
        int m=lane&15, kk=((lane>>4)<<3)|j;
        float w=ldin(w4,(size_t)(mt*16+m)*128 + kt*32+kk, md);
        unsigned short hi=f2bf(w);
        u4h[i]=hi; u4l[i]=f2bf(w-bf2f(hi));
    }
    if(i<968)   F[4+i]=0.f;
    if(i<16896) F[F_P+i]=0.f;    // 16-slot partials (stats2m)
    if(i<16384) F[F_S3P+i]=0.f;  // 64-slot partials (stats3)
    if(i<32768) F[F_C4P+i]=0.f;  // 64-slot partials (conv4)
    if(i<32){ F[F_G1+i]=ldin(g1,i,md); F[F_BE1+i]=ldin(be1,i,md); }
    if(i<64){ F[F_G2+i]=ldin(g2,i,md); F[F_BE2+i]=ldin(be2,i,md); }
    if(i<128){ F[F_G3+i]=ldin(g3,i,md); F[F_BE3+i]=ldin(be3,i,md); }
    if(i<256){ F[F_G4+i]=ldin(g4,i,md); F[F_BE4+i]=ldin(be4,i,md); }
}

// ---- shared feature computation: r[8]; lane groups of 32 = one (b,s) ----
__device__ inline void rif_compute(const float* __restrict__ ctr,const float* __restrict__ loa,
                                   int b,int s,int k,float r[8])
{
    int idx=sidx(s);
    int gi=(idx-16+k)&(NPTS-1);
    size_t cb=((size_t)b*NPTS+gi)*3;
    float px=ctr[cb],py=ctr[cb+1],pz=ctr[cb+2];
    float lx=loa[cb],ly=loa[cb+1],lz=loa[cb+2];
    float sx=__shfl(px,16,32),sy=__shfl(py,16,32),sz=__shfl(pz,16,32);
    float ax=__shfl(lx,16,32),ay=__shfl(ly,16,32),az=__shfl(lz,16,32);
    float vx=px-sx,vy=py-sy,vz=pz-sz;
    float sq=vx*vx+vy*vy+vz*vz;
    float d1=sq>0.f?sqrtf(sq):0.f;
    float inv=d1>0.f?1.f/d1:0.f;
    float ux=vx*inv,uy=vy*inv,uz=vz*inv;
    float a1=ux*ax+uy*ay+uz*az;
    float a2=ux*lx+uy*ly+uz*lz;
    float a3=acosf(clipf(lx*ax+ly*ay+lz*az));
    int src=(k+31)&31;
    float pvx=__shfl(vx,src,32),pvy=__shfl(vy,src,32),pvz=__shfl(vz,src,32);
    float plx=__shfl(lx,src,32),ply=__shfl(ly,src,32),plz=__shfl(lz,src,32);
    float pux=__shfl(ux,src,32),puy=__shfl(uy,src,32),puz=__shfl(uz,src,32);
    float ivx=vx-pvx,ivy=vy-pvy,ivz=vz-pvz;
    float isq=ivx*ivx+ivy*ivy+ivz*ivz;
    float idn=isq>0.f?1.f/sqrtf(isq):0.f;
    float iux=ivx*idn,iuy=ivy*idn,iuz=ivz*idn;
    float a4=iux*lx+iuy*ly+iuz*lz;
    float a5=iux*plx+iuy*ply+iuz*plz;
    float a6=acosf(clipf(lx*plx+ly*ply+lz*plz));
    float d2=acosf(clipf(ux*pux+uy*puy+uz*puz));
    r[0]=d1;r[1]=d2;r[2]=a1;r[3]=a2;r[4]=a3;r[5]=a4;r[6]=a5;r[7]=a6;
}

// ---- features: rif moments (analytic BN1) ----
__global__ __launch_bounds__(256) void k_features(
    const float* __restrict__ ctrf,const float* __restrict__ loaf,
    float* __restrict__ mom1,float* __restrict__ mom2)
{
    __shared__ float sm1[8],sm2[64];
    int t=threadIdx.x;
    if(t<8)sm1[t]=0.f;
    if(t<64)sm2[t]=0.f;
    __syncthreads();
    int lane=t&63,k=t&31;
    int q=blockIdx.x*256+t;
    int pos=q>>5,b=pos>>11,s=pos&2047;
    float r[8];
    rif_compute(ctrf,loaf,b,s,k,r);
#pragma unroll
    for(int i=0;i<8;i++){ float sv=wredsum(r[i]); if(lane==0)atomicAdd(&sm1[i],sv); }
#pragma unroll
    for(int i=0;i<8;i++)
#pragma unroll
        for(int j=i;j<8;j++){ float sv=wredsum(r[i]*r[j]); if(lane==0)atomicAdd(&sm2[i*8+j],sv); }
    __syncthreads();
    if(t<8)atomicAdd(&mom1[t],sm1[t]);
    if(t<64)atomicAdd(&mom2[t],sm2[t]);
}

// ---- analytic BN1 ----
__global__ void k_bn1(float* F){
    int o=threadIdx.x;
    if(o>=32)return;
    const float invP=1.0f/(float)QTOT;
    float m[8],w[8];
#pragma unroll
    for(int c=0;c<8;c++){ m[c]=F[F_MOM1+c]*invP; w[c]=F[F_WF1+o*8+c]; }
    float Ey=0.f;
#pragma unroll
    for(int c=0;c<8;c++) Ey+=w[c]*m[c];
    float Eyy=0.f;
#pragma unroll
    for(int i=0;i<8;i++)
#pragma unroll
        for(int j=0;j<8;j++){
            int a=i<j?i:j,bb=i<j?j:i;
            Eyy+=w[i]*w[j]*F[F_MOM2+a*8+bb]*invP;
        }
    float var=fmaxf(Eyy-Ey*Ey,0.f);
    float sc=F[F_G1+o]/sqrtf(var+1e-5f);
    F[F_SC1+o]=sc;
    F[F_SH1+o]=F[F_BE1+o]-Ey*sc;
}

// ---- stats2m: accumulate M1 = sum h1, M2 = sum h1 h1^T via MFMA ----
#define S2T 264
__global__ __launch_bounds__(256) void k_stats2m(
    const float* __restrict__ ctrf,const float* __restrict__ loaf,
    const float* __restrict__ F,float* __restrict__ P)
{
    __shared__ unsigned short TH[32*S2T];
    __shared__ unsigned short TL[32*S2T];
    int t=threadIdx.x, wv=t>>6, lane=t&63;
    int quad=lane>>4, col=lane&15;
    int mi=wv>>1, ni=wv&1;           // wave's M2 quadrant
    float acc8[8];                   // M1 partials: wave wv owns ch 8wv..8wv+7
#pragma unroll
    for(int k=0;k<8;k++) acc8[k]=0.f;
    f4v Z; Z[0]=0.f;Z[1]=0.f;Z[2]=0.f;Z[3]=0.f;
    f4v C0=Z, C1=Z;
    const float* wf1=F+F_WF1;
    const float* sc1=F+F_SC1; const float* sh1=F+F_SH1;
    for(int tt=0;tt<2;++tt){
        int tile=blockIdx.x*2+tt;                 // 0..2047
        int pos=tile*8 + wv*2 + (lane>>5);        // (b,s) index
        int b=pos>>11, s=pos&2047;
        float r[8]; rif_compute(ctrf,loaf,b,s,lane&31,r);
        int mypos=wv*64+lane;                     // 0..255 within tile
#pragma unroll
        for(int c=0;c<32;c++){                    // fused h1: no h1[32] array
            const float* w=wf1+c*8;
            float y=w[0]*r[0]+w[1]*r[1]+w[2]*r[2]+w[3]*r[3]
                   +w[4]*r[4]+w[5]*r[5]+w[6]*r[6]+w[7]*r[7];
            float h=fmaxf(y*sc1[c]+sh1[c],0.f);
            unsigned short hi=f2bf(h);
            TH[c*S2T+mypos]=hi;
            TL[c*S2T+mypos]=f2bf(h-bf2f(hi));
        }
        __syncthreads();
#pragma unroll
        for(int kt=0;kt<8;kt++){
            s8v AH=*(const s8v*)(TH+(mi*16+col)*S2T + kt*32 + quad*8);
            s8v AL=*(const s8v*)(TL+(mi*16+col)*S2T + kt*32 + quad*8);
            s8v BH=*(const s8v*)(TH+(ni*16+col)*S2T + kt*32 + quad*8);
            s8v BL=*(const s8v*)(TL+(ni*16+col)*S2T + kt*32 + quad*8);
            if(kt&1){
                C1=MFMA(AH,BH,C1); C1=MFMA(AH,BL,C1); C1=MFMA(AL,BH,C1);
            }else{
                C0=MFMA(AH,BH,C0); C0=MFMA(AH,BL,C0); C0=MFMA(AL,BH,C0);
            }
        }
        // M1 from LDS: lane covers pos lane*4..lane*4+3 of each owned channel
#pragma unroll
        for(int k=0;k<8;k++){
            int c=wv*8+k;
            const unsigned short* ph=TH+c*S2T+lane*4;
            const unsigned short* pl=TL+c*S2T+lane*4;
            acc8[k]+=bf2f(ph[0])+bf2f(ph[1])+bf2f(ph[2])+bf2f(ph[3])
                    +bf2f(pl[0])+bf2f(pl[1])+bf2f(pl[2])+bf2f(pl[3]);
        }
        __syncthreads();
    }
    // flush to partial slot (slot = blk & 15): P[slot][0..31]=M1, [32..1055]=M2
    float* Ps=P+(size_t)(blockIdx.x&15)*1056;
#pragma unroll
    for(int rg=0;rg<4;rg++){
        float v=C0[rg]+C1[rg];
        atomicAdd(&Ps[32+(mi*16+quad*4+rg)*32 + ni*16+col], v);
    }
#pragma unroll
    for(int k=0;k<8;k++){
        float sv=wredsum(acc8[k]);
        if(lane==0) atomicAdd(&Ps[wv*8+k],sv);
    }
}

// ---- fold 16 partial slots into F_M1/F_M2, then analytic BN2 (merged) ----
__global__ void k_red(float* F){
    int t=threadIdx.x;   // 1 block x 256 threads
    for(int e=t;e<1056;e+=256){
        float s=0.f;
#pragma unroll
        for(int k=0;k<16;k++) s+=F[F_P+k*1056+e];
        if(e<32) F[F_M1+e]=s; else F[F_M2+e-32]=s;
    }
    __syncthreads();
    int o=t;
    if(o<64){
        const float invP=1.0f/(float)QTOT;
        const float* w=F+F_WF2+o*32;
        const float* M2=F+F_M2;
        float Ey=0.f;
#pragma unroll
        for(int c=0;c<32;c++) Ey+=w[c]*F[F_M1+c];
        Ey*=invP;
        float Eyy=0.f;
        for(int c1=0;c1<32;c1++){
            float acc=0.f;
#pragma unroll
            for(int c2=0;c2<32;c2++) acc+=w[c2]*M2[c1*32+c2];
            Eyy+=w[c1]*acc;
        }
        Eyy*=invP;
        float var=fmaxf(Eyy-Ey*Ey,0.f);
        float s=F[F_G2+o]/sqrtf(var+1e-5f);
        F[F_SC2+o]=s;
        F[F_SH2+o]=F[F_BE2+o]-Ey*s;
    }
}

// ---- fold stats3 64 slots -> BN3 scale/shift (single writer) ----
__global__ void k_bnd3(float* F){
    int o=threadIdx.x;
    if(o>=128)return;
    float sum=0.f,ssq=0.f;
    for(int s=0;s<64;s++){
        sum+=F[F_S3P+s*256+o];
        ssq+=F[F_S3P+s*256+128+o];
    }
    const float invP=1.0f/(float)QTOT;
    float mean=sum*invP;
    float var=fmaxf(ssq*invP-mean*mean,0.f);
    float sc=F[F_G3+o]/sqrtf(var+1e-5f);
    F[F_SC3+o]=sc;
    F[F_SH3+o]=F[F_BE3+o]-mean*sc;
}

// ---- fold conv4 64 slots -> BN4 scale/shift (single writer) ----
__global__ void k_bnd4(float* F){
    int o=threadIdx.x;
    if(o>=256)return;
    float sum=0.f,ssq=0.f;
    for(int s=0;s<64;s++){
        sum+=F[F_C4P+s*512+o];
        ssq+=F[F_C4P+s*512+256+o];
    }
    const float invP=1.0f/(float)QTOT;
    float mean=sum*invP;
    float var=fmaxf(ssq*invP-mean*mean,0.f);
    float sc=F[F_G4+o]/sqrtf(var+1e-5f);
    F[F_SC4+o]=sc;
    F[F_SH4+o]=F[F_BE4+o]-mean*sc;
}

// =====================================================================
// MFMA tile kernels, 512-thread (8-wave) version (round-7 known-good:
// VGPR 44/60, no spill). Tile = 64 positions (2 s). Global stats flush
// goes to 64 slots (blockIdx&63) -> 128 RMWs/address instead of 8192
// (round-5-proven de-contention).
// =====================================================================
#define XST 136   // ushort row stride (16B-aligned rows)

__device__ inline void build_x2_8(
    const float* __restrict__ ctrf,const float* __restrict__ loaf,
    const void* __restrict__ fm,const float* __restrict__ F,
    const unsigned short* __restrict__ u2h,const unsigned short* __restrict__ u2l,
    int md,int b,int s0,int wv,int lane,
    unsigned short* XH,unsigned short* XL)
{
    int quad=lane>>4, col=lane&15;
    if(wv<4){
        // rif + h1, 8 channels per wave (waves 0-3)
        float r8[8]; rif_compute(ctrf,loaf,b,s0+(lane>>5),lane&31,r8);
        const float* wf1=F+F_WF1;
        const float* sc1=F+F_SC1; const float* sh1=F+F_SH1;
        s8v vh,vl;
#pragma unroll
        for(int j=0;j<8;j++){
            int o=8*wv+j;
            const float* w=wf1+o*8;
            float y=w[0]*r8[0]+w[1]*r8[1]+w[2]*r8[2]+w[3]*r8[3]
                   +w[4]*r8[4]+w[5]*r8[5]+w[6]*r8[6]+w[7]*r8[7];
            float h=fmaxf(y*sc1[o]+sh1[o],0.f);
            unsigned short hi=f2bf(h);
            vh[j]=(short)hi;
            vl[j]=(short)f2bf(h-bf2f(hi));
        }
        *(s8v*)(XH + lane*XST + 8*wv)=vh;
        *(s8v*)(XL + lane*XST + 8*wv)=vl;
    }else{
        // fm gather, 16 d per wave (waves 4-7)
        int dbase=16*(wv-4);
        int s=s0+(lane>>5), k=lane&31;
        int gi=(sidx(s)-16+k)&(NPTS-1);
        size_t fb=(size_t)b*64*NPTS+gi;
        for(int g=0;g<2;g++){
            s8v vh,vl;
#pragma unroll
            for(int j=0;j<8;j++){
                int d=dbase+g*8+j;
                float v = md ? ((const float*)fm)[fb+(size_t)d*NPTS]
                             : bf2f(((const unsigned short*)fm)[fb+(size_t)d*NPTS]);
                unsigned short hi=f2bf(v);
                vh[j]=(short)hi;
                vl[j]=(short)f2bf(v-bf2f(hi));
            }
            *(s8v*)(XH + lane*XST + 64 + dbase + g*8)=vh;
            *(s8v*)(XL + lane*XST + 64 + dbase + g*8)=vl;
        }
    }
    __syncthreads();   // h1 (cols 0..31) + fm (cols 64..127) visible
    // ---- conv2 via MFMA: wave -> (ch-group cg, nt-pair nb) ----
    int cg=wv>>1, nb=(wv&1)*2;
    s8v AH=*(const s8v*)(u2h+(cg*64+lane)*8);
    s8v AL=*(const s8v*)(u2l+(cg*64+lane)*8);
    s8v BH0=*(const s8v*)(XH+((nb  )*16+col)*XST+quad*8);
    s8v BL0=*(const s8v*)(XL+((nb  )*16+col)*XST+quad*8);
    s8v BH1=*(const s8v*)(XH+((nb+1)*16+col)*XST+quad*8);
    s8v BL1=*(const s8v*)(XL+((nb+1)*16+col)*XST+quad*8);
    f4v Z; Z[0]=0.f;Z[1]=0.f;Z[2]=0.f;Z[3]=0.f;
    f4v c0=MFMA(AH,BH0,Z), c1=MFMA(AH,BH1,Z);
    c0=MFMA(AH,BL0,c0); c1=MFMA(AH,BL1,c1);
    c0=MFMA(AL,BH0,c0); c1=MFMA(AL,BH1,c1);
    __syncthreads();   // all h1 reads done before cols 0..63 overwritten
    // ---- BN2 + relu, write split h2 to cols 0..63 ----
    const float* sc2=F+F_SC2; const float* sh2=F+F_SH2;
    int chb=cg*16+quad*4;
    float g0=sc2[chb],g1=sc2[chb+1],g2=sc2[chb+2],g3=sc2[chb+3];
    float b0=sh2[chb],b1=sh2[chb+1],b2=sh2[chb+2],b3=sh2[chb+3];
#pragma unroll
    for(int i=0;i<2;i++){
        f4v c = i? c1 : c0;
        int p=(nb+i)*16+col;
        float v0=fmaxf(c[0]*g0+b0,0.f);
        float v1=fmaxf(c[1]*g1+b1,0.f);
        float v2=fmaxf(c[2]*g2+b2,0.f);
        float v3=fmaxf(c[3]*g3+b3,0.f);
        unsigned short h0=f2bf(v0),h1=f2bf(v1),h2=f2bf(v2),h3=f2bf(v3);
        s4v vh,vl;
        vh[0]=(short)h0; vh[1]=(short)h1; vh[2]=(short)h2; vh[3]=(short)h3;
        vl[0]=(short)f2bf(v0-bf2f(h0)); vl[1]=(short)f2bf(v1-bf2f(h1));
        vl[2]=(short)f2bf(v2-bf2f(h2)); vl[3]=(short)f2bf(v3-bf2f(h3));
        *(s4v*)(XH + p*XST + chb)=vh;
        *(s4v*)(XL + p*XST + chb)=vl;
    }
    // caller's __syncthreads() completes the tile
}

// GEMM1 (512t): wave wv owns mt=wv (mt 0..7), acc C[4]
#define G1_STEP8(UH,UL) \
    for(int kt=0;kt<4;kt++){ \
        s8v BH[4],BL[4]; \
        for(int nt=0;nt<4;nt++){ \
            int boff=(nt*16+col)*XST + kt*32 + quad*8; \
            BH[nt]=*(const s8v*)(XH+boff); \
            BL[nt]=*(const s8v*)(XL+boff); \
        } \
        { \
            s8v AH=*(const s8v*)(UH+((wv*4+kt)*64+lane)*8); \
            s8v AL=*(const s8v*)(UL+((wv*4+kt)*64+lane)*8); \
            for(int nt=0;nt<4;nt++) C[nt]=MFMA(AH,BH[nt],C[nt]); \
            for(int nt=0;nt<4;nt++) C[nt]=MFMA(AH,BL[nt],C[nt]); \
            for(int nt=0;nt<4;nt++) C[nt]=MFMA(AL,BH[nt],C[nt]); \
        } \
    }

// GEMM2 (512t): wave wv owns mt=2wv..2wv+1, acc C2[2][4]
#define G2_STEP8(UH,UL) \
    for(int kt=0;kt<4;kt++){ \
        s8v BH[4],BL[4]; \
        for(int nt=0;nt<4;nt++){ \
            int boff=(nt*16+col)*XST + kt*32 + quad*8; \
            BH[nt]=*(const s8v*)(XH+boff); \
            BL[nt]=*(const s8v*)(XL+boff); \
        } \
        for(int mi=0;mi<2;mi++){ \
            int mt=2*wv+mi; \
            s8v AH=*(const s8v*)(UH+((mt*4+kt)*64+lane)*8); \
            s8v AL=*(const s8v*)(UL+((mt*4+kt)*64+lane)*8); \
            for(int nt=0;nt<4;nt++) C2[mi][nt]=MFMA(AH,BH[nt],C2[mi][nt]); \
            for(int nt=0;nt<4;nt++) C2[mi][nt]=MFMA(AH,BL[nt],C2[mi][nt]); \
            for(int nt=0;nt<4;nt++) C2[mi][nt]=MFMA(AL,BH[nt],C2[mi][nt]); \
        } \
    }

// ---- stats3: x2 tile -> GEMM1 (W3) -> sum/ssq of y3; exports h2 tile ----
__global__ __launch_bounds__(512) void k_stats3(
    const float* __restrict__ ctrf,const float* __restrict__ loaf,
    const void* __restrict__ fm,float* __restrict__ F,
    const unsigned short* __restrict__ u2h,const unsigned short* __restrict__ u2l,
    const unsigned short* __restrict__ u3h,const unsigned short* __restrict__ u3l,
    unsigned short* __restrict__ h2h,unsigned short* __restrict__ h2l)
{
    __shared__ unsigned short XH[64*XST];
    __shared__ unsigned short XL[64*XST];
    __shared__ float as_[128],qs_[128];
    int t=threadIdx.x, wv=t>>6, lane=t&63;
    if(t<128){as_[t]=0.f;qs_[t]=0.f;}
    int md=((const int*)F)[0];
    int pos0=blockIdx.x*2, b=pos0>>11, s0=pos0&2047;
    build_x2_8(ctrf,loaf,fm,F,u2h,u2l,md,b,s0,wv,lane,XH,XL);
    __syncthreads();
    int quad=lane>>4, col=lane&15;
    f4v Z; Z[0]=0.f;Z[1]=0.f;Z[2]=0.f;Z[3]=0.f;
    f4v C[4];
#pragma unroll
    for(int nt=0;nt<4;nt++) C[nt]=Z;
#pragma unroll
    G1_STEP8(u3h,u3l)
    // ---- tier1 export: h2 tile (cols 0..63) bit-exact to global ----
    if(h2h){
        int pos=t>>3, off=((t&7)^(pos&7))*8;    // XOR chunk swizzle, bijective per pos
        size_t go=(size_t)blockIdx.x*4096 + (size_t)pos*64 + off;
        *(s8v*)(h2h+go)=*(const s8v*)(XH+pos*XST+off);
        *(s8v*)(h2l+go)=*(const s8v*)(XL+pos*XST+off);
    }
#pragma unroll
    for(int rg=0;rg<4;rg++){
        float sm=0.f,sq=0.f;
#pragma unroll
        for(int nt=0;nt<4;nt++){ float v=C[nt][rg]; sm+=v; sq+=v*v; }
        sm+=__shfl_xor(sm,1); sq+=__shfl_xor(sq,1);
        sm+=__shfl_xor(sm,2); sq+=__shfl_xor(sq,2);
        sm+=__shfl_xor(sm,4); sq+=__shfl_xor(sq,4);
        sm+=__shfl_xor(sm,8); sq+=__shfl_xor(sq,8);
        if(col==0){
            int ch=wv*16+quad*4+rg;
            atomicAdd(&as_[ch],sm); atomicAdd(&qs_[ch],sq);
        }
    }
    __syncthreads();
    // 64-slot de-contended flush (128 RMWs/address instead of 8192)
    float* Ps=F+F_S3P+(size_t)(blockIdx.x&63)*256;
    if(t<128){atomicAdd(&Ps[t],as_[t]);atomicAdd(&Ps[128+t],qs_[t]);}
}

// ---- conv4 H2 (tier1): reload h2, regather fm, GEMM1->BN3->GEMM2 ----
__global__ __launch_bounds__(512) void k_conv4h(
    const void* __restrict__ fm,float* __restrict__ F,
    const unsigned short* __restrict__ u3h,const unsigned short* __restrict__ u3l,
    const unsigned short* __restrict__ u4h,const unsigned short* __restrict__ u4l,
    const unsigned short* __restrict__ h2h,const unsigned short* __restrict__ h2l,
    float* __restrict__ maxb)
{
    __shared__ unsigned short XH[64*XST];
    __shared__ unsigned short XL[64*XST];
    __shared__ float as_[256],qs_[256];
    int t=threadIdx.x, wv=t>>6, lane=t&63;
    if(t<256){as_[t]=0.f; qs_[t]=0.f;}
    int md=((const int*)F)[0];
    int pos0=blockIdx.x*2, b=pos0>>11, s0=pos0&2047;
    // ---- h2 import (matches export layout: global[pos][j]=lds[pos][j]) ----
    {
        int pos=t>>3, off=((t&7)^(pos&7))*8;
        size_t go=(size_t)blockIdx.x*4096 + (size_t)pos*64 + off;
        *(s8v*)(XH+pos*XST+off)=*(const s8v*)(h2h+go);
        *(s8v*)(XL+pos*XST+off)=*(const s8v*)(h2l+go);
    }
    // ---- fm gather: wave wv covers d [8wv, 8wv+8) ----
    {
        int dbase=8*wv;
        int s=s0+(lane>>5), k=lane&31;
        int gi=(sidx(s)-16+k)&(NPTS-1);
        size_t fb=(size_t)b*64*NPTS+gi;
        s8v vh,vl;
#pragma unroll
        for(int j=0;j<8;j++){
            int d=dbase+j;
            float v = md ? ((const float*)fm)[fb+(size_t)d*NPTS]
                         : bf2f(((const unsigned short*)fm)[fb+(size_t)d*NPTS]);
            unsigned short hi=f2bf(v);
            vh[j]=(short)hi;
            vl[j]=(short)f2bf(v-bf2f(hi));
        }
        *(s8v*)(XH + lane*XST + 64 + dbase)=vh;
        *(s8v*)(XL + lane*XST + 64 + dbase)=vl;
    }
    __syncthreads();   // x2 tile complete
    int quad=lane>>4, col=lane&15;
    // ---- GEMM1: C[4], mt=wv ----
    f4v Z; Z[0]=0.f;Z[1]=0.f;Z[2]=0.f;Z[3]=0.f;
    f4v C[4];
#pragma unroll
    for(int nt=0;nt<4;nt++) C[nt]=Z;
#pragma unroll
    G1_STEP8(u3h,u3l)
    __syncthreads();   // all waves done reading x2
    // ---- BN3 + relu -> h3 split ----
    const float* sc3=F+F_SC3; const float* sh3=F+F_SH3;
    {
        int chb=wv*16+quad*4;
#pragma unroll
        for(int nt=0;nt<4;nt++){
            int p=nt*16+col;
            s4v vh,vl;
#pragma unroll
            for(int rg=0;rg<4;rg++){
                float v=C[nt][rg];
                v=fmaxf(v*sc3[chb+rg]+sh3[chb+rg],0.f);
                unsigned short hi=f2bf(v);
                vh[rg]=(short)hi;
                vl[rg]=(short)f2bf(v-bf2f(hi));
            }
            *(s4v*)(XH + p*XST + chb)=vh;
            *(s4v*)(XL + p*XST + chb)=vl;
        }
    }
    __syncthreads();   // h3 tile complete
    // ---- GEMM2: C2[2][4], mt=2wv..2wv+1 ----
    f4v C2[2][4];
#pragma unroll
    for(int mi=0;mi<2;mi++)
#pragma unroll
        for(int nt=0;nt<4;nt++) C2[mi][nt]=Z;
#pragma unroll
    G2_STEP8(u4h,u4l)
    // ---- epilogue ----
#pragma unroll
    for(int mi=0;mi<2;mi++){
        int mt=2*wv+mi;
#pragma unroll
        for(int rg=0;rg<4;rg++){
            float sm=0.f,sq=0.f,mx0=-3.4e38f,mx1=-3.4e38f;
#pragma unroll
            for(int nt=0;nt<4;nt++){
                float v=C2[mi][nt][rg];
                sm+=v; sq+=v*v;
                if(nt<2) mx0=fmaxf(mx0,v); else mx1=fmaxf(mx1,v);
            }
            sm+=__shfl_xor(sm,1); sq+=__shfl_xor(sq,1);
            sm+=__shfl_xor(sm,2); sq+=__shfl_xor(sq,2);
            sm+=__shfl_xor(sm,4); sq+=__shfl_xor(sq,4);
            sm+=__shfl_xor(sm,8); sq+=__shfl_xor(sq,8);
            mx0=fmaxf(mx0,__shfl_xor(mx0,1)); mx1=fmaxf(mx1,__shfl_xor(mx1,1));
            mx0=fmaxf(mx0,__shfl_xor(mx0,2)); mx1=fmaxf(mx1,__shfl_xor(mx1,2));
            mx0=fmaxf(mx0,__shfl_xor(mx0,4)); mx1=fmaxf(mx1,__shfl_xor(mx1,4));
            mx0=fmaxf(mx0,__shfl_xor(mx0,8)); mx1=fmaxf(mx1,__shfl_xor(mx1,8));
            if(col==0){
                int ch=mt*16+quad*4+rg;
                atomicAdd(&as_[ch],sm); atomicAdd(&qs_[ch],sq);
                size_t ob=((size_t)b*256+ch)*SSZ + s0;
                maxb[ob]=mx0; maxb[ob+1]=mx1;
            }
        }
    }
    __syncthreads();
    // 64-slot de-contended flush
    float* Ps=F+F_C4P+(size_t)(blockIdx.x&63)*512;
    if(t<256){atomicAdd(&Ps[t],as_[t]);atomicAdd(&Ps[256+t],qs_[t]);}
}

// ---- conv4 SLOW (fallback when ws too small): full rebuild, 512t ----
__global__ __launch_bounds__(512) void k_conv4(
    const float* __restrict__ ctrf,const float* __restrict__ loaf,
    const void* __restrict__ fm,float* __restrict__ F,
    const unsigned short* __restrict__ u2h,const unsigned short* __restrict__ u2l,
    const unsigned short* __restrict__ u3h,const unsigned short* __restrict__ u3l,
    const unsigned short* __restrict__ u4h,const unsigned short* __restrict__ u4l,
    float* __restrict__ maxb)
{
    __shared__ unsigned short XH[64*XST];
    __shared__ unsigned short XL[64*XST];
    __shared__ float as_[256],qs_[256];
    int t=threadIdx.x, wv=t>>6, lane=t&63;
    if(t<256){as_[t]=0.f; qs_[t]=0.f;}
    int md=((const int*)F)[0];
    int pos0=blockIdx.x*2, b=pos0>>11, s0=pos0&2047;
    build_x2_8(ctrf,loaf,fm,F,u2h,u2l,md,b,s0,wv,lane,XH,XL);
    __syncthreads();
    int quad=lane>>4, col=lane&15;
    f4v Z; Z[0]=0.f;Z[1]=0.f;Z[2]=0.f;Z[3]=0.f;
    f4v C[4];
#pragma unroll
    for(int nt=0;nt<4;nt++) C[nt]=Z;
#pragma unroll
    G1_STEP8(u3h,u3l)
    __syncthreads();
    const float* sc3=F+F_SC3; const float* sh3=F+F_SH3;
    {
        int chb=wv*16+quad*4;
#pragma unroll
        for(int nt=0;nt<4;nt++){
            int p=nt*16+col;
            s4v vh,vl;
#pragma unroll
            for(int rg=0;rg<4;rg++){
                float v=C[nt][rg];
                v=fmaxf(v*sc3[chb+rg]+sh3[chb+rg],0.f);
                unsigned short hi=f2bf(v);
                vh[rg]=(short)hi;
                vl[rg]=(short)f2bf(v-bf2f(hi));
            }
            *(s4v*)(XH + p*XST + chb)=vh;
            *(s4v*)(XL + p*XST + chb)=vl;
        }
    }
    __syncthreads();
    f4v C2[2][4];
#pragma unroll
    for(int mi=0;mi<2;mi++)
#pragma unroll
        for(int nt=0;nt<4;nt++) C2[mi][nt]=Z;
#pragma unroll
    G2_STEP8(u4h,u4l)
#pragma unroll
    for(int mi=0;mi<2;mi++){
        int mt=2*wv+mi;
#pragma unroll
        for(int rg=0;rg<4;rg++){
            float sm=0.f,sq=0.f,mx0=-3.4e38f,mx1=-3.4e38f;
#pragma unroll
            for(int nt=0;nt<4;nt++){
                float v=C2[mi][nt][rg];
                sm+=v; sq+=v*v;
                if(nt<2) mx0=fmaxf(mx0,v); else mx1=fmaxf(mx1,v);
            }
            sm+=__shfl_xor(sm,1); sq+=__shfl_xor(sq,1);
            sm+=__shfl_xor(sm,2); sq+=__shfl_xor(sq,2);
            sm+=__shfl_xor(sm,4); sq+=__shfl_xor(sq,4);
            sm+=__shfl_xor(sm,8); sq+=__shfl_xor(sq,8);
            mx0=fmaxf(mx0,__shfl_xor(mx0,1)); mx1=fmaxf(mx1,__shfl_xor(mx1,1));
            mx0=fmaxf(mx0,__shfl_xor(mx0,2)); mx1=fmaxf(mx1,__shfl_xor(mx1,2));
            mx0=fmaxf(mx0,__shfl_xor(mx0,4)); mx1=fmaxf(mx1,__shfl_xor(mx1,4));
            mx0=fmaxf(mx0,__shfl_xor(mx0,8)); mx1=fmaxf(mx1,__shfl_xor(mx1,8));
            if(col==0){
                int ch=mt*16+quad*4+rg;
                atomicAdd(&as_[ch],sm); atomicAdd(&qs_[ch],sq);
                size_t ob=((size_t)b*256+ch)*SSZ + s0;
                maxb[ob]=mx0; maxb[ob+1]=mx1;
            }
        }
    }
    __syncthreads();
    float* Ps=F+F_C4P+(size_t)(blockIdx.x&63)*512;
    if(t<256){atomicAdd(&Ps[t],as_[t]);atomicAdd(&Ps[256+t],qs_[t]);}
}

// ---- final: out2 = relu(BN4(K-max)) in place, float4 (gamma=1 => scale>0) ----
__global__ __launch_bounds__(256) void k_apply(
    const float* __restrict__ F,float* __restrict__ out)
{
    int e4=blockIdx.x*256+threadIdx.x;     // 1048576 quads = B*256*S/4
    int j=(e4>>9)&255;                     // (e4*4>>11)&255; 4 elems share j
    float sc=F[F_SC4+j],sh=F[F_SH4+j];
    fl4* p=(fl4*)(out+98304)+e4;
    fl4 v=*p;
    v[0]=fmaxf(v[0]*sc+sh,0.f);
    v[1]=fmaxf(v[1]*sc+sh,0.f);
    v[2]=fmaxf(v[2]*sc+sh,0.f);
    v[3]=fmaxf(v[3]*sc+sh,0.f);
    *p=v;
}

extern "C" void kernel_launch(void* const* d_in, const int* in_sizes, int n_in,
                              void* d_out, int out_size, void* d_ws, size_t ws_size,
                              hipStream_t stream)
{
    const void* contour=d_in[0];
    const void* loa    =d_in[1];
    const void* fm     =d_in[2];
    const void* w1 =d_in[3];  const void* g1 =d_in[5];  const void* be1=d_in[6];
    const void* w2 =d_in[7];  const void* g2 =d_in[9];  const void* be2=d_in[10];
    const void* w3 =d_in[11]; const void* g3 =d_in[13]; const void* be3=d_in[14];
    const void* w4 =d_in[15]; const void* g4 =d_in[17]; const void* be4=d_in[18];
    float* out=(float*)d_out;          // output buffer is float32

    float* F=(float*)d_ws;
    char* base=(char*)d_ws;
    float* ctrf=(float*)(base+CTR_OFF);
    float* loaf=(float*)(base+LOA_OFF);
    unsigned short* u3h=(unsigned short*)(base+U3H_OFF);
    unsigned short* u3l=(unsigned short*)(base+U3L_OFF);
    unsigned short* u4h=(unsigned short*)(base+U4H_OFF);
    unsigned short* u4l=(unsigned short*)(base+U4L_OFF);
    unsigned short* u2h=(unsigned short*)(base+U2H_OFF);
    unsigned short* u2l=(unsigned short*)(base+U2L_OFF);
    int tier = (ws_size >= WS_H2) ? 1 : 0;
    unsigned short* h2h = tier==1 ? (unsigned short*)(base+H2H_OFF) : (unsigned short*)0;
    unsigned short* h2l = tier==1 ? (unsigned short*)(base+H2L_OFF) : (unsigned short*)0;
    float* maxb=out+98304;             // out2 f32 region doubles as K-max scratch

    k_detect<<<1,256,0,stream>>>(contour,(int*)d_ws);
    k_convert<<<768,256,0,stream>>>(contour,loa,w1,w2,w3,w4,g1,be1,g2,be2,g3,be3,g4,be4,
                                    F,ctrf,loaf,u2h,u2l,u3h,u3l,u4h,u4l,out);
    k_features<<<2048,256,0,stream>>>(ctrf,loaf,F+F_MOM1,F+F_MOM2);
    k_bn1<<<1,32,0,stream>>>(F);
    k_stats2m<<<1024,256,0,stream>>>(ctrf,loaf,F,F+F_P);
    k_red<<<1,256,0,stream>>>(F);
    k_stats3<<<8192,512,0,stream>>>(ctrf,loaf,fm,F,u2h,u2l,u3h,u3l,h2h,h2l);
    k_bnd3<<<1,128,0,stream>>>(F);
    if(tier==1){
        k_conv4h<<<8192,512,0,stream>>>(fm,F,u3h,u3l,u4h,u4l,h2h,h2l,maxb);
    }else{
        k_conv4<<<8192,512,0,stream>>>(ctrf,loaf,fm,F,u2h,u2l,u3h,u3l,u4h,u4l,maxb);
    }
    k_bnd4<<<1,256,0,stream>>>(F);
    k_apply<<<4096,256,0,stream>>>(F,out);
}

// Round 14
// 591.524 us; speedup vs baseline: 1.5105x; 1.0748x over previous
//
#include <hip/hip_runtime.h>
#include <stdint.h>

#define NPTS 8192
#define SSZ  2048
#define QTOT (8*2048*32)   // 524288 positions (b,s,k)

// ---- float-index offsets within ws param region F ----
#define F_MOM1   4
#define F_MOM2   12
#define F_SC1    972
#define F_SH1    1004
#define F_SC2    1036
#define F_SH2    1100
#define F_SC3    1164
#define F_SH3    1292
#define F_SC4    1420
#define F_SH4    1676
#define F_WF1    1932
#define F_WF2    2188
#define F_G1     53388
#define F_BE1    53420
#define F_G2     53452
#define F_BE2    53516
#define F_G3     53580
#define F_BE3    53708
#define F_G4     53836
#define F_BE4    54092
// h1 moment results (BN2 analytic): M1[32] then M2[32*32]
#define F_M1     57344
#define F_M2     57376
// 16-slot partials for stats2m flush: P[16][1056] floats (60000..76896)
#define F_P      60000
// 64-slot partials for stats3 flush: [64][256] floats (77000..93384)
#define F_S3P    77000
// 64-slot partials for conv4 flush: [64][512] floats (94000..126768 < 131072)
#define F_C4P    94000
// byte offsets of big ws buffers
#define CTR_OFF  524288ull
#define LOA_OFF  1310720ull
#define U3H_OFF  2097152ull   // W3 A-frag packed, hi bf16 [16384]
#define U3L_OFF  2129920ull   // lo
#define U4H_OFF  2162688ull   // W4 A-frag packed, hi bf16 [32768]
#define U4L_OFF  2228224ull   // lo
#define U2H_OFF  2293760ull   // W2 A-frag packed, hi bf16 [2048]
#define U2L_OFF  2297856ull   // lo; ends 2301952
// tier-1: y3 single-bf16 in C-fragment order: 8192 blocks x 16KB = 134.2 MB
#define Y3_OFF   2301952ull
#define WS_T1    (2301952ull + 134217728ull)    // ~130.2 MiB

typedef __attribute__((ext_vector_type(8))) short s8v;   // 8 bf16 (4 VGPRs)
typedef __attribute__((ext_vector_type(4))) short s4v;   // 4 bf16 (b64)
typedef __attribute__((ext_vector_type(4))) float f4v;   // MFMA acc
typedef __attribute__((ext_vector_type(4))) float fl4;
#define MFMA(a,b,c) __builtin_amdgcn_mfma_f32_16x16x32_bf16(a,b,c,0,0,0)

__device__ inline float bf2f(unsigned short u){ return __uint_as_float(((uint32_t)u)<<16); }
__device__ inline unsigned short f2bf(float f){
    uint32_t x=__float_as_uint(f);
    return (unsigned short)((x + 0x7fffu + ((x>>16)&1u))>>16);
}
__device__ inline float clipf(float x){
    const float LO=(float)(-1.0+1e-7), HI=(float)(1.0-1e-7);
    return fminf(fmaxf(x,LO),HI);
}
__device__ inline float wredsum(float v){
#pragma unroll
    for(int m=1;m<64;m<<=1) v+=__shfl_xor(v,m,64);
    return v;
}
// mode: 0 = bf16 ushort storage, 1 = f32 storage
__device__ inline float ldin(const void* p,size_t i,int md){
    return md ? ((const float*)p)[i] : bf2f(((const unsigned short*)p)[i]);
}
// exact np.linspace(0,8191,2048)[s].astype(int32)
__device__ inline int sidx(int s){ return (s*8191)/2047; }

// ---- dtype probe ----
__global__ void k_detect(const void* contour,int* flag){
    __shared__ int he;
    if(threadIdx.x==0) he=0;
    __syncthreads();
    const unsigned short* u=(const unsigned short*)contour;
    int h=0;
    for(int i=threadIdx.x;i<4096;i+=256){
        unsigned short lo=u[2*i];
        if(((lo>>7)&0xFF)>=0x86) h++;
    }
    atomicAdd(&he,h);
    __syncthreads();
    if(threadIdx.x==0) *flag = (he>400) ? 1 : 0;
}

// ---- canonicalize inputs, pack W2/W3/W4 A-frags, write outputs 0/1 ----
__global__ __launch_bounds__(256) void k_convert(
    const void* ctr,const void* loa,
    const void* w1,const void* w2,const void* w3,const void* w4,
    const void* g1,const void* be1,const void* g2,const void* be2,
    const void* g3,const void* be3,const void* g4,const void* be4,
    float* F, float* ctrf, float* loaf,
    unsigned short* u2h, unsigned short* u2l,
    unsigned short* u3h, unsigned short* u3l,
    unsigned short* u4h, unsigned short* u4l,
    float* out)
{
    int md=((const int*)F)[0];
    int i = blockIdx.x*256+threadIdx.x;     // 768 blocks -> 196608
    ctrf[i]=ldin(ctr,i,md);
    loaf[i]=ldin(loa,i,md);
    if(i<16384){
        // outputs 0/1: sampled contour + LOA (f32)
        int b=i>>11, s=i&2047;
        int idx=sidx(s);
        size_t cb=((size_t)b*NPTS+idx)*3;
        size_t ob=(size_t)i*3;
        out[ob]        =ldin(ctr,cb  ,md);
        out[ob+1]      =ldin(ctr,cb+1,md);
        out[ob+2]      =ldin(ctr,cb+2,md);
        out[49152+ob]  =ldin(loa,cb  ,md);
        out[49152+ob+1]=ldin(loa,cb+1,md);
        out[49152+ob+2]=ldin(loa,cb+2,md);
    }
    if(i<256)  F[F_WF1+i]=ldin(w1,i,md);
    if(i<2048) F[F_WF2+i]=ldin(w2,i,md);
    if(i<2048){
        // W2 (64x32) A-frags, kt=0 only: mt 0..3
        int j=i&7, lane=(i>>3)&63, mt=i>>9;
        int m=lane&15, kk=((lane>>4)<<3)|j;
        float w=ldin(w2,(size_t)(mt*16+m)*32 + kk, md);
        unsigned short hi=f2bf(w);
        u2h[i]=hi; u2l[i]=f2bf(w-bf2f(hi));
    }
    if(i<16384){
        int j=i&7, lane=(i>>3)&63, kt=(i>>9)&3, mt=i>>11;
        int m=lane&15, kk=((lane>>4)<<3)|j;
        float w=ldin(w3,(size_t)(mt*16+m)*128 + kt*32+kk, md);
        unsigned short hi=f2bf(w);
        u3h[i]=hi; u3l[i]=f2bf(w-bf2f(hi));
    }
    if(i<32768){
        int j=i&7, lane=(i>>3)&63, kt=(i>>9)&3, mt=i>>11;   // mt 0..15
        int m=lane&15, kk=((lane>>4)<<3)|j;
        float w=ldin(w4,(size_t)(mt*16+m)*128 + kt*32+kk, md);
        unsigned short hi=f2bf(w);
        u4h[i]=hi; u4l[i]=f2bf(w-bf2f(hi));
    }
    if(i<968)   F[4+i]=0.f;
    if(i<16896) F[F_P+i]=0.f;    // 16-slot partials (stats2m)
    if(i<16384) F[F_S3P+i]=0.f;  // 64-slot partials (stats3)
    if(i<32768) F[F_C4P+i]=0.f;  // 64-slot partials (conv4)
    if(i<32){ F[F_G1+i]=ldin(g1,i,md); F[F_BE1+i]=ldin(be1,i,md); }
    if(i<64){ F[F_G2+i]=ldin(g2,i,md); F[F_BE2+i]=ldin(be2,i,md); }
    if(i<128){ F[F_G3+i]=ldin(g3,i,md); F[F_BE3+i]=ldin(be3,i,md); }
    if(i<256){ F[F_G4+i]=ldin(g4,i,md); F[F_BE4+i]=ldin(be4,i,md); }
}

// ---- shared feature computation: r[8]; lane groups of 32 = one (b,s) ----
__device__ inline void rif_compute(const float* __restrict__ ctr,const float* __restrict__ loa,
                                   int b,int s,int k,float r[8])
{
    int idx=sidx(s);
    int gi=(idx-16+k)&(NPTS-1);
    size_t cb=((size_t)b*NPTS+gi)*3;
    float px=ctr[cb],py=ctr[cb+1],pz=ctr[cb+2];
    float lx=loa[cb],ly=loa[cb+1],lz=loa[cb+2];
    float sx=__shfl(px,16,32),sy=__shfl(py,16,32),sz=__shfl(pz,16,32);
    float ax=__shfl(lx,16,32),ay=__shfl(ly,16,32),az=__shfl(lz,16,32);
    float vx=px-sx,vy=py-sy,vz=pz-sz;
    float sq=vx*vx+vy*vy+vz*vz;
    float d1=sq>0.f?sqrtf(sq):0.f;
    float inv=d1>0.f?1.f/d1:0.f;
    float ux=vx*inv,uy=vy*inv,uz=vz*inv;
    float a1=ux*ax+uy*ay+uz*az;
    float a2=ux*lx+uy*ly+uz*lz;
    float a3=acosf(clipf(lx*ax+ly*ay+lz*az));
    int src=(k+31)&31;
    float pvx=__shfl(vx,src,32),pvy=__shfl(vy,src,32),pvz=__shfl(vz,src,32);
    float plx=__shfl(lx,src,32),ply=__shfl(ly,src,32),plz=__shfl(lz,src,32);
    float pux=__shfl(ux,src,32),puy=__shfl(uy,src,32),puz=__shfl(uz,src,32);
    float ivx=vx-pvx,ivy=vy-pvy,ivz=vz-pvz;
    float isq=ivx*ivx+ivy*ivy+ivz*ivz;
    float idn=isq>0.f?1.f/sqrtf(isq):0.f;
    float iux=ivx*idn,iuy=ivy*idn,iuz=ivz*idn;
    float a4=iux*lx+iuy*ly+iuz*lz;
    float a5=iux*plx+iuy*ply+iuz*plz;
    float a6=acosf(clipf(lx*plx+ly*ply+lz*plz));
    float d2=acosf(clipf(ux*pux+uy*puy+uz*puz));
    r[0]=d1;r[1]=d2;r[2]=a1;r[3]=a2;r[4]=a3;r[5]=a4;r[6]=a5;r[7]=a6;
}

// ---- features: rif moments (analytic BN1) ----
__global__ __launch_bounds__(256) void k_features(
    const float* __restrict__ ctrf,const float* __restrict__ loaf,
    float* __restrict__ mom1,float* __restrict__ mom2)
{
    __shared__ float sm1[8],sm2[64];
    int t=threadIdx.x;
    if(t<8)sm1[t]=0.f;
    if(t<64)sm2[t]=0.f;
    __syncthreads();
    int lane=t&63,k=t&31;
    int q=blockIdx.x*256+t;
    int pos=q>>5,b=pos>>11,s=pos&2047;
    float r[8];
    rif_compute(ctrf,loaf,b,s,k,r);
#pragma unroll
    for(int i=0;i<8;i++){ float sv=wredsum(r[i]); if(lane==0)atomicAdd(&sm1[i],sv); }
#pragma unroll
    for(int i=0;i<8;i++)
#pragma unroll
        for(int j=i;j<8;j++){ float sv=wredsum(r[i]*r[j]); if(lane==0)atomicAdd(&sm2[i*8+j],sv); }
    __syncthreads();
    if(t<8)atomicAdd(&mom1[t],sm1[t]);
    if(t<64)atomicAdd(&mom2[t],sm2[t]);
}

// ---- analytic BN1 ----
__global__ void k_bn1(float* F){
    int o=threadIdx.x;
    if(o>=32)return;
    const float invP=1.0f/(float)QTOT;
    float m[8],w[8];
#pragma unroll
    for(int c=0;c<8;c++){ m[c]=F[F_MOM1+c]*invP; w[c]=F[F_WF1+o*8+c]; }
    float Ey=0.f;
#pragma unroll
    for(int c=0;c<8;c++) Ey+=w[c]*m[c];
    float Eyy=0.f;
#pragma unroll
    for(int i=0;i<8;i++)
#pragma unroll
        for(int j=0;j<8;j++){
            int a=i<j?i:j,bb=i<j?j:i;
            Eyy+=w[i]*w[j]*F[F_MOM2+a*8+bb]*invP;
        }
    float var=fmaxf(Eyy-Ey*Ey,0.f);
    float sc=F[F_G1+o]/sqrtf(var+1e-5f);
    F[F_SC1+o]=sc;
    F[F_SH1+o]=F[F_BE1+o]-Ey*sc;
}

// ---- stats2m: accumulate M1 = sum h1, M2 = sum h1 h1^T via MFMA ----
#define S2T 264
__global__ __launch_bounds__(256) void k_stats2m(
    const float* __restrict__ ctrf,const float* __restrict__ loaf,
    const float* __restrict__ F,float* __restrict__ P)
{
    __shared__ unsigned short TH[32*S2T];
    __shared__ unsigned short TL[32*S2T];
    int t=threadIdx.x, wv=t>>6, lane=t&63;
    int quad=lane>>4, col=lane&15;
    int mi=wv>>1, ni=wv&1;           // wave's M2 quadrant
    float acc8[8];                   // M1 partials: wave wv owns ch 8wv..8wv+7
#pragma unroll
    for(int k=0;k<8;k++) acc8[k]=0.f;
    f4v Z; Z[0]=0.f;Z[1]=0.f;Z[2]=0.f;Z[3]=0.f;
    f4v C0=Z, C1=Z;
    const float* wf1=F+F_WF1;
    const float* sc1=F+F_SC1; const float* sh1=F+F_SH1;
    for(int tt=0;tt<2;++tt){
        int tile=blockIdx.x*2+tt;                 // 0..2047
        int pos=tile*8 + wv*2 + (lane>>5);        // (b,s) index
        int b=pos>>11, s=pos&2047;
        float r[8]; rif_compute(ctrf,loaf,b,s,lane&31,r);
        int mypos=wv*64+lane;                     // 0..255 within tile
#pragma unroll
        for(int c=0;c<32;c++){                    // fused h1: no h1[32] array
            const float* w=wf1+c*8;
            float y=w[0]*r[0]+w[1]*r[1]+w[2]*r[2]+w[3]*r[3]
                   +w[4]*r[4]+w[5]*r[5]+w[6]*r[6]+w[7]*r[7];
            float h=fmaxf(y*sc1[c]+sh1[c],0.f);
            unsigned short hi=f2bf(h);
            TH[c*S2T+mypos]=hi;
            TL[c*S2T+mypos]=f2bf(h-bf2f(hi));
        }
        __syncthreads();
#pragma unroll
        for(int kt=0;kt<8;kt++){
            s8v AH=*(const s8v*)(TH+(mi*16+col)*S2T + kt*32 + quad*8);
            s8v AL=*(const s8v*)(TL+(mi*16+col)*S2T + kt*32 + quad*8);
            s8v BH=*(const s8v*)(TH+(ni*16+col)*S2T + kt*32 + quad*8);
            s8v BL=*(const s8v*)(TL+(ni*16+col)*S2T + kt*32 + quad*8);
            if(kt&1){
                C1=MFMA(AH,BH,C1); C1=MFMA(AH,BL,C1); C1=MFMA(AL,BH,C1);
            }else{
                C0=MFMA(AH,BH,C0); C0=MFMA(AH,BL,C0); C0=MFMA(AL,BH,C0);
            }
        }
        // M1 from LDS: lane covers pos lane*4..lane*4+3 of each owned channel
#pragma unroll
        for(int k=0;k<8;k++){
            int c=wv*8+k;
            const unsigned short* ph=TH+c*S2T+lane*4;
            const unsigned short* pl=TL+c*S2T+lane*4;
            acc8[k]+=bf2f(ph[0])+bf2f(ph[1])+bf2f(ph[2])+bf2f(ph[3])
                    +bf2f(pl[0])+bf2f(pl[1])+bf2f(pl[2])+bf2f(pl[3]);
        }
        __syncthreads();
    }
    // flush to partial slot (slot = blk & 15): P[slot][0..31]=M1, [32..1055]=M2
    float* Ps=P+(size_t)(blockIdx.x&15)*1056;
#pragma unroll
    for(int rg=0;rg<4;rg++){
        float v=C0[rg]+C1[rg];
        atomicAdd(&Ps[32+(mi*16+quad*4+rg)*32 + ni*16+col], v);
    }
#pragma unroll
    for(int k=0;k<8;k++){
        float sv=wredsum(acc8[k]);
        if(lane==0) atomicAdd(&Ps[wv*8+k],sv);
    }
}

// ---- fold 16 partial slots into F_M1/F_M2, then analytic BN2 (merged) ----
__global__ void k_red(float* F){
    int t=threadIdx.x;   // 1 block x 256 threads
    for(int e=t;e<1056;e+=256){
        float s=0.f;
#pragma unroll
        for(int k=0;k<16;k++) s+=F[F_P+k*1056+e];
        if(e<32) F[F_M1+e]=s; else F[F_M2+e-32]=s;
    }
    __syncthreads();
    int o=t;
    if(o<64){
        const float invP=1.0f/(float)QTOT;
        const float* w=F+F_WF2+o*32;
        const float* M2=F+F_M2;
        float Ey=0.f;
#pragma unroll
        for(int c=0;c<32;c++) Ey+=w[c]*F[F_M1+c];
        Ey*=invP;
        float Eyy=0.f;
        for(int c1=0;c1<32;c1++){
            float acc=0.f;
#pragma unroll
            for(int c2=0;c2<32;c2++) acc+=w[c2]*M2[c1*32+c2];
            Eyy+=w[c1]*acc;
        }
        Eyy*=invP;
        float var=fmaxf(Eyy-Ey*Ey,0.f);
        float s=F[F_G2+o]/sqrtf(var+1e-5f);
        F[F_SC2+o]=s;
        F[F_SH2+o]=F[F_BE2+o]-Ey*s;
    }
}

// ---- fold stats3 64 slots -> BN3 scale/shift (single writer) ----
__global__ void k_bnd3(float* F){
    int o=threadIdx.x;
    if(o>=128)return;
    float sum=0.f,ssq=0.f;
    for(int s=0;s<64;s++){
        sum+=F[F_S3P+s*256+o];
        ssq+=F[F_S3P+s*256+128+o];
    }
    const float invP=1.0f/(float)QTOT;
    float mean=sum*invP;
    float var=fmaxf(ssq*invP-mean*mean,0.f);
    float sc=F[F_G3+o]/sqrtf(var+1e-5f);
    F[F_SC3+o]=sc;
    F[F_SH3+o]=F[F_BE3+o]-mean*sc;
}

// ---- fold conv4 64 slots -> BN4 scale/shift (single writer) ----
__global__ void k_bnd4(float* F){
    int o=threadIdx.x;
    if(o>=256)return;
    float sum=0.f,ssq=0.f;
    for(int s=0;s<64;s++){
        sum+=F[F_C4P+s*512+o];
        ssq+=F[F_C4P+s*512+256+o];
    }
    const float invP=1.0f/(float)QTOT;
    float mean=sum*invP;
    float var=fmaxf(ssq*invP-mean*mean,0.f);
    float sc=F[F_G4+o]/sqrtf(var+1e-5f);
    F[F_SC4+o]=sc;
    F[F_SH4+o]=F[F_BE4+o]-mean*sc;
}

// =====================================================================
// MFMA tile kernels, 512-thread (8-wave). Tile = 64 positions (2 s).
// 64-slot de-contended stats flush (round-13 confirmed: 343->246us).
// Tier-1 now stores y3 as SINGLE bf16 (C-fragment order, 16KB/block) so
// conv4 skips build+GEMM1 entirely.
// =====================================================================
#define XST 136   // ushort row stride (16B-aligned rows)

__device__ inline void build_x2_8(
    const float* __restrict__ ctrf,const float* __restrict__ loaf,
    const void* __restrict__ fm,const float* __restrict__ F,
    const unsigned short* __restrict__ u2h,const unsigned short* __restrict__ u2l,
    int md,int b,int s0,int wv,int lane,
    unsigned short* XH,unsigned short* XL)
{
    int quad=lane>>4, col=lane&15;
    if(wv<4){
        // rif + h1, 8 channels per wave (waves 0-3)
        float r8[8]; rif_compute(ctrf,loaf,b,s0+(lane>>5),lane&31,r8);
        const float* wf1=F+F_WF1;
        const float* sc1=F+F_SC1; const float* sh1=F+F_SH1;
        s8v vh,vl;
#pragma unroll
        for(int j=0;j<8;j++){
            int o=8*wv+j;
            const float* w=wf1+o*8;
            float y=w[0]*r8[0]+w[1]*r8[1]+w[2]*r8[2]+w[3]*r8[3]
                   +w[4]*r8[4]+w[5]*r8[5]+w[6]*r8[6]+w[7]*r8[7];
            float h=fmaxf(y*sc1[o]+sh1[o],0.f);
            unsigned short hi=f2bf(h);
            vh[j]=(short)hi;
            vl[j]=(short)f2bf(h-bf2f(hi));
        }
        *(s8v*)(XH + lane*XST + 8*wv)=vh;
        *(s8v*)(XL + lane*XST + 8*wv)=vl;
    }else{
        // fm gather, 16 d per wave (waves 4-7)
        int dbase=16*(wv-4);
        int s=s0+(lane>>5), k=lane&31;
        int gi=(sidx(s)-16+k)&(NPTS-1);
        size_t fb=(size_t)b*64*NPTS+gi;
        for(int g=0;g<2;g++){
            s8v vh,vl;
#pragma unroll
            for(int j=0;j<8;j++){
                int d=dbase+g*8+j;
                float v = md ? ((const float*)fm)[fb+(size_t)d*NPTS]
                             : bf2f(((const unsigned short*)fm)[fb+(size_t)d*NPTS]);
                unsigned short hi=f2bf(v);
                vh[j]=(short)hi;
                vl[j]=(short)f2bf(v-bf2f(hi));
            }
            *(s8v*)(XH + lane*XST + 64 + dbase + g*8)=vh;
            *(s8v*)(XL + lane*XST + 64 + dbase + g*8)=vl;
        }
    }
    __syncthreads();   // h1 (cols 0..31) + fm (cols 64..127) visible
    // ---- conv2 via MFMA: wave -> (ch-group cg, nt-pair nb) ----
    int cg=wv>>1, nb=(wv&1)*2;
    s8v AH=*(const s8v*)(u2h+(cg*64+lane)*8);
    s8v AL=*(const s8v*)(u2l+(cg*64+lane)*8);
    s8v BH0=*(const s8v*)(XH+((nb  )*16+col)*XST+quad*8);
    s8v BL0=*(const s8v*)(XL+((nb  )*16+col)*XST+quad*8);
    s8v BH1=*(const s8v*)(XH+((nb+1)*16+col)*XST+quad*8);
    s8v BL1=*(const s8v*)(XL+((nb+1)*16+col)*XST+quad*8);
    f4v Z; Z[0]=0.f;Z[1]=0.f;Z[2]=0.f;Z[3]=0.f;
    f4v c0=MFMA(AH,BH0,Z), c1=MFMA(AH,BH1,Z);
    c0=MFMA(AH,BL0,c0); c1=MFMA(AH,BL1,c1);
    c0=MFMA(AL,BH0,c0); c1=MFMA(AL,BH1,c1);
    __syncthreads();   // all h1 reads done before cols 0..63 overwritten
    // ---- BN2 + relu, write split h2 to cols 0..63 ----
    const float* sc2=F+F_SC2; const float* sh2=F+F_SH2;
    int chb=cg*16+quad*4;
    float g0=sc2[chb],g1=sc2[chb+1],g2=sc2[chb+2],g3=sc2[chb+3];
    float b0=sh2[chb],b1=sh2[chb+1],b2=sh2[chb+2],b3=sh2[chb+3];
#pragma unroll
    for(int i=0;i<2;i++){
        f4v c = i? c1 : c0;
        int p=(nb+i)*16+col;
        float v0=fmaxf(c[0]*g0+b0,0.f);
        float v1=fmaxf(c[1]*g1+b1,0.f);
        float v2=fmaxf(c[2]*g2+b2,0.f);
        float v3=fmaxf(c[3]*g3+b3,0.f);
        unsigned short h0=f2bf(v0),h1=f2bf(v1),h2=f2bf(v2),h3=f2bf(v3);
        s4v vh,vl;
        vh[0]=(short)h0; vh[1]=(short)h1; vh[2]=(short)h2; vh[3]=(short)h3;
        vl[0]=(short)f2bf(v0-bf2f(h0)); vl[1]=(short)f2bf(v1-bf2f(h1));
        vl[2]=(short)f2bf(v2-bf2f(h2)); vl[3]=(short)f2bf(v3-bf2f(h3));
        *(s4v*)(XH + p*XST + chb)=vh;
        *(s4v*)(XL + p*XST + chb)=vl;
    }
    // caller's __syncthreads() completes the tile
}

// GEMM1 (512t): wave wv owns mt=wv (mt 0..7), acc C[4]
#define G1_STEP8(UH,UL) \
    for(int kt=0;kt<4;kt++){ \
        s8v BH[4],BL[4]; \
        for(int nt=0;nt<4;nt++){ \
            int boff=(nt*16+col)*XST + kt*32 + quad*8; \
            BH[nt]=*(const s8v*)(XH+boff); \
            BL[nt]=*(const s8v*)(XL+boff); \
        } \
        { \
            s8v AH=*(const s8v*)(UH+((wv*4+kt)*64+lane)*8); \
            s8v AL=*(const s8v*)(UL+((wv*4+kt)*64+lane)*8); \
            for(int nt=0;nt<4;nt++) C[nt]=MFMA(AH,BH[nt],C[nt]); \
            for(int nt=0;nt<4;nt++) C[nt]=MFMA(AH,BL[nt],C[nt]); \
            for(int nt=0;nt<4;nt++) C[nt]=MFMA(AL,BH[nt],C[nt]); \
        } \
    }

// GEMM2 (512t): wave wv owns mt=2wv..2wv+1, acc C2[2][4]
#define G2_STEP8(UH,UL) \
    for(int kt=0;kt<4;kt++){ \
        s8v BH[4],BL[4]; \
        for(int nt=0;nt<4;nt++){ \
            int boff=(nt*16+col)*XST + kt*32 + quad*8; \
            BH[nt]=*(const s8v*)(XH+boff); \
            BL[nt]=*(const s8v*)(XL+boff); \
        } \
        for(int mi=0;mi<2;mi++){ \
            int mt=2*wv+mi; \
            s8v AH=*(const s8v*)(UH+((mt*4+kt)*64+lane)*8); \
            s8v AL=*(const s8v*)(UL+((mt*4+kt)*64+lane)*8); \
            for(int nt=0;nt<4;nt++) C2[mi][nt]=MFMA(AH,BH[nt],C2[mi][nt]); \
            for(int nt=0;nt<4;nt++) C2[mi][nt]=MFMA(AH,BL[nt],C2[mi][nt]); \
            for(int nt=0;nt<4;nt++) C2[mi][nt]=MFMA(AL,BH[nt],C2[mi][nt]); \
        } \
    }

// ---- stats3: x2 tile -> GEMM1 (W3) -> sum/ssq of y3; exports y3 bf16 ----
__global__ __launch_bounds__(512) void k_stats3(
    const float* __restrict__ ctrf,const float* __restrict__ loaf,
    const void* __restrict__ fm,float* __restrict__ F,
    const unsigned short* __restrict__ u2h,const unsigned short* __restrict__ u2l,
    const unsigned short* __restrict__ u3h,const unsigned short* __restrict__ u3l,
    unsigned short* __restrict__ y3)
{
    __shared__ unsigned short XH[64*XST];
    __shared__ unsigned short XL[64*XST];
    __shared__ float as_[128],qs_[128];
    int t=threadIdx.x, wv=t>>6, lane=t&63;
    if(t<128){as_[t]=0.f;qs_[t]=0.f;}
    int md=((const int*)F)[0];
    int pos0=blockIdx.x*2, b=pos0>>11, s0=pos0&2047;
    build_x2_8(ctrf,loaf,fm,F,u2h,u2l,md,b,s0,wv,lane,XH,XL);
    __syncthreads();
    int quad=lane>>4, col=lane&15;
    f4v Z; Z[0]=0.f;Z[1]=0.f;Z[2]=0.f;Z[3]=0.f;
    f4v C[4];
#pragma unroll
    for(int nt=0;nt<4;nt++) C[nt]=Z;
#pragma unroll
    G1_STEP8(u3h,u3l)
    // ---- tier1 export: y3 single-bf16, C-fragment order, 8B/lane ----
    if(y3){
#pragma unroll
        for(int nt=0;nt<4;nt++){
            s4v v4;
#pragma unroll
            for(int rg=0;rg<4;rg++) v4[rg]=(short)f2bf(C[nt][rg]);
            *(s4v*)(y3 + (size_t)blockIdx.x*8192 + (size_t)(wv*4+nt)*256 + lane*4) = v4;
        }
    }
#pragma unroll
    for(int rg=0;rg<4;rg++){
        float sm=0.f,sq=0.f;
#pragma unroll
        for(int nt=0;nt<4;nt++){ float v=C[nt][rg]; sm+=v; sq+=v*v; }
        sm+=__shfl_xor(sm,1); sq+=__shfl_xor(sq,1);
        sm+=__shfl_xor(sm,2); sq+=__shfl_xor(sq,2);
        sm+=__shfl_xor(sm,4); sq+=__shfl_xor(sq,4);
        sm+=__shfl_xor(sm,8); sq+=__shfl_xor(sq,8);
        if(col==0){
            int ch=wv*16+quad*4+rg;
            atomicAdd(&as_[ch],sm); atomicAdd(&qs_[ch],sq);
        }
    }
    __syncthreads();
    // 64-slot de-contended flush (128 RMWs/address instead of 8192)
    float* Ps=F+F_S3P+(size_t)(blockIdx.x&63)*256;
    if(t<128){atomicAdd(&Ps[t],as_[t]);atomicAdd(&Ps[128+t],qs_[t]);}
}

// ---- conv4 Y (tier1): reload y3 bf16 -> BN3/relu -> h3(LDS) -> GEMM2 ----
__global__ __launch_bounds__(512) void k_conv4y(
    float* __restrict__ F,
    const unsigned short* __restrict__ u4h,const unsigned short* __restrict__ u4l,
    const unsigned short* __restrict__ y3,
    float* __restrict__ maxb)
{
    __shared__ unsigned short XH[64*XST];
    __shared__ unsigned short XL[64*XST];
    __shared__ float as_[256],qs_[256];
    int t=threadIdx.x, wv=t>>6, lane=t&63;
    if(t<256){as_[t]=0.f; qs_[t]=0.f;}
    int quad=lane>>4, col=lane&15;
    int pos0=blockIdx.x*2, b=pos0>>11, s0=pos0&2047;
    const float* sc3=F+F_SC3; const float* sh3=F+F_SH3;
    // ---- load y3, BN3+relu, write split h3 tile (cols 0..127) ----
    {
        int chb=wv*16+quad*4;
#pragma unroll
        for(int nt=0;nt<4;nt++){
            s4v v4=*(const s4v*)(y3 + (size_t)blockIdx.x*8192 + (size_t)(wv*4+nt)*256 + lane*4);
            s4v vh,vl;
#pragma unroll
            for(int rg=0;rg<4;rg++){
                float v=bf2f((unsigned short)v4[rg]);
                v=fmaxf(v*sc3[chb+rg]+sh3[chb+rg],0.f);
                unsigned short hi=f2bf(v);
                vh[rg]=(short)hi;
                vl[rg]=(short)f2bf(v-bf2f(hi));
            }
            int p=nt*16+col;
            *(s4v*)(XH + p*XST + chb)=vh;
            *(s4v*)(XL + p*XST + chb)=vl;
        }
    }
    __syncthreads();   // h3 tile complete
    // ---- GEMM2: C2[2][4], mt=2wv..2wv+1 ----
    f4v Z; Z[0]=0.f;Z[1]=0.f;Z[2]=0.f;Z[3]=0.f;
    f4v C2[2][4];
#pragma unroll
    for(int mi=0;mi<2;mi++)
#pragma unroll
        for(int nt=0;nt<4;nt++) C2[mi][nt]=Z;
#pragma unroll
    G2_STEP8(u4h,u4l)
    // ---- epilogue ----
#pragma unroll
    for(int mi=0;mi<2;mi++){
        int mt=2*wv+mi;
#pragma unroll
        for(int rg=0;rg<4;rg++){
            float sm=0.f,sq=0.f,mx0=-3.4e38f,mx1=-3.4e38f;
#pragma unroll
            for(int nt=0;nt<4;nt++){
                float v=C2[mi][nt][rg];
                sm+=v; sq+=v*v;
                if(nt<2) mx0=fmaxf(mx0,v); else mx1=fmaxf(mx1,v);
            }
            sm+=__shfl_xor(sm,1); sq+=__shfl_xor(sq,1);
            sm+=__shfl_xor(sm,2); sq+=__shfl_xor(sq,2);
            sm+=__shfl_xor(sm,4); sq+=__shfl_xor(sq,4);
            sm+=__shfl_xor(sm,8); sq+=__shfl_xor(sq,8);
            mx0=fmaxf(mx0,__shfl_xor(mx0,1)); mx1=fmaxf(mx1,__shfl_xor(mx1,1));
            mx0=fmaxf(mx0,__shfl_xor(mx0,2)); mx1=fmaxf(mx1,__shfl_xor(mx1,2));
            mx0=fmaxf(mx0,__shfl_xor(mx0,4)); mx1=fmaxf(mx1,__shfl_xor(mx1,4));
            mx0=fmaxf(mx0,__shfl_xor(mx0,8)); mx1=fmaxf(mx1,__shfl_xor(mx1,8));
            if(col==0){
                int ch=mt*16+quad*4+rg;
                atomicAdd(&as_[ch],sm); atomicAdd(&qs_[ch],sq);
                size_t ob=((size_t)b*256+ch)*SSZ + s0;
                maxb[ob]=mx0; maxb[ob+1]=mx1;
            }
        }
    }
    __syncthreads();
    // 64-slot de-contended flush
    float* Ps=F+F_C4P+(size_t)(blockIdx.x&63)*512;
    if(t<256){atomicAdd(&Ps[t],as_[t]);atomicAdd(&Ps[256+t],qs_[t]);}
}

// ---- conv4 SLOW (fallback when ws too small): full rebuild, 512t ----
__global__ __launch_bounds__(512) void k_conv4(
    const float* __restrict__ ctrf,const float* __restrict__ loaf,
    const void* __restrict__ fm,float* __restrict__ F,
    const unsigned short* __restrict__ u2h,const unsigned short* __restrict__ u2l,
    const unsigned short* __restrict__ u3h,const unsigned short* __restrict__ u3l,
    const unsigned short* __restrict__ u4h,const unsigned short* __restrict__ u4l,
    float* __restrict__ maxb)
{
    __shared__ unsigned short XH[64*XST];
    __shared__ unsigned short XL[64*XST];
    __shared__ float as_[256],qs_[256];
    int t=threadIdx.x, wv=t>>6, lane=t&63;
    if(t<256){as_[t]=0.f; qs_[t]=0.f;}
    int md=((const int*)F)[0];
    int pos0=blockIdx.x*2, b=pos0>>11, s0=pos0&2047;
    build_x2_8(ctrf,loaf,fm,F,u2h,u2l,md,b,s0,wv,lane,XH,XL);
    __syncthreads();
    int quad=lane>>4, col=lane&15;
    f4v Z; Z[0]=0.f;Z[1]=0.f;Z[2]=0.f;Z[3]=0.f;
    f4v C[4];
#pragma unroll
    for(int nt=0;nt<4;nt++) C[nt]=Z;
#pragma unroll
    G1_STEP8(u3h,u3l)
    __syncthreads();
    const float* sc3=F+F_SC3; const float* sh3=F+F_SH3;
    {
        int chb=wv*16+quad*4;
#pragma unroll
        for(int nt=0;nt<4;nt++){
            int p=nt*16+col;
            s4v vh,vl;
#pragma unroll
            for(int rg=0;rg<4;rg++){
                float v=C[nt][rg];
                v=fmaxf(v*sc3[chb+rg]+sh3[chb+rg],0.f);
                unsigned short hi=f2bf(v);
                vh[rg]=(short)hi;
                vl[rg]=(short)f2bf(v-bf2f(hi));
            }
            *(s4v*)(XH + p*XST + chb)=vh;
            *(s4v*)(XL + p*XST + chb)=vl;
        }
    }
    __syncthreads();
    f4v C2[2][4];
#pragma unroll
    for(int mi=0;mi<2;mi++)
#pragma unroll
        for(int nt=0;nt<4;nt++) C2[mi][nt]=Z;
#pragma unroll
    G2_STEP8(u4h,u4l)
#pragma unroll
    for(int mi=0;mi<2;mi++){
        int mt=2*wv+mi;
#pragma unroll
        for(int rg=0;rg<4;rg++){
            float sm=0.f,sq=0.f,mx0=-3.4e38f,mx1=-3.4e38f;
#pragma unroll
            for(int nt=0;nt<4;nt++){
                float v=C2[mi][nt][rg];
                sm+=v; sq+=v*v;
                if(nt<2) mx0=fmaxf(mx0,v); else mx1=fmaxf(mx1,v);
            }
            sm+=__shfl_xor(sm,1); sq+=__shfl_xor(sq,1);
            sm+=__shfl_xor(sm,2); sq+=__shfl_xor(sq,2);
            sm+=__shfl_xor(sm,4); sq+=__shfl_xor(sq,4);
            sm+=__shfl_xor(sm,8); sq+=__shfl_xor(sq,8);
            mx0=fmaxf(mx0,__shfl_xor(mx0,1)); mx1=fmaxf(mx1,__shfl_xor(mx1,1));
            mx0=fmaxf(mx0,__shfl_xor(mx0,2)); mx1=fmaxf(mx1,__shfl_xor(mx1,2));
            mx0=fmaxf(mx0,__shfl_xor(mx0,4)); mx1=fmaxf(mx1,__shfl_xor(mx1,4));
            mx0=fmaxf(mx0,__shfl_xor(mx0,8)); mx1=fmaxf(mx1,__shfl_xor(mx1,8));
            if(col==0){
                int ch=mt*16+quad*4+rg;
                atomicAdd(&as_[ch],sm); atomicAdd(&qs_[ch],sq);
                size_t ob=((size_t)b*256+ch)*SSZ + s0;
                maxb[ob]=mx0; maxb[ob+1]=mx1;
            }
        }
    }
    __syncthreads();
    float* Ps=F+F_C4P+(size_t)(blockIdx.x&63)*512;
    if(t<256){atomicAdd(&Ps[t],as_[t]);atomicAdd(&Ps[256+t],qs_[t]);}
}

// ---- final: out2 = relu(BN4(K-max)) in place, float4 (gamma=1 => scale>0) ----
__global__ __launch_bounds__(256) void k_apply(
    const float* __restrict__ F,float* __restrict__ out)
{
    int e4=blockIdx.x*256+threadIdx.x;     // 1048576 quads = B*256*S/4
    int j=(e4>>9)&255;                     // (e4*4>>11)&255; 4 elems share j
    float sc=F[F_SC4+j],sh=F[F_SH4+j];
    fl4* p=(fl4*)(out+98304)+e4;
    fl4 v=*p;
    v[0]=fmaxf(v[0]*sc+sh,0.f);
    v[1]=fmaxf(v[1]*sc+sh,0.f);
    v[2]=fmaxf(v[2]*sc+sh,0.f);
    v[3]=fmaxf(v[3]*sc+sh,0.f);
    *p=v;
}

extern "C" void kernel_launch(void* const* d_in, const int* in_sizes, int n_in,
                              void* d_out, int out_size, void* d_ws, size_t ws_size,
                              hipStream_t stream)
{
    const void* contour=d_in[0];
    const void* loa    =d_in[1];
    const void* fm     =d_in[2];
    const void* w1 =d_in[3];  const void* g1 =d_in[5];  const void* be1=d_in[6];
    const void* w2 =d_in[7];  const void* g2 =d_in[9];  const void* be2=d_in[10];
    const void* w3 =d_in[11]; const void* g3 =d_in[13]; const void* be3=d_in[14];
    const void* w4 =d_in[15]; const void* g4 =d_in[17]; const void* be4=d_in[18];
    float* out=(float*)d_out;          // output buffer is float32

    float* F=(float*)d_ws;
    char* base=(char*)d_ws;
    float* ctrf=(float*)(base+CTR_OFF);
    float* loaf=(float*)(base+LOA_OFF);
    unsigned short* u3h=(unsigned short*)(base+U3H_OFF);
    unsigned short* u3l=(unsigned short*)(base+U3L_OFF);
    unsigned short* u4h=(unsigned short*)(base+U4H_OFF);
    unsigned short* u4l=(unsigned short*)(base+U4L_OFF);
    unsigned short* u2h=(unsigned short*)(base+U2H_OFF);
    unsigned short* u2l=(unsigned short*)(base+U2L_OFF);
    int tier = (ws_size >= WS_T1) ? 1 : 0;
    unsigned short* y3 = tier==1 ? (unsigned short*)(base+Y3_OFF) : (unsigned short*)0;
    float* maxb=out+98304;             // out2 f32 region doubles as K-max scratch

    k_detect<<<1,256,0,stream>>>(contour,(int*)d_ws);
    k_convert<<<768,256,0,stream>>>(contour,loa,w1,w2,w3,w4,g1,be1,g2,be2,g3,be3,g4,be4,
                                    F,ctrf,loaf,u2h,u2l,u3h,u3l,u4h,u4l,out);
    k_features<<<2048,256,0,stream>>>(ctrf,loaf,F+F_MOM1,F+F_MOM2);
    k_bn1<<<1,32,0,stream>>>(F);
    k_stats2m<<<1024,256,0,stream>>>(ctrf,loaf,F,F+F_P);
    k_red<<<1,256,0,stream>>>(F);
    k_stats3<<<8192,512,0,stream>>>(ctrf,loaf,fm,F,u2h,u2l,u3h,u3l,y3);
    k_bnd3<<<1,128,0,stream>>>(F);
    if(tier==1){
        k_conv4y<<<8192,512,0,stream>>>(F,u4h,u4l,y3,maxb);
    }else{
        k_conv4<<<8192,512,0,stream>>>(ctrf,loaf,fm,F,u2h,u2l,u3h,u3l,u4h,u4l,maxb);
    }
    k_bnd4<<<1,256,0,stream>>>(F);
    k_apply<<<4096,256,0,stream>>>(F,out);
}

// Round 15
// 531.323 us; speedup vs baseline: 1.6816x; 1.1133x over previous
//
#include <hip/hip_runtime.h>
#include <stdint.h>

#define NPTS 8192
#define SSZ  2048
#define QTOT (8*2048*32)   // 524288 positions (b,s,k)

// ---- float-index offsets within ws param region F ----
#define F_MOM1   4
#define F_MOM2   12
#define F_SC1    972
#define F_SH1    1004
#define F_SC2    1036
#define F_SH2    1100
#define F_SC3    1164
#define F_SH3    1292
#define F_SC4    1420
#define F_SH4    1676
#define F_WF1    1932
#define F_WF2    2188
#define F_G1     53388
#define F_BE1    53420
#define F_G2     53452
#define F_BE2    53516
#define F_G3     53580
#define F_BE3    53708
#define F_G4     53836
#define F_BE4    54092
// h1 moment results (BN2 analytic): M1[32] then M2[32*32]
#define F_M1     57344
#define F_M2     57376
// 16-slot partials for stats2m flush: P[16][1056] floats (60000..76896)
#define F_P      60000
// 64-slot partials for stats3 flush: [64][256] floats (77000..93384)
#define F_S3P    77000
// 64-slot partials for conv4 flush: [64][512] floats (94000..126768 < 131072)
#define F_C4P    94000
// byte offsets of big ws buffers
#define CTR_OFF  524288ull
#define LOA_OFF  1310720ull
#define U3H_OFF  2097152ull   // W3 A-frag packed, hi bf16 [16384]
#define U3L_OFF  2129920ull   // lo
#define U4H_OFF  2162688ull   // W4 A-frag packed, hi bf16 [32768]
#define U4L_OFF  2228224ull   // lo
#define U2H_OFF  2293760ull   // W2 A-frag packed, hi bf16 [2048]
#define U2L_OFF  2297856ull   // lo; ends 2301952
// tier-1: y3 single-bf16 in C-fragment order: 8192 blocks x 16KB = 134.2 MB
#define Y3_OFF   2301952ull
#define WS_T1    (2301952ull + 134217728ull)    // 136.5 MB
// tier-2: + r[8] f32 per (b,s,k): 16.8 MB
#define R_OFF    (2301952ull + 134217728ull)
#define WS_T2    (R_OFF + 16777216ull)          // 153.3 MB

typedef __attribute__((ext_vector_type(8))) short s8v;   // 8 bf16 (4 VGPRs)
typedef __attribute__((ext_vector_type(4))) short s4v;   // 4 bf16 (b64)
typedef __attribute__((ext_vector_type(4))) float f4v;   // MFMA acc
typedef __attribute__((ext_vector_type(4))) float fl4;
#define MFMA(a,b,c) __builtin_amdgcn_mfma_f32_16x16x32_bf16(a,b,c,0,0,0)

__device__ inline float bf2f(unsigned short u){ return __uint_as_float(((uint32_t)u)<<16); }
__device__ inline unsigned short f2bf(float f){
    uint32_t x=__float_as_uint(f);
    return (unsigned short)((x + 0x7fffu + ((x>>16)&1u))>>16);
}
__device__ inline float clipf(float x){
    const float LO=(float)(-1.0+1e-7), HI=(float)(1.0-1e-7);
    return fminf(fmaxf(x,LO),HI);
}
__device__ inline float wredsum(float v){
#pragma unroll
    for(int m=1;m<64;m<<=1) v+=__shfl_xor(v,m,64);
    return v;
}
// mode: 0 = bf16 ushort storage, 1 = f32 storage
__device__ inline float ldin(const void* p,size_t i,int md){
    return md ? ((const float*)p)[i] : bf2f(((const unsigned short*)p)[i]);
}
// exact np.linspace(0,8191,2048)[s].astype(int32)
__device__ inline int sidx(int s){ return (s*8191)/2047; }

// ---- dtype probe ----
__global__ void k_detect(const void* contour,int* flag){
    __shared__ int he;
    if(threadIdx.x==0) he=0;
    __syncthreads();
    const unsigned short* u=(const unsigned short*)contour;
    int h=0;
    for(int i=threadIdx.x;i<4096;i+=256){
        unsigned short lo=u[2*i];
        if(((lo>>7)&0xFF)>=0x86) h++;
    }
    atomicAdd(&he,h);
    __syncthreads();
    if(threadIdx.x==0) *flag = (he>400) ? 1 : 0;
}

// ---- canonicalize inputs, pack W2/W3/W4 A-frags, write outputs 0/1 ----
__global__ __launch_bounds__(256) void k_convert(
    const void* ctr,const void* loa,
    const void* w1,const void* w2,const void* w3,const void* w4,
    const void* g1,const void* be1,const void* g2,const void* be2,
    const void* g3,const void* be3,const void* g4,const void* be4,
    float* F, float* ctrf, float* loaf,
    unsigned short* u2h, unsigned short* u2l,
    unsigned short* u3h, unsigned short* u3l,
    unsigned short* u4h, unsigned short* u4l,
    float* out)
{
    int md=((const int*)F)[0];
    int i = blockIdx.x*256+threadIdx.x;     // 768 blocks -> 196608
    ctrf[i]=ldin(ctr,i,md);
    loaf[i]=ldin(loa,i,md);
    if(i<16384){
        // outputs 0/1: sampled contour + LOA (f32)
        int b=i>>11, s=i&2047;
        int idx=sidx(s);
        size_t cb=((size_t)b*NPTS+idx)*3;
        size_t ob=(size_t)i*3;
        out[ob]        =ldin(ctr,cb  ,md);
        out[ob+1]      =ldin(ctr,cb+1,md);
        out[ob+2]      =ldin(ctr,cb+2,md);
        out[49152+ob]  =ldin(loa,cb  ,md);
        out[49152+ob+1]=ldin(loa,cb+1,md);
        out[49152+ob+2]=ldin(loa,cb+2,md);
    }
    if(i<256)  F[F_WF1+i]=ldin(w1,i,md);
    if(i<2048) F[F_WF2+i]=ldin(w2,i,md);
    if(i<2048){
        // W2 (64x32) A-frags, kt=0 only: mt 0..3
        int j=i&7, lane=(i>>3)&63, mt=i>>9;
        int m=lane&15, kk=((lane>>4)<<3)|j;
        float w=ldin(w2,(size_t)(mt*16+m)*32 + kk, md);
        unsigned short hi=f2bf(w);
        u2h[i]=hi; u2l[i]=f2bf(w-bf2f(hi));
    }
    if(i<16384){
        int j=i&7, lane=(i>>3)&63, kt=(i>>9)&3, mt=i>>11;
        int m=lane&15, kk=((lane>>4)<<3)|j;
        float w=ldin(w3,(size_t)(mt*16+m)*128 + kt*32+kk, md);
        unsigned short hi=f2bf(w);
        u3h[i]=hi; u3l[i]=f2bf(w-bf2f(hi));
    }
    if(i<32768){
        int j=i&7, lane=(i>>3)&63, kt=(i>>9)&3, mt=i>>11;   // mt 0..15
        int m=lane&15, kk=((lane>>4)<<3)|j;
        float w=ldin(w4,(size_t)(mt*16+m)*128 + kt*32+kk, md);
        unsigned short hi=f2bf(w);
        u4h[i]=hi; u4l[i]=f2bf(w-bf2f(hi));
    }
    if(i<968)   F[4+i]=0.f;
    if(i<16896) F[F_P+i]=0.f;    // 16-slot partials (stats2m)
    if(i<16384) F[F_S3P+i]=0.f;  // 64-slot partials (stats3)
    if(i<32768) F[F_C4P+i]=0.f;  // 64-slot partials (conv4)
    if(i<32){ F[F_G1+i]=ldin(g1,i,md); F[F_BE1+i]=ldin(be1,i,md); }
    if(i<64){ F[F_G2+i]=ldin(g2,i,md); F[F_BE2+i]=ldin(be2,i,md); }
    if(i<128){ F[F_G3+i]=ldin(g3,i,md); F[F_BE3+i]=ldin(be3,i,md); }
    if(i<256){ F[F_G4+i]=ldin(g4,i,md); F[F_BE4+i]=ldin(be4,i,md); }
}

// ---- shared feature computation: r[8]; lane groups of 32 = one (b,s) ----
__device__ inline void rif_compute(const float* __restrict__ ctr,const float* __restrict__ loa,
                                   int b,int s,int k,float r[8])
{
    int idx=sidx(s);
    int gi=(idx-16+k)&(NPTS-1);
    size_t cb=((size_t)b*NPTS+gi)*3;
    float px=ctr[cb],py=ctr[cb+1],pz=ctr[cb+2];
    float lx=loa[cb],ly=loa[cb+1],lz=loa[cb+2];
    float sx=__shfl(px,16,32),sy=__shfl(py,16,32),sz=__shfl(pz,16,32);
    float ax=__shfl(lx,16,32),ay=__shfl(ly,16,32),az=__shfl(lz,16,32);
    float vx=px-sx,vy=py-sy,vz=pz-sz;
    float sq=vx*vx+vy*vy+vz*vz;
    float d1=sq>0.f?sqrtf(sq):0.f;
    float inv=d1>0.f?1.f/d1:0.f;
    float ux=vx*inv,uy=vy*inv,uz=vz*inv;
    float a1=ux*ax+uy*ay+uz*az;
    float a2=ux*lx+uy*ly+uz*lz;
    float a3=acosf(clipf(lx*ax+ly*ay+lz*az));
    int src=(k+31)&31;
    float pvx=__shfl(vx,src,32),pvy=__shfl(vy,src,32),pvz=__shfl(vz,src,32);
    float plx=__shfl(lx,src,32),ply=__shfl(ly,src,32),plz=__shfl(lz,src,32);
    float pux=__shfl(ux,src,32),puy=__shfl(uy,src,32),puz=__shfl(uz,src,32);
    float ivx=vx-pvx,ivy=vy-pvy,ivz=vz-pvz;
    float isq=ivx*ivx+ivy*ivy+ivz*ivz;
    float idn=isq>0.f?1.f/sqrtf(isq):0.f;
    float iux=ivx*idn,iuy=ivy*idn,iuz=ivz*idn;
    float a4=iux*lx+iuy*ly+iuz*lz;
    float a5=iux*plx+iuy*ply+iuz*plz;
    float a6=acosf(clipf(lx*plx+ly*ply+lz*plz));
    float d2=acosf(clipf(ux*pux+uy*puy+uz*puz));
    r[0]=d1;r[1]=d2;r[2]=a1;r[3]=a2;r[4]=a3;r[5]=a4;r[6]=a5;r[7]=a6;
}

// ---- features: rif moments (analytic BN1); optional r export (f32) ----
__global__ __launch_bounds__(256) void k_features(
    const float* __restrict__ ctrf,const float* __restrict__ loaf,
    float* __restrict__ mom1,float* __restrict__ mom2,
    float* __restrict__ rbuf)
{
    __shared__ float sm1[8],sm2[64];
    int t=threadIdx.x;
    if(t<8)sm1[t]=0.f;
    if(t<64)sm2[t]=0.f;
    __syncthreads();
    int lane=t&63,k=t&31;
    int q=blockIdx.x*256+t;
    int pos=q>>5,b=pos>>11,s=pos&2047;
    float r[8];
    rif_compute(ctrf,loaf,b,s,k,r);
    if(rbuf){
        fl4 a; a[0]=r[0];a[1]=r[1];a[2]=r[2];a[3]=r[3];
        fl4 c; c[0]=r[4];c[1]=r[5];c[2]=r[6];c[3]=r[7];
        ((fl4*)rbuf)[(size_t)q*2  ]=a;
        ((fl4*)rbuf)[(size_t)q*2+1]=c;
    }
#pragma unroll
    for(int i=0;i<8;i++){ float sv=wredsum(r[i]); if(lane==0)atomicAdd(&sm1[i],sv); }
#pragma unroll
    for(int i=0;i<8;i++)
#pragma unroll
        for(int j=i;j<8;j++){ float sv=wredsum(r[i]*r[j]); if(lane==0)atomicAdd(&sm2[i*8+j],sv); }
    __syncthreads();
    if(t<8)atomicAdd(&mom1[t],sm1[t]);
    if(t<64)atomicAdd(&mom2[t],sm2[t]);
}

// ---- analytic BN1 ----
__global__ void k_bn1(float* F){
    int o=threadIdx.x;
    if(o>=32)return;
    const float invP=1.0f/(float)QTOT;
    float m[8],w[8];
#pragma unroll
    for(int c=0;c<8;c++){ m[c]=F[F_MOM1+c]*invP; w[c]=F[F_WF1+o*8+c]; }
    float Ey=0.f;
#pragma unroll
    for(int c=0;c<8;c++) Ey+=w[c]*m[c];
    float Eyy=0.f;
#pragma unroll
    for(int i=0;i<8;i++)
#pragma unroll
        for(int j=0;j<8;j++){
            int a=i<j?i:j,bb=i<j?j:i;
            Eyy+=w[i]*w[j]*F[F_MOM2+a*8+bb]*invP;
        }
    float var=fmaxf(Eyy-Ey*Ey,0.f);
    float sc=F[F_G1+o]/sqrtf(var+1e-5f);
    F[F_SC1+o]=sc;
    F[F_SH1+o]=F[F_BE1+o]-Ey*sc;
}

// ---- stats2m: accumulate M1 = sum h1, M2 = sum h1 h1^T via MFMA ----
#define S2T 264
__global__ __launch_bounds__(256) void k_stats2m(
    const float* __restrict__ ctrf,const float* __restrict__ loaf,
    const float* __restrict__ F,float* __restrict__ P,
    const float* __restrict__ rbuf)
{
    __shared__ unsigned short TH[32*S2T];
    __shared__ unsigned short TL[32*S2T];
    int t=threadIdx.x, wv=t>>6, lane=t&63;
    int quad=lane>>4, col=lane&15;
    int mi=wv>>1, ni=wv&1;           // wave's M2 quadrant
    float acc8[8];                   // M1 partials: wave wv owns ch 8wv..8wv+7
#pragma unroll
    for(int k=0;k<8;k++) acc8[k]=0.f;
    f4v Z; Z[0]=0.f;Z[1]=0.f;Z[2]=0.f;Z[3]=0.f;
    f4v C0=Z, C1=Z;
    const float* wf1=F+F_WF1;
    const float* sc1=F+F_SC1; const float* sh1=F+F_SH1;
    for(int tt=0;tt<2;++tt){
        int tile=blockIdx.x*2+tt;                 // 0..2047
        int pos=tile*8 + wv*2 + (lane>>5);        // (b,s) index
        int b=pos>>11, s=pos&2047;
        float r[8];
        if(rbuf){
            size_t q=((size_t)pos*32+(lane&31));
            fl4 ra=((const fl4*)rbuf)[q*2], rc=((const fl4*)rbuf)[q*2+1];
            r[0]=ra[0];r[1]=ra[1];r[2]=ra[2];r[3]=ra[3];
            r[4]=rc[0];r[5]=rc[1];r[6]=rc[2];r[7]=rc[3];
        }else{
            rif_compute(ctrf,loaf,b,s,lane&31,r);
        }
        int mypos=wv*64+lane;                     // 0..255 within tile
#pragma unroll
        for(int c=0;c<32;c++){                    // fused h1: no h1[32] array
            const float* w=wf1+c*8;
            float y=w[0]*r[0]+w[1]*r[1]+w[2]*r[2]+w[3]*r[3]
                   +w[4]*r[4]+w[5]*r[5]+w[6]*r[6]+w[7]*r[7];
            float h=fmaxf(y*sc1[c]+sh1[c],0.f);
            unsigned short hi=f2bf(h);
            TH[c*S2T+mypos]=hi;
            TL[c*S2T+mypos]=f2bf(h-bf2f(hi));
        }
        __syncthreads();
#pragma unroll
        for(int kt=0;kt<8;kt++){
            s8v AH=*(const s8v*)(TH+(mi*16+col)*S2T + kt*32 + quad*8);
            s8v AL=*(const s8v*)(TL+(mi*16+col)*S2T + kt*32 + quad*8);
            s8v BH=*(const s8v*)(TH+(ni*16+col)*S2T + kt*32 + quad*8);
            s8v BL=*(const s8v*)(TL+(ni*16+col)*S2T + kt*32 + quad*8);
            if(kt&1){
                C1=MFMA(AH,BH,C1); C1=MFMA(AH,BL,C1); C1=MFMA(AL,BH,C1);
            }else{
                C0=MFMA(AH,BH,C0); C0=MFMA(AH,BL,C0); C0=MFMA(AL,BH,C0);
            }
        }
        // M1 from LDS: lane covers pos lane*4..lane*4+3 of each owned channel
#pragma unroll
        for(int k=0;k<8;k++){
            int c=wv*8+k;
            const unsigned short* ph=TH+c*S2T+lane*4;
            const unsigned short* pl=TL+c*S2T+lane*4;
            acc8[k]+=bf2f(ph[0])+bf2f(ph[1])+bf2f(ph[2])+bf2f(ph[3])
                    +bf2f(pl[0])+bf2f(pl[1])+bf2f(pl[2])+bf2f(pl[3]);
        }
        __syncthreads();
    }
    // flush to partial slot (slot = blk & 15): P[slot][0..31]=M1, [32..1055]=M2
    float* Ps=P+(size_t)(blockIdx.x&15)*1056;
#pragma unroll
    for(int rg=0;rg<4;rg++){
        float v=C0[rg]+C1[rg];
        atomicAdd(&Ps[32+(mi*16+quad*4+rg)*32 + ni*16+col], v);
    }
#pragma unroll
    for(int k=0;k<8;k++){
        float sv=wredsum(acc8[k]);
        if(lane==0) atomicAdd(&Ps[wv*8+k],sv);
    }
}

// ---- fold 16 partial slots into F_M1/F_M2, then analytic BN2 (merged) ----
__global__ void k_red(float* F){
    int t=threadIdx.x;   // 1 block x 256 threads
    for(int e=t;e<1056;e+=256){
        float s=0.f;
#pragma unroll
        for(int k=0;k<16;k++) s+=F[F_P+k*1056+e];
        if(e<32) F[F_M1+e]=s; else F[F_M2+e-32]=s;
    }
    __syncthreads();
    int o=t;
    if(o<64){
        const float invP=1.0f/(float)QTOT;
        const float* w=F+F_WF2+o*32;
        const float* M2=F+F_M2;
        float Ey=0.f;
#pragma unroll
        for(int c=0;c<32;c++) Ey+=w[c]*F[F_M1+c];
        Ey*=invP;
        float Eyy=0.f;
        for(int c1=0;c1<32;c1++){
            float acc=0.f;
#pragma unroll
            for(int c2=0;c2<32;c2++) acc+=w[c2]*M2[c1*32+c2];
            Eyy+=w[c1]*acc;
        }
        Eyy*=invP;
        float var=fmaxf(Eyy-Ey*Ey,0.f);
        float s=F[F_G2+o]/sqrtf(var+1e-5f);
        F[F_SC2+o]=s;
        F[F_SH2+o]=F[F_BE2+o]-Ey*s;
    }
}

// ---- fold stats3 64 slots -> BN3 scale/shift (single writer) ----
__global__ void k_bnd3(float* F){
    int o=threadIdx.x;
    if(o>=128)return;
    float sum=0.f,ssq=0.f;
    for(int s=0;s<64;s++){
        sum+=F[F_S3P+s*256+o];
        ssq+=F[F_S3P+s*256+128+o];
    }
    const float invP=1.0f/(float)QTOT;
    float mean=sum*invP;
    float var=fmaxf(ssq*invP-mean*mean,0.f);
    float sc=F[F_G3+o]/sqrtf(var+1e-5f);
    F[F_SC3+o]=sc;
    F[F_SH3+o]=F[F_BE3+o]-mean*sc;
}

// ---- fold conv4 64 slots -> BN4 scale/shift (single writer) ----
__global__ void k_bnd4(float* F){
    int o=threadIdx.x;
    if(o>=256)return;
    float sum=0.f,ssq=0.f;
    for(int s=0;s<64;s++){
        sum+=F[F_C4P+s*512+o];
        ssq+=F[F_C4P+s*512+256+o];
    }
    const float invP=1.0f/(float)QTOT;
    float mean=sum*invP;
    float var=fmaxf(ssq*invP-mean*mean,0.f);
    float sc=F[F_G4+o]/sqrtf(var+1e-5f);
    F[F_SC4+o]=sc;
    F[F_SH4+o]=F[F_BE4+o]-mean*sc;
}

// =====================================================================
// MFMA tile kernels, 512-thread (8-wave). Tile = 64 positions (2 s).
// 64-slot de-contended stats flush (round-13: 343->246us). Tier-1 y3
// interstage (round-14: conv4 -> GEMM2-only). Tier-2: r precomputed in
// k_features -> stats3 build balanced: all 8 waves do 4 h1-ch + 8 fm-d.
// =====================================================================
#define XST 136   // ushort row stride (16B-aligned rows)

__device__ inline void build_x2_8(
    const float* __restrict__ ctrf,const float* __restrict__ loaf,
    const void* __restrict__ fm,const float* __restrict__ F,
    const unsigned short* __restrict__ u2h,const unsigned short* __restrict__ u2l,
    int md,int b,int s0,int wv,int lane,
    unsigned short* XH,unsigned short* XL)
{
    int quad=lane>>4, col=lane&15;
    if(wv<4){
        // rif + h1, 8 channels per wave (waves 0-3)
        float r8[8]; rif_compute(ctrf,loaf,b,s0+(lane>>5),lane&31,r8);
        const float* wf1=F+F_WF1;
        const float* sc1=F+F_SC1; const float* sh1=F+F_SH1;
        s8v vh,vl;
#pragma unroll
        for(int j=0;j<8;j++){
            int o=8*wv+j;
            const float* w=wf1+o*8;
            float y=w[0]*r8[0]+w[1]*r8[1]+w[2]*r8[2]+w[3]*r8[3]
                   +w[4]*r8[4]+w[5]*r8[5]+w[6]*r8[6]+w[7]*r8[7];
            float h=fmaxf(y*sc1[o]+sh1[o],0.f);
            unsigned short hi=f2bf(h);
            vh[j]=(short)hi;
            vl[j]=(short)f2bf(h-bf2f(hi));
        }
        *(s8v*)(XH + lane*XST + 8*wv)=vh;
        *(s8v*)(XL + lane*XST + 8*wv)=vl;
    }else{
        // fm gather, 16 d per wave (waves 4-7)
        int dbase=16*(wv-4);
        int s=s0+(lane>>5), k=lane&31;
        int gi=(sidx(s)-16+k)&(NPTS-1);
        size_t fb=(size_t)b*64*NPTS+gi;
        for(int g=0;g<2;g++){
            s8v vh,vl;
#pragma unroll
            for(int j=0;j<8;j++){
                int d=dbase+g*8+j;
                float v = md ? ((const float*)fm)[fb+(size_t)d*NPTS]
                             : bf2f(((const unsigned short*)fm)[fb+(size_t)d*NPTS]);
                unsigned short hi=f2bf(v);
                vh[j]=(short)hi;
                vl[j]=(short)f2bf(v-bf2f(hi));
            }
            *(s8v*)(XH + lane*XST + 64 + dbase + g*8)=vh;
            *(s8v*)(XL + lane*XST + 64 + dbase + g*8)=vl;
        }
    }
    __syncthreads();   // h1 (cols 0..31) + fm (cols 64..127) visible
    // ---- conv2 via MFMA: wave -> (ch-group cg, nt-pair nb) ----
    int cg=wv>>1, nb=(wv&1)*2;
    s8v AH=*(const s8v*)(u2h+(cg*64+lane)*8);
    s8v AL=*(const s8v*)(u2l+(cg*64+lane)*8);
    s8v BH0=*(const s8v*)(XH+((nb  )*16+col)*XST+quad*8);
    s8v BL0=*(const s8v*)(XL+((nb  )*16+col)*XST+quad*8);
    s8v BH1=*(const s8v*)(XH+((nb+1)*16+col)*XST+quad*8);
    s8v BL1=*(const s8v*)(XL+((nb+1)*16+col)*XST+quad*8);
    f4v Z; Z[0]=0.f;Z[1]=0.f;Z[2]=0.f;Z[3]=0.f;
    f4v c0=MFMA(AH,BH0,Z), c1=MFMA(AH,BH1,Z);
    c0=MFMA(AH,BL0,c0); c1=MFMA(AH,BL1,c1);
    c0=MFMA(AL,BH0,c0); c1=MFMA(AL,BH1,c1);
    __syncthreads();   // all h1 reads done before cols 0..63 overwritten
    // ---- BN2 + relu, write split h2 to cols 0..63 ----
    const float* sc2=F+F_SC2; const float* sh2=F+F_SH2;
    int chb=cg*16+quad*4;
    float g0=sc2[chb],g1=sc2[chb+1],g2=sc2[chb+2],g3=sc2[chb+3];
    float b0=sh2[chb],b1=sh2[chb+1],b2=sh2[chb+2],b3=sh2[chb+3];
#pragma unroll
    for(int i=0;i<2;i++){
        f4v c = i? c1 : c0;
        int p=(nb+i)*16+col;
        float v0=fmaxf(c[0]*g0+b0,0.f);
        float v1=fmaxf(c[1]*g1+b1,0.f);
        float v2=fmaxf(c[2]*g2+b2,0.f);
        float v3=fmaxf(c[3]*g3+b3,0.f);
        unsigned short h0=f2bf(v0),h1=f2bf(v1),h2=f2bf(v2),h3=f2bf(v3);
        s4v vh,vl;
        vh[0]=(short)h0; vh[1]=(short)h1; vh[2]=(short)h2; vh[3]=(short)h3;
        vl[0]=(short)f2bf(v0-bf2f(h0)); vl[1]=(short)f2bf(v1-bf2f(h1));
        vl[2]=(short)f2bf(v2-bf2f(h2)); vl[3]=(short)f2bf(v3-bf2f(h3));
        *(s4v*)(XH + p*XST + chb)=vh;
        *(s4v*)(XL + p*XST + chb)=vl;
    }
    // caller's __syncthreads() completes the tile
}

// GEMM1 (512t): wave wv owns mt=wv (mt 0..7), acc C[4]
#define G1_STEP8(UH,UL) \
    for(int kt=0;kt<4;kt++){ \
        s8v BH[4],BL[4]; \
        for(int nt=0;nt<4;nt++){ \
            int boff=(nt*16+col)*XST + kt*32 + quad*8; \
            BH[nt]=*(const s8v*)(XH+boff); \
            BL[nt]=*(const s8v*)(XL+boff); \
        } \
        { \
            s8v AH=*(const s8v*)(UH+((wv*4+kt)*64+lane)*8); \
            s8v AL=*(const s8v*)(UL+((wv*4+kt)*64+lane)*8); \
            for(int nt=0;nt<4;nt++) C[nt]=MFMA(AH,BH[nt],C[nt]); \
            for(int nt=0;nt<4;nt++) C[nt]=MFMA(AH,BL[nt],C[nt]); \
            for(int nt=0;nt<4;nt++) C[nt]=MFMA(AL,BH[nt],C[nt]); \
        } \
    }

// GEMM2 (512t): wave wv owns mt=2wv..2wv+1, acc C2[2][4]
#define G2_STEP8(UH,UL) \
    for(int kt=0;kt<4;kt++){ \
        s8v BH[4],BL[4]; \
        for(int nt=0;nt<4;nt++){ \
            int boff=(nt*16+col)*XST + kt*32 + quad*8; \
            BH[nt]=*(const s8v*)(XH+boff); \
            BL[nt]=*(const s8v*)(XL+boff); \
        } \
        for(int mi=0;mi<2;mi++){ \
            int mt=2*wv+mi; \
            s8v AH=*(const s8v*)(UH+((mt*4+kt)*64+lane)*8); \
            s8v AL=*(const s8v*)(UL+((mt*4+kt)*64+lane)*8); \
            for(int nt=0;nt<4;nt++) C2[mi][nt]=MFMA(AH,BH[nt],C2[mi][nt]); \
            for(int nt=0;nt<4;nt++) C2[mi][nt]=MFMA(AH,BL[nt],C2[mi][nt]); \
            for(int nt=0;nt<4;nt++) C2[mi][nt]=MFMA(AL,BH[nt],C2[mi][nt]); \
        } \
    }

// stats3 tail: y3 export + sum/ssq reduce + 64-slot flush
#define S3_TAIL \
    if(y3){ \
        for(int nt=0;nt<4;nt++){ \
            s4v v4; \
            for(int rg=0;rg<4;rg++) v4[rg]=(short)f2bf(C[nt][rg]); \
            *(s4v*)(y3 + (size_t)blockIdx.x*8192 + (size_t)(wv*4+nt)*256 + lane*4) = v4; \
        } \
    } \
    for(int rg=0;rg<4;rg++){ \
        float sm=0.f,sq=0.f; \
        for(int nt=0;nt<4;nt++){ float v=C[nt][rg]; sm+=v; sq+=v*v; } \
        sm+=__shfl_xor(sm,1); sq+=__shfl_xor(sq,1); \
        sm+=__shfl_xor(sm,2); sq+=__shfl_xor(sq,2); \
        sm+=__shfl_xor(sm,4); sq+=__shfl_xor(sq,4); \
        sm+=__shfl_xor(sm,8); sq+=__shfl_xor(sq,8); \
        if(col==0){ \
            int ch=wv*16+quad*4+rg; \
            atomicAdd(&as_[ch],sm); atomicAdd(&qs_[ch],sq); \
        } \
    } \
    __syncthreads(); \
    float* Ps=F+F_S3P+(size_t)(blockIdx.x&63)*256; \
    if(t<128){atomicAdd(&Ps[t],as_[t]);atomicAdd(&Ps[128+t],qs_[t]);}

// ---- stats3 (tier<2): rif-based build -> GEMM1 -> y3 + stats ----
__global__ __launch_bounds__(512) void k_stats3(
    const float* __restrict__ ctrf,const float* __restrict__ loaf,
    const void* __restrict__ fm,float* __restrict__ F,
    const unsigned short* __restrict__ u2h,const unsigned short* __restrict__ u2l,
    const unsigned short* __restrict__ u3h,const unsigned short* __restrict__ u3l,
    unsigned short* __restrict__ y3)
{
    __shared__ unsigned short XH[64*XST];
    __shared__ unsigned short XL[64*XST];
    __shared__ float as_[128],qs_[128];
    int t=threadIdx.x, wv=t>>6, lane=t&63;
    if(t<128){as_[t]=0.f;qs_[t]=0.f;}
    int md=((const int*)F)[0];
    int pos0=blockIdx.x*2, b=pos0>>11, s0=pos0&2047;
    build_x2_8(ctrf,loaf,fm,F,u2h,u2l,md,b,s0,wv,lane,XH,XL);
    __syncthreads();
    int quad=lane>>4, col=lane&15;
    f4v Z; Z[0]=0.f;Z[1]=0.f;Z[2]=0.f;Z[3]=0.f;
    f4v C[4];
#pragma unroll
    for(int nt=0;nt<4;nt++) C[nt]=Z;
#pragma unroll
    G1_STEP8(u3h,u3l)
    S3_TAIL
}

// ---- stats3r (tier2): r preloaded; balanced build (all 8 waves) ----
__global__ __launch_bounds__(512) void k_stats3r(
    const void* __restrict__ fm,float* __restrict__ F,
    const float* __restrict__ rbuf,
    const unsigned short* __restrict__ u2h,const unsigned short* __restrict__ u2l,
    const unsigned short* __restrict__ u3h,const unsigned short* __restrict__ u3l,
    unsigned short* __restrict__ y3)
{
    __shared__ unsigned short XH[64*XST];
    __shared__ unsigned short XL[64*XST];
    __shared__ float as_[128],qs_[128];
    int t=threadIdx.x, wv=t>>6, lane=t&63;
    if(t<128){as_[t]=0.f;qs_[t]=0.f;}
    int md=((const int*)F)[0];
    int pos0=blockIdx.x*2, b=pos0>>11, s0=pos0&2047;
    int quad=lane>>4, col=lane&15;
    int scol=lane>>5, k=lane&31;
    int s=s0+scol;
    // ---- fm gather: every wave covers 8 d (dbase=8*wv) ----
    {
        int dbase=8*wv;
        int gi=(sidx(s)-16+k)&(NPTS-1);
        size_t fb=(size_t)b*64*NPTS+gi;
        s8v fvh,fvl;
#pragma unroll
        for(int j=0;j<8;j++){
            int d=dbase+j;
            float v = md ? ((const float*)fm)[fb+(size_t)d*NPTS]
                         : bf2f(((const unsigned short*)fm)[fb+(size_t)d*NPTS]);
            unsigned short hi=f2bf(v);
            fvh[j]=(short)hi;
            fvl[j]=(short)f2bf(v-bf2f(hi));
        }
        *(s8v*)(XH + lane*XST + 64 + dbase)=fvh;
        *(s8v*)(XL + lane*XST + 64 + dbase)=fvl;
    }
    // ---- h1: every wave covers 4 ch (o=wv*4..wv*4+3) from loaded r ----
    {
        size_t q=(((size_t)b*2048+s)*32+k);
        fl4 ra=((const fl4*)rbuf)[q*2], rc=((const fl4*)rbuf)[q*2+1];
        const float* wf1=F+F_WF1;
        const float* sc1=F+F_SC1; const float* sh1=F+F_SH1;
        s4v vh,vl;
#pragma unroll
        for(int j=0;j<4;j++){
            int o=wv*4+j;
            const float* w=wf1+o*8;
            float y=w[0]*ra[0]+w[1]*ra[1]+w[2]*ra[2]+w[3]*ra[3]
                   +w[4]*rc[0]+w[5]*rc[1]+w[6]*rc[2]+w[7]*rc[3];
            float h=fmaxf(y*sc1[o]+sh1[o],0.f);
            unsigned short hi=f2bf(h);
            vh[j]=(short)hi;
            vl[j]=(short)f2bf(h-bf2f(hi));
        }
        *(s4v*)(XH + lane*XST + wv*4)=vh;
        *(s4v*)(XL + lane*XST + wv*4)=vl;
    }
    __syncthreads();   // h1 (cols 0..31) + fm (cols 64..127) visible
    // ---- conv2 via MFMA: wave -> (ch-group cg, nt-pair nb) ----
    int cg=wv>>1, nb=(wv&1)*2;
    s8v AH=*(const s8v*)(u2h+(cg*64+lane)*8);
    s8v AL=*(const s8v*)(u2l+(cg*64+lane)*8);
    s8v BH0=*(const s8v*)(XH+((nb  )*16+col)*XST+quad*8);
    s8v BL0=*(const s8v*)(XL+((nb  )*16+col)*XST+quad*8);
    s8v BH1=*(const s8v*)(XH+((nb+1)*16+col)*XST+quad*8);
    s8v BL1=*(const s8v*)(XL+((nb+1)*16+col)*XST+quad*8);
    f4v Z; Z[0]=0.f;Z[1]=0.f;Z[2]=0.f;Z[3]=0.f;
    f4v c0=MFMA(AH,BH0,Z), c1=MFMA(AH,BH1,Z);
    c0=MFMA(AH,BL0,c0); c1=MFMA(AH,BL1,c1);
    c0=MFMA(AL,BH0,c0); c1=MFMA(AL,BH1,c1);
    __syncthreads();   // all h1 reads done before cols 0..63 overwritten
    // ---- BN2 + relu, write split h2 to cols 0..63 ----
    {
        const float* sc2=F+F_SC2; const float* sh2=F+F_SH2;
        int chb=cg*16+quad*4;
        float g0=sc2[chb],g1=sc2[chb+1],g2=sc2[chb+2],g3=sc2[chb+3];
        float b0=sh2[chb],b1=sh2[chb+1],b2=sh2[chb+2],b3=sh2[chb+3];
#pragma unroll
        for(int i=0;i<2;i++){
            f4v c = i? c1 : c0;
            int p=(nb+i)*16+col;
            float v0=fmaxf(c[0]*g0+b0,0.f);
            float v1=fmaxf(c[1]*g1+b1,0.f);
            float v2=fmaxf(c[2]*g2+b2,0.f);
            float v3=fmaxf(c[3]*g3+b3,0.f);
            unsigned short h0=f2bf(v0),h1=f2bf(v1),h2=f2bf(v2),h3=f2bf(v3);
            s4v vh,vl;
            vh[0]=(short)h0; vh[1]=(short)h1; vh[2]=(short)h2; vh[3]=(short)h3;
            vl[0]=(short)f2bf(v0-bf2f(h0)); vl[1]=(short)f2bf(v1-bf2f(h1));
            vl[2]=(short)f2bf(v2-bf2f(h2)); vl[3]=(short)f2bf(v3-bf2f(h3));
            *(s4v*)(XH + p*XST + chb)=vh;
            *(s4v*)(XL + p*XST + chb)=vl;
        }
    }
    __syncthreads();   // x2 tile complete
    f4v C[4];
#pragma unroll
    for(int nt=0;nt<4;nt++) C[nt]=Z;
#pragma unroll
    G1_STEP8(u3h,u3l)
    S3_TAIL
}

// ---- conv4 Y (tier>=1): reload y3 bf16 -> BN3/relu -> h3(LDS) -> GEMM2 ----
__global__ __launch_bounds__(512) void k_conv4y(
    float* __restrict__ F,
    const unsigned short* __restrict__ u4h,const unsigned short* __restrict__ u4l,
    const unsigned short* __restrict__ y3,
    float* __restrict__ maxb)
{
    __shared__ unsigned short XH[64*XST];
    __shared__ unsigned short XL[64*XST];
    __shared__ float as_[256],qs_[256];
    int t=threadIdx.x, wv=t>>6, lane=t&63;
    if(t<256){as_[t]=0.f; qs_[t]=0.f;}
    int quad=lane>>4, col=lane&15;
    int pos0=blockIdx.x*2, b=pos0>>11, s0=pos0&2047;
    const float* sc3=F+F_SC3; const float* sh3=F+F_SH3;
    // ---- load y3, BN3+relu, write split h3 tile (cols 0..127) ----
    {
        int chb=wv*16+quad*4;
#pragma unroll
        for(int nt=0;nt<4;nt++){
            s4v v4=*(const s4v*)(y3 + (size_t)blockIdx.x*8192 + (size_t)(wv*4+nt)*256 + lane*4);
            s4v vh,vl;
#pragma unroll
            for(int rg=0;rg<4;rg++){
                float v=bf2f((unsigned short)v4[rg]);
                v=fmaxf(v*sc3[chb+rg]+sh3[chb+rg],0.f);
                unsigned short hi=f2bf(v);
                vh[rg]=(short)hi;
                vl[rg]=(short)f2bf(v-bf2f(hi));
            }
            int p=nt*16+col;
            *(s4v*)(XH + p*XST + chb)=vh;
            *(s4v*)(XL + p*XST + chb)=vl;
        }
    }
    __syncthreads();   // h3 tile complete
    // ---- GEMM2: C2[2][4], mt=2wv..2wv+1 ----
    f4v Z; Z[0]=0.f;Z[1]=0.f;Z[2]=0.f;Z[3]=0.f;
    f4v C2[2][4];
#pragma unroll
    for(int mi=0;mi<2;mi++)
#pragma unroll
        for(int nt=0;nt<4;nt++) C2[mi][nt]=Z;
#pragma unroll
    G2_STEP8(u4h,u4l)
    // ---- epilogue ----
#pragma unroll
    for(int mi=0;mi<2;mi++){
        int mt=2*wv+mi;
#pragma unroll
        for(int rg=0;rg<4;rg++){
            float sm=0.f,sq=0.f,mx0=-3.4e38f,mx1=-3.4e38f;
#pragma unroll
            for(int nt=0;nt<4;nt++){
                float v=C2[mi][nt][rg];
                sm+=v; sq+=v*v;
                if(nt<2) mx0=fmaxf(mx0,v); else mx1=fmaxf(mx1,v);
            }
            sm+=__shfl_xor(sm,1); sq+=__shfl_xor(sq,1);
            sm+=__shfl_xor(sm,2); sq+=__shfl_xor(sq,2);
            sm+=__shfl_xor(sm,4); sq+=__shfl_xor(sq,4);
            sm+=__shfl_xor(sm,8); sq+=__shfl_xor(sq,8);
            mx0=fmaxf(mx0,__shfl_xor(mx0,1)); mx1=fmaxf(mx1,__shfl_xor(mx1,1));
            mx0=fmaxf(mx0,__shfl_xor(mx0,2)); mx1=fmaxf(mx1,__shfl_xor(mx1,2));
            mx0=fmaxf(mx0,__shfl_xor(mx0,4)); mx1=fmaxf(mx1,__shfl_xor(mx1,4));
            mx0=fmaxf(mx0,__shfl_xor(mx0,8)); mx1=fmaxf(mx1,__shfl_xor(mx1,8));
            if(col==0){
                int ch=mt*16+quad*4+rg;
                atomicAdd(&as_[ch],sm); atomicAdd(&qs_[ch],sq);
                size_t ob=((size_t)b*256+ch)*SSZ + s0;
                maxb[ob]=mx0; maxb[ob+1]=mx1;
            }
        }
    }
    __syncthreads();
    // 64-slot de-contended flush
    float* Ps=F+F_C4P+(size_t)(blockIdx.x&63)*512;
    if(t<256){atomicAdd(&Ps[t],as_[t]);atomicAdd(&Ps[256+t],qs_[t]);}
}

// ---- conv4 SLOW (fallback when ws too small): full rebuild, 512t ----
__global__ __launch_bounds__(512) void k_conv4(
    const float* __restrict__ ctrf,const float* __restrict__ loaf,
    const void* __restrict__ fm,float* __restrict__ F,
    const unsigned short* __restrict__ u2h,const unsigned short* __restrict__ u2l,
    const unsigned short* __restrict__ u3h,const unsigned short* __restrict__ u3l,
    const unsigned short* __restrict__ u4h,const unsigned short* __restrict__ u4l,
    float* __restrict__ maxb)
{
    __shared__ unsigned short XH[64*XST];
    __shared__ unsigned short XL[64*XST];
    __shared__ float as_[256],qs_[256];
    int t=threadIdx.x, wv=t>>6, lane=t&63;
    if(t<256){as_[t]=0.f; qs_[t]=0.f;}
    int md=((const int*)F)[0];
    int pos0=blockIdx.x*2, b=pos0>>11, s0=pos0&2047;
    build_x2_8(ctrf,loaf,fm,F,u2h,u2l,md,b,s0,wv,lane,XH,XL);
    __syncthreads();
    int quad=lane>>4, col=lane&15;
    f4v Z; Z[0]=0.f;Z[1]=0.f;Z[2]=0.f;Z[3]=0.f;
    f4v C[4];
#pragma unroll
    for(int nt=0;nt<4;nt++) C[nt]=Z;
#pragma unroll
    G1_STEP8(u3h,u3l)
    __syncthreads();
    const float* sc3=F+F_SC3; const float* sh3=F+F_SH3;
    {
        int chb=wv*16+quad*4;
#pragma unroll
        for(int nt=0;nt<4;nt++){
            int p=nt*16+col;
            s4v vh,vl;
#pragma unroll
            for(int rg=0;rg<4;rg++){
                float v=C[nt][rg];
                v=fmaxf(v*sc3[chb+rg]+sh3[chb+rg],0.f);
                unsigned short hi=f2bf(v);
                vh[rg]=(short)hi;
                vl[rg]=(short)f2bf(v-bf2f(hi));
            }
            *(s4v*)(XH + p*XST + chb)=vh;
            *(s4v*)(XL + p*XST + chb)=vl;
        }
    }
    __syncthreads();
    f4v C2[2][4];
#pragma unroll
    for(int mi=0;mi<2;mi++)
#pragma unroll
        for(int nt=0;nt<4;nt++) C2[mi][nt]=Z;
#pragma unroll
    G2_STEP8(u4h,u4l)
#pragma unroll
    for(int mi=0;mi<2;mi++){
        int mt=2*wv+mi;
#pragma unroll
        for(int rg=0;rg<4;rg++){
            float sm=0.f,sq=0.f,mx0=-3.4e38f,mx1=-3.4e38f;
#pragma unroll
            for(int nt=0;nt<4;nt++){
                float v=C2[mi][nt][rg];
                sm+=v; sq+=v*v;
                if(nt<2) mx0=fmaxf(mx0,v); else mx1=fmaxf(mx1,v);
            }
            sm+=__shfl_xor(sm,1); sq+=__shfl_xor(sq,1);
            sm+=__shfl_xor(sm,2); sq+=__shfl_xor(sq,2);
            sm+=__shfl_xor(sm,4); sq+=__shfl_xor(sq,4);
            sm+=__shfl_xor(sm,8); sq+=__shfl_xor(sq,8);
            mx0=fmaxf(mx0,__shfl_xor(mx0,1)); mx1=fmaxf(mx1,__shfl_xor(mx1,1));
            mx0=fmaxf(mx0,__shfl_xor(mx0,2)); mx1=fmaxf(mx1,__shfl_xor(mx1,2));
            mx0=fmaxf(mx0,__shfl_xor(mx0,4)); mx1=fmaxf(mx1,__shfl_xor(mx1,4));
            mx0=fmaxf(mx0,__shfl_xor(mx0,8)); mx1=fmaxf(mx1,__shfl_xor(mx1,8));
            if(col==0){
                int ch=mt*16+quad*4+rg;
                atomicAdd(&as_[ch],sm); atomicAdd(&qs_[ch],sq);
                size_t ob=((size_t)b*256+ch)*SSZ + s0;
                maxb[ob]=mx0; maxb[ob+1]=mx1;
            }
        }
    }
    __syncthreads();
    float* Ps=F+F_C4P+(size_t)(blockIdx.x&63)*512;
    if(t<256){atomicAdd(&Ps[t],as_[t]);atomicAdd(&Ps[256+t],qs_[t]);}
}

// ---- final: out2 = relu(BN4(K-max)) in place, float4 (gamma=1 => scale>0) ----
__global__ __launch_bounds__(256) void k_apply(
    const float* __restrict__ F,float* __restrict__ out)
{
    int e4=blockIdx.x*256+threadIdx.x;     // 1048576 quads = B*256*S/4
    int j=(e4>>9)&255;                     // (e4*4>>11)&255; 4 elems share j
    float sc=F[F_SC4+j],sh=F[F_SH4+j];
    fl4* p=(fl4*)(out+98304)+e4;
    fl4 v=*p;
    v[0]=fmaxf(v[0]*sc+sh,0.f);
    v[1]=fmaxf(v[1]*sc+sh,0.f);
    v[2]=fmaxf(v[2]*sc+sh,0.f);
    v[3]=fmaxf(v[3]*sc+sh,0.f);
    *p=v;
}

extern "C" void kernel_launch(void* const* d_in, const int* in_sizes, int n_in,
                              void* d_out, int out_size, void* d_ws, size_t ws_size,
                              hipStream_t stream)
{
    const void* contour=d_in[0];
    const void* loa    =d_in[1];
    const void* fm     =d_in[2];
    const void* w1 =d_in[3];  const void* g1 =d_in[5];  const void* be1=d_in[6];
    const void* w2 =d_in[7];  const void* g2 =d_in[9];  const void* be2=d_in[10];
    const void* w3 =d_in[11]; const void* g3 =d_in[13]; const void* be3=d_in[14];
    const void* w4 =d_in[15]; const void* g4 =d_in[17]; const void* be4=d_in[18];
    float* out=(float*)d_out;          // output buffer is float32

    float* F=(float*)d_ws;
    char* base=(char*)d_ws;
    float* ctrf=(float*)(base+CTR_OFF);
    float* loaf=(float*)(base+LOA_OFF);
    unsigned short* u3h=(unsigned short*)(base+U3H_OFF);
    unsigned short* u3l=(unsigned short*)(base+U3L_OFF);
    unsigned short* u4h=(unsigned short*)(base+U4H_OFF);
    unsigned short* u4l=(unsigned short*)(base+U4L_OFF);
    unsigned short* u2h=(unsigned short*)(base+U2H_OFF);
    unsigned short* u2l=(unsigned short*)(base+U2L_OFF);
    int tier = (ws_size >= WS_T2) ? 2 : (ws_size >= WS_T1) ? 1 : 0;
    unsigned short* y3 = tier>=1 ? (unsigned short*)(base+Y3_OFF) : (unsigned short*)0;
    float* rbuf = tier==2 ? (float*)(base+R_OFF) : (float*)0;
    float* maxb=out+98304;             // out2 f32 region doubles as K-max scratch

    k_detect<<<1,256,0,stream>>>(contour,(int*)d_ws);
    k_convert<<<768,256,0,stream>>>(contour,loa,w1,w2,w3,w4,g1,be1,g2,be2,g3,be3,g4,be4,
                                    F,ctrf,loaf,u2h,u2l,u3h,u3l,u4h,u4l,out);
    k_features<<<2048,256,0,stream>>>(ctrf,loaf,F+F_MOM1,F+F_MOM2,rbuf);
    k_bn1<<<1,32,0,stream>>>(F);
    k_stats2m<<<1024,256,0,stream>>>(ctrf,loaf,F,F+F_P,rbuf);
    k_red<<<1,256,0,stream>>>(F);
    if(tier==2){
        k_stats3r<<<8192,512,0,stream>>>(fm,F,rbuf,u2h,u2l,u3h,u3l,y3);
    }else{
        k_stats3<<<8192,512,0,stream>>>(ctrf,loaf,fm,F,u2h,u2l,u3h,u3l,y3);
    }
    k_bnd3<<<1,128,0,stream>>>(F);
    if(tier>=1){
        k_conv4y<<<8192,512,0,stream>>>(F,u4h,u4l,y3,maxb);
    }else{
        k_conv4<<<8192,512,0,stream>>>(ctrf,loaf,fm,F,u2h,u2l,u3h,u3l,u4h,u4l,maxb);
    }
    k_bnd4<<<1,256,0,stream>>>(F);
    k_apply<<<4096,256,0,stream>>>(F,out);
}